// Round 1
// baseline (864.997 us; speedup 1.0000x reference)
//
#include <hip/hip_runtime.h>
#include <hip/hip_bf16.h>
#include <cstdint>
#include <cstddef>

// Problem constants
#define NSEQ 4096
#define MDIM 1024
// band: |i-j| < 250  -> row-tile ti only needs col-tiles [ti-2, ti+2]
// banded logits layout: Lband[i][c], c = j - 128*(ti-2), width 640

typedef __attribute__((ext_vector_type(8))) short short8;
typedef __attribute__((ext_vector_type(4))) float f32x4;

__device__ __forceinline__ unsigned short f2b(float x) {
  union { float f; unsigned int u; } a; a.f = x;
  unsigned int r = (a.u + 0x7fffu + ((a.u >> 16) & 1u)) >> 16;
  return (unsigned short)r;
}

// -------- fp32 -> bf16 convert (n4 = n/4) --------
__global__ __launch_bounds__(256) void k_cvt(const float* __restrict__ in,
                                             unsigned short* __restrict__ out, int n4) {
  int idx = blockIdx.x * 256 + threadIdx.x;
  if (idx >= n4) return;
  float4 v = *(const float4*)(in + (size_t)idx * 4);
  ushort4 o;
  o.x = f2b(v.x); o.y = f2b(v.y); o.z = f2b(v.z); o.w = f2b(v.w);
  *(ushort4*)(out + (size_t)idx * 4) = o;
}

// -------- GEMM: C = alpha*(A @ B^T) + bias, A[M,K] bf16, B[N,K] bf16 --------
// mode 0: normal. grid = (N/128, M/128)
// mode 1: banded logits. grid = (5, M/128); col tile = by+bx-2; store into Lband (ldc=640) at col bx*128
// mode 2: banded K (A has band-sparse cols): K-loop limited to [128*(by-2), 128*(by+3))
__global__ __launch_bounds__(256) void k_gemm(
    const unsigned short* __restrict__ A, int lda,
    const unsigned short* __restrict__ B, int ldb,
    void* __restrict__ Cout, int ldc,
    int Ncols, int K, float alpha,
    const float* __restrict__ bias, int relu, int out_bf16, int mode) {
  __shared__ unsigned short As[128][40];  // +8 pad: conflict-light, keeps 16B align
  __shared__ unsigned short Bs[128][40];
  int by = blockIdx.y;
  int bx = blockIdx.x;
  int btile;
  if (mode == 1) {
    btile = by + bx - 2;
    if (btile < 0 || btile * 128 >= Ncols) return;
  } else {
    btile = bx;
  }
  int ccol0 = bx * 128;
  int k0 = 0, k1 = K;
  if (mode == 2) {
    int lo = by - 2; if (lo < 0) lo = 0;
    int hi = (by + 3) * 128; if (hi > K) hi = K;
    k0 = lo * 128; k1 = hi;
  }
  const int t = threadIdx.x;
  const int lane = t & 63;
  const int w = t >> 6;
  const int wm = (w >> 1) * 64;
  const int wn = (w & 1) * 64;
  const int fr = lane & 15;
  const int k8 = (lane >> 4) * 8;
  const int fq4 = (lane >> 4) * 4;

  f32x4 acc[4][4];
#pragma unroll
  for (int m = 0; m < 4; m++)
#pragma unroll
    for (int n = 0; n < 4; n++) acc[m][n] = (f32x4){0.f, 0.f, 0.f, 0.f};

  const unsigned short* Ab = A + (size_t)by * 128 * lda;
  const unsigned short* Bb = B + (size_t)btile * 128 * ldb;
  const int r0 = t >> 2;
  const int c0 = (t & 3) * 8;

  for (int kk = k0; kk < k1; kk += 32) {
    uint4 av0 = *(const uint4*)(Ab + (size_t)r0 * lda + kk + c0);
    uint4 av1 = *(const uint4*)(Ab + (size_t)(r0 + 64) * lda + kk + c0);
    uint4 bv0 = *(const uint4*)(Bb + (size_t)r0 * ldb + kk + c0);
    uint4 bv1 = *(const uint4*)(Bb + (size_t)(r0 + 64) * ldb + kk + c0);
    __syncthreads();
    *(uint4*)&As[r0][c0] = av0;
    *(uint4*)&As[r0 + 64][c0] = av1;
    *(uint4*)&Bs[r0][c0] = bv0;
    *(uint4*)&Bs[r0 + 64][c0] = bv1;
    __syncthreads();
    short8 af[4], bf[4];
#pragma unroll
    for (int m = 0; m < 4; m++) af[m] = *(const short8*)&As[wm + m * 16 + fr][k8];
#pragma unroll
    for (int n = 0; n < 4; n++) bf[n] = *(const short8*)&Bs[wn + n * 16 + fr][k8];
#pragma unroll
    for (int m = 0; m < 4; m++)
#pragma unroll
      for (int n = 0; n < 4; n++)
        acc[m][n] = __builtin_amdgcn_mfma_f32_16x16x32_bf16(af[m], bf[n], acc[m][n], 0, 0, 0);
  }

#pragma unroll
  for (int m = 0; m < 4; m++) {
#pragma unroll
    for (int n = 0; n < 4; n++) {
      int col = ccol0 + wn + n * 16 + fr;
      float bv = bias ? bias[col] : 0.f;
#pragma unroll
      for (int r = 0; r < 4; r++) {
        int row = by * 128 + wm + m * 16 + fq4 + r;
        float v = acc[m][n][r] * alpha + bv;
        if (relu) v = fmaxf(v, 0.f);
        size_t idx = (size_t)row * ldc + col;
        if (out_bf16) ((unsigned short*)Cout)[idx] = f2b(v);
        else ((float*)Cout)[idx] = v;
      }
    }
  }
}

// -------- per-row softmax stats over the band: stats[i] = (max, sumexp) --------
__global__ __launch_bounds__(256) void k_stats(const float* __restrict__ Lband,
                                               float2* __restrict__ stats) {
  int i = blockIdx.x * 4 + (threadIdx.x >> 6);
  int lane = threadIdx.x & 63;
  int ti = i >> 7;
  int cbase = (ti - 2) * 128;
  int jlo = i - 249; if (jlo < 0) jlo = 0;
  int jhi = i + 249; if (jhi > NSEQ - 1) jhi = NSEQ - 1;
  int clo = jlo - cbase, chi = jhi - cbase;
  const float* L = Lband + (size_t)i * 640;
  float m = -1e30f;
  for (int c = clo + lane; c <= chi; c += 64) m = fmaxf(m, L[c]);
  for (int off = 32; off; off >>= 1) m = fmaxf(m, __shfl_xor(m, off));
  float s = 0.f;
  for (int c = clo + lane; c <= chi; c += 64) s += __expf(L[c] - m);
  for (int off = 32; off; off >>= 1) s += __shfl_xor(s, off);
  if (lane == 0) stats[i] = make_float2(m, s);
}

// -------- build attT (bf16): attT[i][j] = att[j][i]; grid (5, 32) band tiles --------
__global__ __launch_bounds__(256) void k_build_attT(const float* __restrict__ Lband,
                                                    const float2* __restrict__ stats,
                                                    unsigned short* __restrict__ attT) {
  int ti = blockIdx.y;                 // i tile (attT rows)
  int tj = ti + (int)blockIdx.x - 2;   // j tile
  if (tj < 0 || tj >= 32) return;
  __shared__ unsigned short T[128][132];  // T[i_loc][j_loc]
  int t = threadIdx.x;
  int c0 = (ti - tj + 2) * 128;  // Lband col base for rows in tile tj reading i-tile ti
  int colg = (t & 31) * 4;       // i_loc
  for (int jj = t >> 5; jj < 128; jj += 8) {
    int j = tj * 128 + jj;
    float2 st = stats[j];
    float inv = 1.f / st.y;
    float4 v = *(const float4*)&Lband[(size_t)j * 640 + c0 + colg];
    float vv[4] = {v.x, v.y, v.z, v.w};
#pragma unroll
    for (int q = 0; q < 4; q++) {
      int i = ti * 128 + colg + q;
      int d = i - j;
      float a = (d < 250 && d > -250) ? __expf(vv[q] - st.x) * inv : 0.f;
      T[colg + q][jj] = f2b(a);
    }
  }
  __syncthreads();
  for (int ii = t >> 5; ii < 128; ii += 8) {
    size_t o = (size_t)(ti * 128 + ii) * NSEQ + tj * 128 + colg;
    *(ushort4*)(attT + o) = *(ushort4*)&T[ii][colg];
  }
}

// -------- write full fp32 att row (zeros outside band) --------
__global__ __launch_bounds__(256) void k_write_att(const float* __restrict__ Lband,
                                                   const float2* __restrict__ stats,
                                                   float* __restrict__ att) {
  int i = blockIdx.x;
  int ti = i >> 7, cbase = (ti - 2) * 128;
  int jlo = i - 249; if (jlo < 0) jlo = 0;
  int jhi = i + 249; if (jhi > NSEQ - 1) jhi = NSEQ - 1;
  float2 st = stats[i];
  float m = st.x, inv = 1.f / st.y;
  const float* L = Lband + (size_t)i * 640;
  float* arow = att + (size_t)i * NSEQ;
  for (int j0 = threadIdx.x * 4; j0 < NSEQ; j0 += 1024) {
    float ov[4];
#pragma unroll
    for (int q = 0; q < 4; q++) {
      int j = j0 + q;
      ov[q] = (j >= jlo && j <= jhi) ? __expf(L[j - cbase] - m) * inv : 0.f;
    }
    float4 o = make_float4(ov[0], ov[1], ov[2], ov[3]);
    *(float4*)(arow + j0) = o;
  }
}

// -------- residual + LayerNorm (ddof=1, eps on std) + accumulate into ysum --------
__global__ __launch_bounds__(256) void k_ln_res(const float* __restrict__ yo,
                                                const float* __restrict__ x,
                                                const float* __restrict__ g,
                                                const float* __restrict__ b,
                                                float* __restrict__ ysum, int first) {
  int i = blockIdx.x, t = threadIdx.x;
  float4 a = *(const float4*)(yo + (size_t)i * MDIM + t * 4);
  float4 xx = *(const float4*)(x + (size_t)i * MDIM + t * 4);
  float v[4] = {a.x + xx.x, a.y + xx.y, a.z + xx.z, a.w + xx.w};
  float s1 = v[0] + v[1] + v[2] + v[3];
  float s2 = v[0]*v[0] + v[1]*v[1] + v[2]*v[2] + v[3]*v[3];
  for (int off = 32; off; off >>= 1) { s1 += __shfl_xor(s1, off); s2 += __shfl_xor(s2, off); }
  __shared__ float red[8];
  int w = t >> 6, lane = t & 63;
  if (lane == 0) { red[w] = s1; red[4 + w] = s2; }
  __syncthreads();
  float S1 = red[0] + red[1] + red[2] + red[3];
  float S2 = red[4] + red[5] + red[6] + red[7];
  float mean = S1 * (1.f / 1024.f);
  float var = (S2 - S1 * mean) * (1.f / 1023.f);
  float rstd = 1.f / (sqrtf(var) + 1e-6f);
  float4 gg = *(const float4*)(g + t * 4);
  float4 bb = *(const float4*)(b + t * 4);
  float o[4];
  o[0] = gg.x * (v[0] - mean) * rstd + bb.x;
  o[1] = gg.y * (v[1] - mean) * rstd + bb.y;
  o[2] = gg.z * (v[2] - mean) * rstd + bb.z;
  o[3] = gg.w * (v[3] - mean) * rstd + bb.w;
  float* dst = ysum + (size_t)i * MDIM + t * 4;
  if (first) {
    *(float4*)dst = make_float4(o[0], o[1], o[2], o[3]);
  } else {
    float4 p = *(const float4*)dst;
    *(float4*)dst = make_float4(p.x + o[0], p.y + o[1], p.z + o[2], p.w + o[3]);
  }
}

// -------- final: LN(128, gkc/bkc) -> dot(kd_w) + kd_b -> sigmoid -> y_out[i] --------
__global__ __launch_bounds__(128) void k_final(const float* __restrict__ h3,
                                               const float* __restrict__ g,
                                               const float* __restrict__ b,
                                               const float* __restrict__ kdw,
                                               const float* __restrict__ kdb,
                                               float* __restrict__ yout) {
  int i = blockIdx.x, t = threadIdx.x;
  float v = h3[(size_t)i * 128 + t];
  float s1 = v, s2 = v * v;
  for (int off = 32; off; off >>= 1) { s1 += __shfl_xor(s1, off); s2 += __shfl_xor(s2, off); }
  __shared__ float red[4];
  int w = t >> 6, lane = t & 63;
  if (lane == 0) { red[w] = s1; red[2 + w] = s2; }
  __syncthreads();
  float S1 = red[0] + red[1], S2 = red[2] + red[3];
  float mean = S1 * (1.f / 128.f);
  float var = (S2 - S1 * mean) * (1.f / 127.f);
  float rstd = 1.f / (sqrtf(var) + 1e-6f);
  float ln = g[t] * (v - mean) * rstd + b[t];
  float p = ln * kdw[t];
  for (int off = 32; off; off >>= 1) p += __shfl_xor(p, off);
  __syncthreads();
  if (lane == 0) red[w] = p;
  __syncthreads();
  if (t == 0) {
    float z = red[0] + red[1] + kdb[0];
    yout[i] = 1.f / (1.f + __expf(-z));
  }
}

extern "C" void kernel_launch(void* const* d_in, const int* in_sizes, int n_in,
                              void* d_out, int out_size, void* d_ws, size_t ws_size,
                              hipStream_t stream) {
  const float* x1 = (const float*)d_in[0];
  const float* x2 = (const float*)d_in[1];
  const float* x3 = (const float*)d_in[2];
  const float* Wq = (const float*)d_in[3];
  const float* Wk = (const float*)d_in[4];
  const float* Wv = (const float*)d_in[5];
  const float* Wo = (const float*)d_in[6];
  const float* ka_w = (const float*)d_in[7];
  const float* ka_b = (const float*)d_in[8];
  const float* kb_w = (const float*)d_in[9];
  const float* kb_b = (const float*)d_in[10];
  const float* kc_w = (const float*)d_in[11];
  const float* kc_b = (const float*)d_in[12];
  const float* kd_w = (const float*)d_in[13];
  const float* kd_b = (const float*)d_in[14];
  const float* g13 = (const float*)d_in[15];
  const float* b13 = (const float*)d_in[16];
  const float* gkc = (const float*)d_in[17];
  const float* bkc = (const float*)d_in[18];

  float* y_out = (float*)d_out;
  float* att_out = y_out + NSEQ;                       // [4096,4096] fp32
  unsigned short* attT = (unsigned short*)att_out;     // scratch: attT bf16 lives here first

  // workspace layout (~93 MB)
  char* ws = (char*)d_ws;
  size_t off = 0;
  auto alloc = [&](size_t bytes) -> void* {
    void* p = ws + off;
    off += (bytes + 255) & ~(size_t)255;
    return p;
  };
  unsigned short* Wq_b = (unsigned short*)alloc(1024 * 1024 * 2);
  unsigned short* Wk_b = (unsigned short*)alloc(1024 * 1024 * 2);
  unsigned short* Wv_b = (unsigned short*)alloc(1024 * 1024 * 2);
  unsigned short* Wo_b = (unsigned short*)alloc(1024 * 1024 * 2);
  unsigned short* ka_wb = (unsigned short*)alloc(1024 * 1024 * 2);
  unsigned short* kb_wb = (unsigned short*)alloc(512 * 1024 * 2);
  unsigned short* kc_wb = (unsigned short*)alloc(128 * 512 * 2);
  unsigned short* Xb  = (unsigned short*)alloc((size_t)NSEQ * MDIM * 2);
  unsigned short* Qb  = (unsigned short*)alloc((size_t)NSEQ * MDIM * 2);
  unsigned short* Kb  = (unsigned short*)alloc((size_t)NSEQ * MDIM * 2);
  unsigned short* VTb = (unsigned short*)alloc((size_t)MDIM * NSEQ * 2);
  float* Lband = (float*)alloc((size_t)NSEQ * 640 * 4);
  float2* stats = (float2*)alloc((size_t)NSEQ * 8);
  unsigned short* yb = (unsigned short*)alloc((size_t)NSEQ * MDIM * 2);
  float* yo = (float*)alloc((size_t)NSEQ * MDIM * 4);
  float* ysum = (float*)alloc((size_t)NSEQ * MDIM * 4);
  // aliases into freed attention scratch for the MLP tail
  unsigned short* ysum_b = Qb;       // 8 MB
  unsigned short* h1b = Kb;          // 8 MB
  unsigned short* h2b = VTb;         // 4 MB used
  float* h3 = (float*)yb;            // 2 MB used

  auto gemm = [&](const unsigned short* A, int lda, const unsigned short* B, int ldb,
                  void* C, int ldc, int Mrows, int Ncols, int K, float alpha,
                  const float* bias, int relu, int out_bf16, int mode, int gridx) {
    dim3 g(gridx, Mrows / 128);
    k_gemm<<<g, 256, 0, stream>>>(A, lda, B, ldb, C, ldc, Ncols, K, alpha, bias, relu, out_bf16, mode);
  };

  // weights -> bf16
  k_cvt<<<1024, 256, 0, stream>>>(Wq, Wq_b, 262144);
  k_cvt<<<1024, 256, 0, stream>>>(Wk, Wk_b, 262144);
  k_cvt<<<1024, 256, 0, stream>>>(Wv, Wv_b, 262144);
  k_cvt<<<1024, 256, 0, stream>>>(Wo, Wo_b, 262144);
  k_cvt<<<1024, 256, 0, stream>>>(ka_w, ka_wb, 262144);
  k_cvt<<<512, 256, 0, stream>>>(kb_w, kb_wb, 131072);
  k_cvt<<<64, 256, 0, stream>>>(kc_w, kc_wb, 16384);

  // process x1 LAST so its attT/att can live in d_out's att region
  const float* xs[3] = {x2, x3, x1};
  for (int s = 0; s < 3; s++) {
    const float* xp = xs[s];
    k_cvt<<<4096, 256, 0, stream>>>(xp, Xb, 1048576);
    gemm(Xb, 1024, Wq_b, 1024, Qb, 1024, NSEQ, 1024, 1024, 0.06f, nullptr, 0, 1, 0, 8);
    gemm(Xb, 1024, Wk_b, 1024, Kb, 1024, NSEQ, 1024, 1024, 1.f, nullptr, 0, 1, 0, 8);
    gemm(Wv_b, 1024, Xb, 1024, VTb, NSEQ, 1024, NSEQ, 1024, 1.f, nullptr, 0, 1, 0, 32);
    // banded logits: Lband fp32
    gemm(Qb, 1024, Kb, 1024, Lband, 640, NSEQ, NSEQ, 1024, 1.f, nullptr, 0, 0, 1, 5);
    k_stats<<<1024, 256, 0, stream>>>(Lband, stats);
    k_build_attT<<<dim3(5, 32), 256, 0, stream>>>(Lband, stats, attT);
    // y = attT @ V  (banded K), bf16 out
    gemm(attT, NSEQ, VTb, NSEQ, yb, 1024, NSEQ, 1024, NSEQ, 1.f, nullptr, 0, 1, 2, 8);
    // yo = y @ Wo^T, fp32
    gemm(yb, 1024, Wo_b, 1024, yo, 1024, NSEQ, 1024, 1024, 1.f, nullptr, 0, 0, 0, 8);
    k_ln_res<<<4096, 256, 0, stream>>>(yo, xp, g13, b13, ysum, s == 0 ? 1 : 0);
    if (s == 2) k_write_att<<<4096, 256, 0, stream>>>(Lband, stats, att_out);
  }

  // MLP head
  k_cvt<<<4096, 256, 0, stream>>>(ysum, ysum_b, 1048576);
  gemm(ysum_b, 1024, ka_wb, 1024, h1b, 1024, NSEQ, 1024, 1024, 1.f, ka_b, 0, 1, 0, 8);
  gemm(h1b, 1024, kb_wb, 1024, h2b, 512, NSEQ, 512, 1024, 1.f, kb_b, 0, 1, 0, 4);
  gemm(h2b, 512, kc_wb, 512, h3, 128, NSEQ, 128, 512, 1.f, kc_b, 1, 0, 0, 1);
  k_final<<<4096, 128, 0, stream>>>(h3, gkc, bkc, kd_w, kd_b, y_out);
}

// Round 2
// 556.677 us; speedup vs baseline: 1.5539x; 1.5539x over previous
//
#include <hip/hip_runtime.h>
#include <hip/hip_bf16.h>
#include <cstdint>
#include <cstddef>

// Problem constants
#define NSEQ 4096
#define MDIM 1024
// band: |i-j| < 250 -> row-tile ti needs col-tiles [ti-2, ti+2]
// banded layout (both Lband fp32 and attT bf16): row i, col c = j - 128*((i>>7)-2), width 640

typedef __attribute__((ext_vector_type(8))) short short8;
typedef __attribute__((ext_vector_type(4))) float f32x4;

typedef const __attribute__((address_space(1))) void gvoid_t;
typedef __attribute__((address_space(3))) void lvoid_t;

__device__ __forceinline__ unsigned short f2b(float x) {
  union { float f; unsigned int u; } a; a.f = x;
  unsigned int r = (a.u + 0x7fffu + ((a.u >> 16) & 1u)) >> 16;
  return (unsigned short)r;
}
__device__ __forceinline__ float b2f(unsigned short u) {
  union { float f; unsigned int u32; } a; a.u32 = ((unsigned int)u) << 16;
  return a.f;
}

// -------- fp32 -> bf16 convert (n4 = n/4) --------
__global__ __launch_bounds__(256) void k_cvt(const float* __restrict__ in,
                                             unsigned short* __restrict__ out, int n4) {
  int idx = blockIdx.x * 256 + threadIdx.x;
  if (idx >= n4) return;
  float4 v = *(const float4*)(in + (size_t)idx * 4);
  ushort4 o;
  o.x = f2b(v.x); o.y = f2b(v.y); o.z = f2b(v.z); o.w = f2b(v.w);
  *(ushort4*)(out + (size_t)idx * 4) = o;
}

// -------- GEMM: C = alpha*(A @ B^T) + bias, A[M,K] bf16, B[N,K] bf16 --------
// global_load_lds (16B) staging, 128x128 tile, BK=32.
// LDS chunk swizzle: LDS[r][c] holds global chunk (c - (r>>1))&3  (keeps frag
// ds_read_b128 at free 2-way bank aliasing, store needs no padding).
// mode 0: plain batched. grid = (Ntiles, Mtiles)
// mode 1: banded logits (batched, 3 streams of 32 row-tiles). grid = (5, 96).
//         col tile = (by&31)+bx-2 within stream by>>5; C is Lband[12288,640].
// mode 2: attT(banded[4096,640] per stream, lda=640) @ V. grid = (8, 96).
//         K window [max(ti-2,0)*128, min(ti+3,32)*128), B col base stream*4096.
__global__ __launch_bounds__(256) void k_gemm(
    const unsigned short* __restrict__ A, int lda,
    const unsigned short* __restrict__ B, int ldb,
    void* __restrict__ Cout, int ldc,
    int K, float alpha,
    const float* __restrict__ bias, int relu, int out_bf16, int mode,
    const unsigned short* __restrict__ A1, const unsigned short* __restrict__ A2) {
  __shared__ unsigned short As[128 * 32];
  __shared__ unsigned short Bs[128 * 32];
  int by = blockIdx.y;
  int bx = blockIdx.x;
  const unsigned short* Ab;
  const unsigned short* Bb;
  int k0 = 0, k1 = K, a_koff = 0;
  int crow0 = by * 128, ccol0 = bx * 128;
  if (mode == 0) {
    Ab = A + (size_t)by * 128 * lda;
    Bb = B + (size_t)bx * 128 * ldb;
  } else if (mode == 1) {
    int s = by >> 5, ti = by & 31;
    int bt = ti + bx - 2;
    if (bt < 0 || bt >= 32) return;
    Ab = A + (size_t)by * 128 * lda;
    Bb = B + (size_t)(s * 32 + bt) * 128 * ldb;
  } else {
    int s = by >> 5, ti = by & 31;
    const unsigned short* Abase = (s == 0) ? A : ((s == 1) ? A1 : A2);
    Ab = Abase + (size_t)ti * 128 * lda;  // lda = 640
    int lo = ti - 2; if (lo < 0) lo = 0;
    int hi = ti + 3; if (hi > 32) hi = 32;
    k0 = lo * 128; k1 = hi * 128;
    a_koff = (ti - 2) * 128;
    Bb = B + (size_t)bx * 128 * ldb + s * NSEQ;
  }

  const int t = threadIdx.x;
  const int l = t & 63;
  const int w = t >> 6;
  const int sr = l >> 2;       // staging row within 16-row segment
  const int c_lds = l & 3;     // staging chunk slot
  const int fr = l & 15;
  const int quad = l >> 4;
  const int wm = (w >> 1) * 64;
  const int wn = (w & 1) * 64;
  const int fq4 = quad * 4;

  f32x4 acc[4][4];
#pragma unroll
  for (int m = 0; m < 4; m++)
#pragma unroll
    for (int n = 0; n < 4; n++) acc[m][n] = (f32x4){0.f, 0.f, 0.f, 0.f};

  const int ra0 = w * 32 + sr;      // this lane's A/B staging rows
  const int ra1 = ra0 + 16;
  const int cg0 = (c_lds - (ra0 >> 1)) & 3;  // global chunk fetched for slot c_lds
  const int cg1 = (c_lds - (ra1 >> 1)) & 3;

  for (int kk = k0; kk < k1; kk += 32) {
    __syncthreads();
    int ka = kk - a_koff;
    __builtin_amdgcn_global_load_lds(
        (gvoid_t*)(Ab + (size_t)ra0 * lda + ka + cg0 * 8),
        (lvoid_t*)(As + w * 1024 + l * 8), 16, 0, 0);
    __builtin_amdgcn_global_load_lds(
        (gvoid_t*)(Ab + (size_t)ra1 * lda + ka + cg1 * 8),
        (lvoid_t*)(As + w * 1024 + 512 + l * 8), 16, 0, 0);
    __builtin_amdgcn_global_load_lds(
        (gvoid_t*)(Bb + (size_t)ra0 * ldb + kk + cg0 * 8),
        (lvoid_t*)(Bs + w * 1024 + l * 8), 16, 0, 0);
    __builtin_amdgcn_global_load_lds(
        (gvoid_t*)(Bb + (size_t)ra1 * ldb + kk + cg1 * 8),
        (lvoid_t*)(Bs + w * 1024 + 512 + l * 8), 16, 0, 0);
    __syncthreads();
    short8 af[4], bf[4];
#pragma unroll
    for (int m = 0; m < 4; m++) {
      int r = wm + m * 16 + fr;
      af[m] = *(const short8*)(As + r * 32 + (((quad + (r >> 1)) & 3) * 8));
    }
#pragma unroll
    for (int n = 0; n < 4; n++) {
      int r = wn + n * 16 + fr;
      bf[n] = *(const short8*)(Bs + r * 32 + (((quad + (r >> 1)) & 3) * 8));
    }
#pragma unroll
    for (int m = 0; m < 4; m++)
#pragma unroll
      for (int n = 0; n < 4; n++)
        acc[m][n] = __builtin_amdgcn_mfma_f32_16x16x32_bf16(af[m], bf[n], acc[m][n], 0, 0, 0);
  }

#pragma unroll
  for (int m = 0; m < 4; m++) {
#pragma unroll
    for (int n = 0; n < 4; n++) {
      int col = ccol0 + wn + n * 16 + fr;
      float bv = bias ? bias[col] : 0.f;
#pragma unroll
      for (int r = 0; r < 4; r++) {
        int row = crow0 + wm + m * 16 + fq4 + r;
        float v = acc[m][n][r] * alpha + bv;
        if (relu) v = fmaxf(v, 0.f);
        size_t idx = (size_t)row * ldc + col;
        if (out_bf16) ((unsigned short*)Cout)[idx] = f2b(v);
        else ((float*)Cout)[idx] = v;
      }
    }
  }
}

// -------- per-row softmax stats over the band (batched 3 streams) --------
__global__ __launch_bounds__(256) void k_stats(const float* __restrict__ Lband,
                                               float2* __restrict__ stats) {
  int ig = blockIdx.x * 4 + (threadIdx.x >> 6);   // global row 0..12287
  int lane = threadIdx.x & 63;
  int i = ig & 4095;
  int ti = i >> 7;
  int cbase = (ti - 2) * 128;
  int jlo = i - 249; if (jlo < 0) jlo = 0;
  int jhi = i + 249; if (jhi > NSEQ - 1) jhi = NSEQ - 1;
  int clo = jlo - cbase, chi = jhi - cbase;
  const float* L = Lband + (size_t)ig * 640;
  float m = -1e30f;
  for (int c = clo + lane; c <= chi; c += 64) m = fmaxf(m, L[c]);
  for (int off = 32; off; off >>= 1) m = fmaxf(m, __shfl_xor(m, off));
  float s = 0.f;
  for (int c = clo + lane; c <= chi; c += 64) s += __expf(L[c] - m);
  for (int off = 32; off; off >>= 1) s += __shfl_xor(s, off);
  if (lane == 0) stats[ig] = make_float2(m, s);
}

// -------- build banded attT (bf16): attT_s[i][j - 128*((i>>7)-2)] = att[j][i] --------
__global__ __launch_bounds__(256) void k_build_attT(const float* __restrict__ Lband,
                                                    const float2* __restrict__ stats,
                                                    unsigned short* __restrict__ t0,
                                                    unsigned short* __restrict__ t1,
                                                    unsigned short* __restrict__ t2) {
  int byy = blockIdx.y;
  int s = byy >> 5, ti = byy & 31;       // i tile (attT rows), local
  int tj = ti + (int)blockIdx.x - 2;     // j tile
  if (tj < 0 || tj >= 32) return;
  unsigned short* dst = (s == 0) ? t0 : ((s == 1) ? t1 : t2);
  __shared__ unsigned short T[128][132];  // T[i_loc][j_loc]
  int t = threadIdx.x;
  int c0 = (ti - tj + 2) * 128;  // Lband col base for rows j reading i-tile ti
  int colg = (t & 31) * 4;       // i_loc
  for (int jj = t >> 5; jj < 128; jj += 8) {
    int jg = s * NSEQ + tj * 128 + jj;
    float2 st = stats[jg];
    float inv = 1.f / st.y;
    float4 v = *(const float4*)&Lband[(size_t)jg * 640 + c0 + colg];
    float vv[4] = {v.x, v.y, v.z, v.w};
#pragma unroll
    for (int q = 0; q < 4; q++) {
      int i = ti * 128 + colg + q;
      int d = i - (tj * 128 + jj);
      float a = (d < 250 && d > -250) ? __expf(vv[q] - st.x) * inv : 0.f;
      T[colg + q][jj] = f2b(a);
    }
  }
  __syncthreads();
  int jb0 = (tj - ti + 2) * 128;  // banded col base in attT rows of tile ti
  for (int ii = t >> 5; ii < 128; ii += 8) {
    size_t o = (size_t)(ti * 128 + ii) * 640 + jb0 + colg;
    *(ushort4*)(dst + o) = *(ushort4*)&T[ii][colg];
  }
}

// -------- write full fp32 att (stream 0 / x1), zeros outside band --------
__global__ __launch_bounds__(256) void k_write_att(const float* __restrict__ Lband,
                                                   const float2* __restrict__ stats,
                                                   float* __restrict__ att) {
  int i = blockIdx.x;
  int ti = i >> 7, cbase = (ti - 2) * 128;
  int jlo = i - 249; if (jlo < 0) jlo = 0;
  int jhi = i + 249; if (jhi > NSEQ - 1) jhi = NSEQ - 1;
  float2 st = stats[i];
  float m = st.x, inv = 1.f / st.y;
  const float* L = Lband + (size_t)i * 640;
  float* arow = att + (size_t)i * NSEQ;
  for (int j0 = threadIdx.x * 4; j0 < NSEQ; j0 += 1024) {
    float ov[4];
#pragma unroll
    for (int q = 0; q < 4; q++) {
      int j = j0 + q;
      ov[q] = (j >= jlo && j <= jhi) ? __expf(L[j - cbase] - m) * inv : 0.f;
    }
    *(float4*)(arow + j0) = make_float4(ov[0], ov[1], ov[2], ov[3]);
  }
}

// -------- residual + LayerNorm (ddof=1, eps on std) for 3 streams, sum -> bf16 --------
__global__ __launch_bounds__(256) void k_ln3(const unsigned short* __restrict__ yo,
                                             const float* __restrict__ x1,
                                             const float* __restrict__ x2,
                                             const float* __restrict__ x3,
                                             const float* __restrict__ g,
                                             const float* __restrict__ b,
                                             unsigned short* __restrict__ ysum_b) {
  int i = blockIdx.x, t = threadIdx.x;
  int w = t >> 6, lane = t & 63;
  __shared__ float red[8];
  const float* xs[3] = {x1, x2, x3};
  float4 gg = *(const float4*)(g + t * 4);
  float4 bb = *(const float4*)(b + t * 4);
  float acc[4] = {0.f, 0.f, 0.f, 0.f};
  for (int s = 0; s < 3; s++) {
    ushort4 yv = *(const ushort4*)(yo + ((size_t)(s * NSEQ + i)) * MDIM + t * 4);
    float4 xx = *(const float4*)(xs[s] + (size_t)i * MDIM + t * 4);
    float v[4] = {b2f(yv.x) + xx.x, b2f(yv.y) + xx.y, b2f(yv.z) + xx.z, b2f(yv.w) + xx.w};
    float s1 = v[0] + v[1] + v[2] + v[3];
    float s2 = v[0]*v[0] + v[1]*v[1] + v[2]*v[2] + v[3]*v[3];
    for (int off = 32; off; off >>= 1) { s1 += __shfl_xor(s1, off); s2 += __shfl_xor(s2, off); }
    __syncthreads();
    if (lane == 0) { red[w] = s1; red[4 + w] = s2; }
    __syncthreads();
    float S1 = red[0] + red[1] + red[2] + red[3];
    float S2 = red[4] + red[5] + red[6] + red[7];
    float mean = S1 * (1.f / 1024.f);
    float var = (S2 - S1 * mean) * (1.f / 1023.f);
    float rstd = 1.f / (sqrtf(var) + 1e-6f);
    acc[0] += gg.x * (v[0] - mean) * rstd + bb.x;
    acc[1] += gg.y * (v[1] - mean) * rstd + bb.y;
    acc[2] += gg.z * (v[2] - mean) * rstd + bb.z;
    acc[3] += gg.w * (v[3] - mean) * rstd + bb.w;
  }
  ushort4 o;
  o.x = f2b(acc[0]); o.y = f2b(acc[1]); o.z = f2b(acc[2]); o.w = f2b(acc[3]);
  *(ushort4*)(ysum_b + (size_t)i * MDIM + t * 4) = o;
}

// -------- final: LN(128, gkc/bkc) -> dot(kd_w) + kd_b -> sigmoid --------
__global__ __launch_bounds__(128) void k_final(const float* __restrict__ h3,
                                               const float* __restrict__ g,
                                               const float* __restrict__ b,
                                               const float* __restrict__ kdw,
                                               const float* __restrict__ kdb,
                                               float* __restrict__ yout) {
  int i = blockIdx.x, t = threadIdx.x;
  float v = h3[(size_t)i * 128 + t];
  float s1 = v, s2 = v * v;
  for (int off = 32; off; off >>= 1) { s1 += __shfl_xor(s1, off); s2 += __shfl_xor(s2, off); }
  __shared__ float red[4];
  int w = t >> 6, lane = t & 63;
  if (lane == 0) { red[w] = s1; red[2 + w] = s2; }
  __syncthreads();
  float S1 = red[0] + red[1], S2 = red[2] + red[3];
  float mean = S1 * (1.f / 128.f);
  float var = (S2 - S1 * mean) * (1.f / 127.f);
  float rstd = 1.f / (sqrtf(var) + 1e-6f);
  float ln = g[t] * (v - mean) * rstd + b[t];
  float p = ln * kdw[t];
  for (int off = 32; off; off >>= 1) p += __shfl_xor(p, off);
  __syncthreads();
  if (lane == 0) red[w] = p;
  __syncthreads();
  if (t == 0) {
    float z = red[0] + red[1] + kdb[0];
    yout[i] = 1.f / (1.f + __expf(-z));
  }
}

extern "C" void kernel_launch(void* const* d_in, const int* in_sizes, int n_in,
                              void* d_out, int out_size, void* d_ws, size_t ws_size,
                              hipStream_t stream) {
  const float* x1 = (const float*)d_in[0];
  const float* x2 = (const float*)d_in[1];
  const float* x3 = (const float*)d_in[2];
  const float* Wq = (const float*)d_in[3];
  const float* Wk = (const float*)d_in[4];
  const float* Wv = (const float*)d_in[5];
  const float* Wo = (const float*)d_in[6];
  const float* ka_w = (const float*)d_in[7];
  const float* ka_b = (const float*)d_in[8];
  const float* kb_w = (const float*)d_in[9];
  const float* kb_b = (const float*)d_in[10];
  const float* kc_w = (const float*)d_in[11];
  const float* kc_b = (const float*)d_in[12];
  const float* kd_w = (const float*)d_in[13];
  const float* kd_b = (const float*)d_in[14];
  const float* g13 = (const float*)d_in[15];
  const float* b13 = (const float*)d_in[16];
  const float* gkc = (const float*)d_in[17];
  const float* bkc = (const float*)d_in[18];

  float* y_out = (float*)d_out;
  float* att_out = y_out + NSEQ;  // [4096,4096] fp32

  char* ws = (char*)d_ws;
  size_t off = 0;
  auto alloc = [&](size_t bytes) -> void* {
    void* p = ws + off;
    off += (bytes + 255) & ~(size_t)255;
    return p;
  };
  const size_t NM = (size_t)3 * NSEQ * MDIM;  // 12.6M elems
  unsigned short* Wq_b = (unsigned short*)alloc(1024 * 1024 * 2);
  unsigned short* Wk_b = (unsigned short*)alloc(1024 * 1024 * 2);
  unsigned short* Wv_b = (unsigned short*)alloc(1024 * 1024 * 2);
  unsigned short* Wo_b = (unsigned short*)alloc(1024 * 1024 * 2);
  unsigned short* ka_wb = (unsigned short*)alloc(1024 * 1024 * 2);
  unsigned short* kb_wb = (unsigned short*)alloc(512 * 1024 * 2);
  unsigned short* kc_wb = (unsigned short*)alloc(128 * 512 * 2);
  unsigned short* Xb = (unsigned short*)alloc(NM * 2);   // later: yb, then h3 (fp32 2MB)
  unsigned short* Qb = (unsigned short*)alloc(NM * 2);   // later: yo (bf16), then h2b
  unsigned short* Kb = (unsigned short*)alloc(NM * 2);   // later: ysum_b (8MB)
  unsigned short* VTb = (unsigned short*)alloc(NM * 2);  // later: h1b (8MB)
  float* Lband = (float*)alloc((size_t)3 * NSEQ * 640 * 4);
  float2* stats = (float2*)alloc((size_t)3 * NSEQ * 8);
  unsigned short* aT0 = (unsigned short*)alloc((size_t)NSEQ * 640 * 2);
  unsigned short* aT1 = (unsigned short*)alloc((size_t)NSEQ * 640 * 2);
  unsigned short* aT2 = (unsigned short*)alloc((size_t)NSEQ * 640 * 2);
  // aliases (lifetimes disjoint)
  unsigned short* yb = Xb;
  unsigned short* yo = Qb;
  unsigned short* ysum_b = Kb;
  unsigned short* h1b = VTb;
  unsigned short* h2b = Qb;
  float* h3 = (float*)Xb;

  auto gemm = [&](const unsigned short* A, int lda, const unsigned short* B, int ldb,
                  void* C, int ldc, int K, float alpha, const float* bias,
                  int relu, int out_bf16, int mode, int gx, int gy,
                  const unsigned short* A1 = nullptr, const unsigned short* A2 = nullptr) {
    k_gemm<<<dim3(gx, gy), 256, 0, stream>>>(A, lda, B, ldb, C, ldc, K, alpha,
                                             bias, relu, out_bf16, mode, A1, A2);
  };

  // weights -> bf16
  k_cvt<<<1024, 256, 0, stream>>>(Wq, Wq_b, 262144);
  k_cvt<<<1024, 256, 0, stream>>>(Wk, Wk_b, 262144);
  k_cvt<<<1024, 256, 0, stream>>>(Wv, Wv_b, 262144);
  k_cvt<<<1024, 256, 0, stream>>>(Wo, Wo_b, 262144);
  k_cvt<<<1024, 256, 0, stream>>>(ka_w, ka_wb, 262144);
  k_cvt<<<512, 256, 0, stream>>>(kb_w, kb_wb, 131072);
  k_cvt<<<64, 256, 0, stream>>>(kc_w, kc_wb, 16384);
  // x1..x3 -> Xb batched [12288,1024]
  k_cvt<<<4096, 256, 0, stream>>>(x1, Xb, 1048576);
  k_cvt<<<4096, 256, 0, stream>>>(x2, Xb + (size_t)NSEQ * MDIM, 1048576);
  k_cvt<<<4096, 256, 0, stream>>>(x3, Xb + (size_t)2 * NSEQ * MDIM, 1048576);

  // batched projections (M=12288)
  gemm(Xb, 1024, Wq_b, 1024, Qb, 1024, 1024, 0.06f, nullptr, 0, 1, 0, 8, 96);
  gemm(Xb, 1024, Wk_b, 1024, Kb, 1024, 1024, 1.f, nullptr, 0, 1, 0, 8, 96);
  // VT[1024,12288] = Wv @ X^T
  gemm(Wv_b, 1024, Xb, 1024, VTb, 3 * NSEQ, 1024, 1.f, nullptr, 0, 1, 0, 96, 8);
  // banded logits, all streams: Lband[12288,640] fp32
  gemm(Qb, 1024, Kb, 1024, Lband, 640, 1024, 1.f, nullptr, 0, 0, 1, 5, 96);
  k_stats<<<3072, 256, 0, stream>>>(Lband, stats);
  k_build_attT<<<dim3(5, 96), 256, 0, stream>>>(Lband, stats, aT0, aT1, aT2);
  // y[12288,1024] = attT @ V (banded K), bf16 into yb
  gemm(aT0, 640, VTb, 3 * NSEQ, yb, 1024, NSEQ, 1.f, nullptr, 0, 1, 2, 8, 96, aT1, aT2);
  k_write_att<<<4096, 256, 0, stream>>>(Lband, stats, att_out);
  // yo = y @ Wo^T (bf16)
  gemm(yb, 1024, Wo_b, 1024, yo, 1024, 1024, 1.f, nullptr, 0, 1, 0, 8, 96);
  // residual + LN + 3-stream sum -> bf16
  k_ln3<<<4096, 256, 0, stream>>>(yo, x1, x2, x3, g13, b13, ysum_b);

  // MLP head (M=4096)
  gemm(ysum_b, 1024, ka_wb, 1024, h1b, 1024, 1024, 1.f, ka_b, 0, 1, 0, 8, 32);
  gemm(h1b, 1024, kb_wb, 1024, h2b, 512, 1024, 1.f, kb_b, 0, 1, 0, 4, 32);
  gemm(h2b, 512, kc_wb, 512, h3, 128, 512, 1.f, kc_b, 1, 0, 0, 1, 32);
  k_final<<<4096, 128, 0, stream>>>(h3, gkc, bkc, kd_w, kd_b, y_out);
}

// Round 3
// 497.649 us; speedup vs baseline: 1.7382x; 1.1186x over previous
//
#include <hip/hip_runtime.h>
#include <hip/hip_bf16.h>
#include <cstdint>
#include <cstddef>

// Problem constants
#define NSEQ 4096
#define MDIM 1024
// band: |i-j| < 250 -> row-tile ti needs col-tiles [ti-2, ti+2]
// banded layout (Lband fp32, attT bf16): row i, col c = j - 128*((i>>7)-2), width 640

typedef __attribute__((ext_vector_type(8))) short short8;
typedef __attribute__((ext_vector_type(4))) float f32x4;

typedef const __attribute__((address_space(1))) void gvoid_t;
typedef __attribute__((address_space(3))) void lvoid_t;

__device__ __forceinline__ unsigned short f2b(float x) {
  union { float f; unsigned int u; } a; a.f = x;
  unsigned int r = (a.u + 0x7fffu + ((a.u >> 16) & 1u)) >> 16;
  return (unsigned short)r;
}
__device__ __forceinline__ float b2f(unsigned short u) {
  union { float f; unsigned int u32; } a; a.u32 = ((unsigned int)u) << 16;
  return a.f;
}

// -------- merged weight cvt: 7 tensors -> contiguous bf16 dst --------
__global__ __launch_bounds__(256) void k_cvt_w(
    const float* __restrict__ s0, const float* __restrict__ s1,
    const float* __restrict__ s2, const float* __restrict__ s3,
    const float* __restrict__ s4, const float* __restrict__ s5,
    const float* __restrict__ s6, unsigned short* __restrict__ dst) {
  int idx = blockIdx.x * 256 + threadIdx.x;  // chunk of 4
  const float* src; int local;
  if (idx < 1310720) {  // 5 x 2^18
    int seg = idx >> 18; local = idx & 262143;
    src = (seg == 0) ? s0 : (seg == 1) ? s1 : (seg == 2) ? s2 : (seg == 3) ? s3 : s4;
  } else if (idx < 1441792) { src = s5; local = idx - 1310720; }
  else { src = s6; local = idx - 1441792; }
  float4 v = *(const float4*)(src + (size_t)local * 4);
  ushort4 o; o.x = f2b(v.x); o.y = f2b(v.y); o.z = f2b(v.z); o.w = f2b(v.w);
  *(ushort4*)(dst + (size_t)idx * 4) = o;
}

// -------- x1..x3 -> contiguous bf16 [12288,1024] --------
__global__ __launch_bounds__(256) void k_cvt3(
    const float* __restrict__ s0, const float* __restrict__ s1,
    const float* __restrict__ s2, unsigned short* __restrict__ dst) {
  int idx = blockIdx.x * 256 + threadIdx.x;  // chunk of 4, 3*2^20 total
  int seg = idx >> 20, local = idx & 1048575;
  const float* src = (seg == 0) ? s0 : (seg == 1) ? s1 : s2;
  float4 v = *(const float4*)(src + (size_t)local * 4);
  ushort4 o; o.x = f2b(v.x); o.y = f2b(v.y); o.z = f2b(v.z); o.w = f2b(v.w);
  *(ushort4*)(dst + (size_t)idx * 4) = o;
}

// -------- GEMM: C = alpha*(A @ B^T) + bias, A[M,K] bf16, B[N,K] bf16 --------
// BK=64, global_load_lds 16B staging, 8-slot chunk swizzle (slot=(chunk+(row>>1))&7).
// grid.x = M row-tiles (multiple of 8 -> same-A blocks co-locate per XCD), grid.y = N tiles.
// mode 0: plain. mode 3: merged QK (by<8 -> Cout*alpha, by>=8 -> Cout2*1).
// mode 1: banded logits, grid (96,5): row tile bx (s=bx>>5,ti=bx&31), col tile ti+by-2.
// mode 2: attT(banded,lda=640) @ VT, grid (96,8): K window [max(ti-2,0)*128,min(ti+3,32)*128).
__global__ __launch_bounds__(256) void k_gemm(
    const unsigned short* __restrict__ A, int lda,
    const unsigned short* __restrict__ B, int ldb,
    void* __restrict__ Cout, void* __restrict__ Cout2, int ldc,
    int K, float alpha,
    const float* __restrict__ bias, int relu, int out_bf16, int mode,
    const unsigned short* __restrict__ A1, const unsigned short* __restrict__ A2) {
  __shared__ unsigned short smem[2 * 128 * 64];
  unsigned short* As = smem;
  unsigned short* Bs = smem + 128 * 64;
  int bx = blockIdx.x, by = blockIdx.y;
  const unsigned short* Ab;
  const unsigned short* Bb;
  void* Cdst = Cout;
  float aeff = alpha;
  int k0 = 0, k1 = K, a_koff = 0;
  int crow0 = bx * 128, ccol0 = by * 128;
  if (mode == 0) {
    Ab = A + (size_t)bx * 128 * lda;
    Bb = B + (size_t)by * 128 * ldb;
  } else if (mode == 3) {
    Ab = A + (size_t)bx * 128 * lda;
    Bb = B + (size_t)by * 128 * ldb;
    if (by >= 8) { Cdst = Cout2; aeff = 1.f; }
    ccol0 = (by & 7) * 128;
  } else if (mode == 1) {
    int s = bx >> 5, ti = bx & 31;
    int bt = ti + by - 2;
    if (bt < 0 || bt >= 32) return;
    Ab = A + (size_t)bx * 128 * lda;
    Bb = B + (size_t)(s * 32 + bt) * 128 * ldb;
  } else {  // mode 2
    int s = bx >> 5, ti = bx & 31;
    const unsigned short* Abase = (s == 0) ? A : ((s == 1) ? A1 : A2);
    Ab = Abase + (size_t)ti * 128 * lda;  // lda = 640
    int lo = ti - 2; if (lo < 0) lo = 0;
    int hi = ti + 3; if (hi > 32) hi = 32;
    k0 = lo * 128; k1 = hi * 128;
    a_koff = (ti - 2) * 128;
    Bb = B + (size_t)by * 128 * ldb + s * NSEQ;
  }

  const int t = threadIdx.x;
  const int l = t & 63;
  const int w = t >> 6;
  const int fr = l & 15;
  const int quad = l >> 4;
  const int wm = (w >> 1) * 64;
  const int wn = (w & 1) * 64;
  const int fq4 = quad * 4;

  // staging: 4 insts per matrix per wave; inst j covers rows w*32+j*8 .. +7
  int srow[4], scg[4], sloff[4];
#pragma unroll
  for (int j = 0; j < 4; j++) {
    srow[j] = w * 32 + j * 8 + (l >> 3);
    scg[j] = ((l & 7) - (srow[j] >> 1)) & 7;
    sloff[j] = (w * 32 + j * 8) * 64 + l * 8;
  }

  f32x4 acc[4][4];
#pragma unroll
  for (int m = 0; m < 4; m++)
#pragma unroll
    for (int n = 0; n < 4; n++) acc[m][n] = (f32x4){0.f, 0.f, 0.f, 0.f};

  for (int kk = k0; kk < k1; kk += 64) {
    int ka = kk - a_koff;
    __syncthreads();
#pragma unroll
    for (int j = 0; j < 4; j++)
      __builtin_amdgcn_global_load_lds(
          (gvoid_t*)(Ab + (size_t)srow[j] * lda + ka + scg[j] * 8),
          (lvoid_t*)(As + sloff[j]), 16, 0, 0);
#pragma unroll
    for (int j = 0; j < 4; j++)
      __builtin_amdgcn_global_load_lds(
          (gvoid_t*)(Bb + (size_t)srow[j] * ldb + kk + scg[j] * 8),
          (lvoid_t*)(Bs + sloff[j]), 16, 0, 0);
    __syncthreads();
#pragma unroll
    for (int s = 0; s < 2; s++) {
      short8 af[4], bf[4];
#pragma unroll
      for (int m = 0; m < 4; m++) {
        int r = wm + m * 16 + fr;
        int slot = ((s * 4 + quad) + (r >> 1)) & 7;
        af[m] = *(const short8*)(As + r * 64 + slot * 8);
      }
#pragma unroll
      for (int n = 0; n < 4; n++) {
        int r = wn + n * 16 + fr;
        int slot = ((s * 4 + quad) + (r >> 1)) & 7;
        bf[n] = *(const short8*)(Bs + r * 64 + slot * 8);
      }
#pragma unroll
      for (int m = 0; m < 4; m++)
#pragma unroll
        for (int n = 0; n < 4; n++)
          acc[m][n] = __builtin_amdgcn_mfma_f32_16x16x32_bf16(af[m], bf[n], acc[m][n], 0, 0, 0);
    }
  }

  if (out_bf16) {
    // stage C tile (128x128 bf16) in LDS with chunk swizzle, then coalesced 16B stores
    __syncthreads();
#pragma unroll
    for (int m = 0; m < 4; m++) {
#pragma unroll
      for (int n = 0; n < 4; n++) {
        int colb = wn + n * 16 + fr;
        float bv = bias ? bias[ccol0 + colb] : 0.f;
#pragma unroll
        for (int r = 0; r < 4; r++) {
          int row = wm + m * 16 + fq4 + r;
          float v = acc[m][n][r] * aeff + bv;
          if (relu) v = fmaxf(v, 0.f);
          int cc = ((colb >> 3) + row) & 15;
          smem[row * 128 + cc * 8 + (colb & 7)] = f2b(v);
        }
      }
    }
    __syncthreads();
    unsigned short* Cp = (unsigned short*)Cdst;
    for (int i = t; i < 2048; i += 256) {
      int row = i >> 4, lc = i & 15;
      int pc = (lc + row) & 15;
      uint4 v = *(const uint4*)(smem + row * 128 + pc * 8);
      *(uint4*)(Cp + (size_t)(crow0 + row) * ldc + ccol0 + lc * 8) = v;
    }
  } else {
    float* Cp = (float*)Cdst;
#pragma unroll
    for (int m = 0; m < 4; m++) {
#pragma unroll
      for (int n = 0; n < 4; n++) {
        int colb = wn + n * 16 + fr;
        float bv = bias ? bias[ccol0 + colb] : 0.f;
#pragma unroll
        for (int r = 0; r < 4; r++) {
          int row = wm + m * 16 + fq4 + r;
          float v = acc[m][n][r] * aeff + bv;
          if (relu) v = fmaxf(v, 0.f);
          Cp[(size_t)(crow0 + row) * ldc + ccol0 + colb] = v;
        }
      }
    }
  }
}

// -------- per-row softmax stats over the band (batched 3 streams) --------
__global__ __launch_bounds__(256) void k_stats(const float* __restrict__ Lband,
                                               float2* __restrict__ stats) {
  int ig = blockIdx.x * 4 + (threadIdx.x >> 6);   // global row 0..12287
  int lane = threadIdx.x & 63;
  int i = ig & 4095;
  int ti = i >> 7;
  int cbase = (ti - 2) * 128;
  int jlo = i - 249; if (jlo < 0) jlo = 0;
  int jhi = i + 249; if (jhi > NSEQ - 1) jhi = NSEQ - 1;
  int clo = jlo - cbase, chi = jhi - cbase;
  const float* L = Lband + (size_t)ig * 640;
  float m = -1e30f;
  for (int c = clo + lane; c <= chi; c += 64) m = fmaxf(m, L[c]);
  for (int off = 32; off; off >>= 1) m = fmaxf(m, __shfl_xor(m, off));
  float s = 0.f;
  for (int c = clo + lane; c <= chi; c += 64) s += __expf(L[c] - m);
  for (int off = 32; off; off >>= 1) s += __shfl_xor(s, off);
  if (lane == 0) stats[ig] = make_float2(m, s);
}

// -------- build banded attT (bf16): attT_s[i][j - 128*((i>>7)-2)] = att[j][i] --------
__global__ __launch_bounds__(256) void k_build_attT(const float* __restrict__ Lband,
                                                    const float2* __restrict__ stats,
                                                    unsigned short* __restrict__ t0,
                                                    unsigned short* __restrict__ t1,
                                                    unsigned short* __restrict__ t2) {
  int byy = blockIdx.y;
  int s = byy >> 5, ti = byy & 31;       // i tile (attT rows), local
  int tj = ti + (int)blockIdx.x - 2;     // j tile
  if (tj < 0 || tj >= 32) return;
  unsigned short* dst = (s == 0) ? t0 : ((s == 1) ? t1 : t2);
  __shared__ unsigned short T[128][132];  // T[i_loc][j_loc]
  int t = threadIdx.x;
  int c0 = (ti - tj + 2) * 128;  // Lband col base for rows j reading i-tile ti
  int colg = (t & 31) * 4;       // i_loc
  for (int jj = t >> 5; jj < 128; jj += 8) {
    int jg = s * NSEQ + tj * 128 + jj;
    float2 st = stats[jg];
    float inv = 1.f / st.y;
    float4 v = *(const float4*)&Lband[(size_t)jg * 640 + c0 + colg];
    float vv[4] = {v.x, v.y, v.z, v.w};
#pragma unroll
    for (int q = 0; q < 4; q++) {
      int i = ti * 128 + colg + q;
      int d = i - (tj * 128 + jj);
      float a = (d < 250 && d > -250) ? __expf(vv[q] - st.x) * inv : 0.f;
      T[colg + q][jj] = f2b(a);
    }
  }
  __syncthreads();
  int jb0 = (tj - ti + 2) * 128;  // banded col base in attT rows of tile ti
  for (int ii = t >> 5; ii < 128; ii += 8) {
    size_t o = (size_t)(ti * 128 + ii) * 640 + jb0 + colg;
    *(ushort4*)(dst + o) = *(ushort4*)&T[ii][colg];
  }
}

// -------- write full fp32 att (stream 0 / x1), zeros outside band --------
__global__ __launch_bounds__(256) void k_write_att(const float* __restrict__ Lband,
                                                   const float2* __restrict__ stats,
                                                   float* __restrict__ att) {
  int i = blockIdx.x;
  int ti = i >> 7, cbase = (ti - 2) * 128;
  int jlo = i - 249; if (jlo < 0) jlo = 0;
  int jhi = i + 249; if (jhi > NSEQ - 1) jhi = NSEQ - 1;
  float2 st = stats[i];
  float m = st.x, inv = 1.f / st.y;
  const float* L = Lband + (size_t)i * 640;
  float* arow = att + (size_t)i * NSEQ;
  for (int j0 = threadIdx.x * 4; j0 < NSEQ; j0 += 1024) {
    float ov[4];
#pragma unroll
    for (int q = 0; q < 4; q++) {
      int j = j0 + q;
      ov[q] = (j >= jlo && j <= jhi) ? __expf(L[j - cbase] - m) * inv : 0.f;
    }
    *(float4*)(arow + j0) = make_float4(ov[0], ov[1], ov[2], ov[3]);
  }
}

// -------- residual + LayerNorm (ddof=1, eps on std) for 3 streams, sum -> bf16 --------
__global__ __launch_bounds__(256) void k_ln3(const unsigned short* __restrict__ yo,
                                             const float* __restrict__ x1,
                                             const float* __restrict__ x2,
                                             const float* __restrict__ x3,
                                             const float* __restrict__ g,
                                             const float* __restrict__ b,
                                             unsigned short* __restrict__ ysum_b) {
  int i = blockIdx.x, t = threadIdx.x;
  int w = t >> 6, lane = t & 63;
  __shared__ float red[8];
  const float* xs[3] = {x1, x2, x3};
  float4 gg = *(const float4*)(g + t * 4);
  float4 bb = *(const float4*)(b + t * 4);
  float acc[4] = {0.f, 0.f, 0.f, 0.f};
  for (int s = 0; s < 3; s++) {
    ushort4 yv = *(const ushort4*)(yo + ((size_t)(s * NSEQ + i)) * MDIM + t * 4);
    float4 xx = *(const float4*)(xs[s] + (size_t)i * MDIM + t * 4);
    float v[4] = {b2f(yv.x) + xx.x, b2f(yv.y) + xx.y, b2f(yv.z) + xx.z, b2f(yv.w) + xx.w};
    float s1 = v[0] + v[1] + v[2] + v[3];
    float s2 = v[0]*v[0] + v[1]*v[1] + v[2]*v[2] + v[3]*v[3];
    for (int off = 32; off; off >>= 1) { s1 += __shfl_xor(s1, off); s2 += __shfl_xor(s2, off); }
    __syncthreads();
    if (lane == 0) { red[w] = s1; red[4 + w] = s2; }
    __syncthreads();
    float S1 = red[0] + red[1] + red[2] + red[3];
    float S2 = red[4] + red[5] + red[6] + red[7];
    float mean = S1 * (1.f / 1024.f);
    float var = (S2 - S1 * mean) * (1.f / 1023.f);
    float rstd = 1.f / (sqrtf(var) + 1e-6f);
    acc[0] += gg.x * (v[0] - mean) * rstd + bb.x;
    acc[1] += gg.y * (v[1] - mean) * rstd + bb.y;
    acc[2] += gg.z * (v[2] - mean) * rstd + bb.z;
    acc[3] += gg.w * (v[3] - mean) * rstd + bb.w;
  }
  ushort4 o;
  o.x = f2b(acc[0]); o.y = f2b(acc[1]); o.z = f2b(acc[2]); o.w = f2b(acc[3]);
  *(ushort4*)(ysum_b + (size_t)i * MDIM + t * 4) = o;
}

// -------- final: LN(128, gkc/bkc) -> dot(kd_w) + kd_b -> sigmoid --------
__global__ __launch_bounds__(128) void k_final(const float* __restrict__ h3,
                                               const float* __restrict__ g,
                                               const float* __restrict__ b,
                                               const float* __restrict__ kdw,
                                               const float* __restrict__ kdb,
                                               float* __restrict__ yout) {
  int i = blockIdx.x, t = threadIdx.x;
  float v = h3[(size_t)i * 128 + t];
  float s1 = v, s2 = v * v;
  for (int off = 32; off; off >>= 1) { s1 += __shfl_xor(s1, off); s2 += __shfl_xor(s2, off); }
  __shared__ float red[4];
  int w = t >> 6, lane = t & 63;
  if (lane == 0) { red[w] = s1; red[2 + w] = s2; }
  __syncthreads();
  float S1 = red[0] + red[1], S2 = red[2] + red[3];
  float mean = S1 * (1.f / 128.f);
  float var = (S2 - S1 * mean) * (1.f / 127.f);
  float rstd = 1.f / (sqrtf(var) + 1e-6f);
  float ln = g[t] * (v - mean) * rstd + b[t];
  float p = ln * kdw[t];
  for (int off = 32; off; off >>= 1) p += __shfl_xor(p, off);
  __syncthreads();
  if (lane == 0) red[w] = p;
  __syncthreads();
  if (t == 0) {
    float z = red[0] + red[1] + kdb[0];
    yout[i] = 1.f / (1.f + __expf(-z));
  }
}

extern "C" void kernel_launch(void* const* d_in, const int* in_sizes, int n_in,
                              void* d_out, int out_size, void* d_ws, size_t ws_size,
                              hipStream_t stream) {
  const float* x1 = (const float*)d_in[0];
  const float* x2 = (const float*)d_in[1];
  const float* x3 = (const float*)d_in[2];
  const float* Wq = (const float*)d_in[3];
  const float* Wk = (const float*)d_in[4];
  const float* Wv = (const float*)d_in[5];
  const float* Wo = (const float*)d_in[6];
  const float* ka_w = (const float*)d_in[7];
  const float* ka_b = (const float*)d_in[8];
  const float* kb_w = (const float*)d_in[9];
  const float* kb_b = (const float*)d_in[10];
  const float* kc_w = (const float*)d_in[11];
  const float* kc_b = (const float*)d_in[12];
  const float* kd_w = (const float*)d_in[13];
  const float* kd_b = (const float*)d_in[14];
  const float* g13 = (const float*)d_in[15];
  const float* b13 = (const float*)d_in[16];
  const float* gkc = (const float*)d_in[17];
  const float* bkc = (const float*)d_in[18];

  float* y_out = (float*)d_out;
  float* att_out = y_out + NSEQ;  // [4096,4096] fp32

  char* ws = (char*)d_ws;
  size_t off = 0;
  auto alloc = [&](size_t bytes) -> void* {
    void* p = ws + off;
    off += (bytes + 255) & ~(size_t)255;
    return p;
  };
  const size_t NM = (size_t)3 * NSEQ * MDIM;  // 12.6M elems
  // weight block must stay contiguous (k_cvt_w writes it as one run)
  unsigned short* Wq_b = (unsigned short*)alloc(1024 * 1024 * 2);
  unsigned short* Wk_b = (unsigned short*)alloc(1024 * 1024 * 2);
  unsigned short* Wv_b = (unsigned short*)alloc(1024 * 1024 * 2);
  unsigned short* Wo_b = (unsigned short*)alloc(1024 * 1024 * 2);
  unsigned short* ka_wb = (unsigned short*)alloc(1024 * 1024 * 2);
  unsigned short* kb_wb = (unsigned short*)alloc(512 * 1024 * 2);
  unsigned short* kc_wb = (unsigned short*)alloc(128 * 512 * 2);
  unsigned short* Xb = (unsigned short*)alloc(NM * 2);   // later: yb, then h3 (fp32 2MB)
  unsigned short* Qb = (unsigned short*)alloc(NM * 2);   // later: yo (bf16), then h2b
  unsigned short* Kb = (unsigned short*)alloc(NM * 2);   // later: ysum_b (8MB)
  unsigned short* VTb = (unsigned short*)alloc(NM * 2);  // later: h1b (8MB)
  float* Lband = (float*)alloc((size_t)3 * NSEQ * 640 * 4);
  float2* stats = (float2*)alloc((size_t)3 * NSEQ * 8);
  unsigned short* aT0 = (unsigned short*)alloc((size_t)NSEQ * 640 * 2);
  unsigned short* aT1 = (unsigned short*)alloc((size_t)NSEQ * 640 * 2);
  unsigned short* aT2 = (unsigned short*)alloc((size_t)NSEQ * 640 * 2);
  // aliases (lifetimes disjoint)
  unsigned short* yb = Xb;
  unsigned short* yo = Qb;
  unsigned short* ysum_b = Kb;
  unsigned short* h1b = VTb;
  unsigned short* h2b = Qb;
  float* h3 = (float*)Xb;

  auto gemm = [&](int gx, int gy, const unsigned short* A, int lda,
                  const unsigned short* B, int ldb, void* C, void* C2, int ldc,
                  int K, float alpha, const float* bias, int relu, int out_bf16,
                  int mode, const unsigned short* A1 = nullptr,
                  const unsigned short* A2 = nullptr) {
    k_gemm<<<dim3(gx, gy), 256, 0, stream>>>(A, lda, B, ldb, C, C2, ldc, K, alpha,
                                             bias, relu, out_bf16, mode, A1, A2);
  };

  // weights -> bf16 (contiguous dst starting at Wq_b)
  k_cvt_w<<<5696, 256, 0, stream>>>(Wq, Wk, Wv, Wo, ka_w, kb_w, kc_w, Wq_b);
  // x1..x3 -> Xb batched [12288,1024]
  k_cvt3<<<12288, 256, 0, stream>>>(x1, x2, x3, Xb);

  // merged Q+K projection: B = [Wq;Wk] (contiguous), Q gets x0.06
  gemm(96, 16, Xb, 1024, Wq_b, 1024, Qb, Kb, 1024, 1024, 0.06f, nullptr, 0, 1, 3);
  // VT[1024,12288] = Wv @ X^T
  gemm(8, 96, Wv_b, 1024, Xb, 1024, VTb, nullptr, 3 * NSEQ, 1024, 1.f, nullptr, 0, 1, 0);
  // banded logits, all streams: Lband[12288,640] fp32
  gemm(96, 5, Qb, 1024, Kb, 1024, Lband, nullptr, 640, 1024, 1.f, nullptr, 0, 0, 1);
  k_stats<<<3072, 256, 0, stream>>>(Lband, stats);
  k_build_attT<<<dim3(5, 96), 256, 0, stream>>>(Lband, stats, aT0, aT1, aT2);
  // y[12288,1024] = attT @ V (banded K), bf16 into yb
  gemm(96, 8, aT0, 640, VTb, 3 * NSEQ, yb, nullptr, 1024, NSEQ, 1.f, nullptr, 0, 1, 2, aT1, aT2);
  k_write_att<<<4096, 256, 0, stream>>>(Lband, stats, att_out);
  // yo = y @ Wo^T (bf16)
  gemm(96, 8, yb, 1024, Wo_b, 1024, yo, nullptr, 1024, 1024, 1.f, nullptr, 0, 1, 0);
  // residual + LN + 3-stream sum -> bf16
  k_ln3<<<4096, 256, 0, stream>>>(yo, x1, x2, x3, g13, b13, ysum_b);

  // MLP head (M=4096)
  gemm(32, 8, ysum_b, 1024, ka_wb, 1024, h1b, nullptr, 1024, 1024, 1.f, ka_b, 0, 1, 0);
  gemm(32, 4, h1b, 1024, kb_wb, 1024, h2b, nullptr, 512, 1024, 1.f, kb_b, 0, 1, 0);
  gemm(32, 1, h2b, 512, kc_wb, 512, h3, nullptr, 128, 512, 1.f, kc_b, 1, 0, 0);
  k_final<<<4096, 128, 0, stream>>>(h3, gkc, bkc, kd_w, kd_b, y_out);
}

// Round 4
// 488.917 us; speedup vs baseline: 1.7692x; 1.0179x over previous
//
#include <hip/hip_runtime.h>
#include <hip/hip_bf16.h>
#include <cstdint>
#include <cstddef>

// Problem constants
#define NSEQ 4096
#define MDIM 1024
// band: |i-j| < 250 -> row-tile ti needs col-tiles [ti-2, ti+2]
// banded layout (Lband fp32, attT bf16): row i, col c = j - 128*((i>>7)-2), width 640

typedef __attribute__((ext_vector_type(8))) short short8;
typedef __attribute__((ext_vector_type(4))) float f32x4;

typedef const __attribute__((address_space(1))) void gvoid_t;
typedef __attribute__((address_space(3))) void lvoid_t;

__device__ __forceinline__ unsigned short f2b(float x) {
  union { float f; unsigned int u; } a; a.f = x;
  unsigned int r = (a.u + 0x7fffu + ((a.u >> 16) & 1u)) >> 16;
  return (unsigned short)r;
}
__device__ __forceinline__ float b2f(unsigned short u) {
  union { float f; unsigned int u32; } a; a.u32 = ((unsigned int)u) << 16;
  return a.f;
}

// -------- merged weight cvt: 7 tensors -> contiguous bf16 dst --------
__global__ __launch_bounds__(256) void k_cvt_w(
    const float* __restrict__ s0, const float* __restrict__ s1,
    const float* __restrict__ s2, const float* __restrict__ s3,
    const float* __restrict__ s4, const float* __restrict__ s5,
    const float* __restrict__ s6, unsigned short* __restrict__ dst) {
  int idx = blockIdx.x * 256 + threadIdx.x;  // chunk of 4
  const float* src; int local;
  if (idx < 1310720) {  // 5 x 2^18
    int seg = idx >> 18; local = idx & 262143;
    src = (seg == 0) ? s0 : (seg == 1) ? s1 : (seg == 2) ? s2 : (seg == 3) ? s3 : s4;
  } else if (idx < 1441792) { src = s5; local = idx - 1310720; }
  else { src = s6; local = idx - 1441792; }
  float4 v = *(const float4*)(src + (size_t)local * 4);
  ushort4 o; o.x = f2b(v.x); o.y = f2b(v.y); o.z = f2b(v.z); o.w = f2b(v.w);
  *(ushort4*)(dst + (size_t)idx * 4) = o;
}

// -------- x1..x3 -> contiguous bf16 [12288,1024] --------
__global__ __launch_bounds__(256) void k_cvt3(
    const float* __restrict__ s0, const float* __restrict__ s1,
    const float* __restrict__ s2, unsigned short* __restrict__ dst) {
  int idx = blockIdx.x * 256 + threadIdx.x;  // chunk of 4, 3*2^20 total
  int seg = idx >> 20, local = idx & 1048575;
  const float* src = (seg == 0) ? s0 : (seg == 1) ? s1 : s2;
  float4 v = *(const float4*)(src + (size_t)local * 4);
  ushort4 o; o.x = f2b(v.x); o.y = f2b(v.y); o.z = f2b(v.z); o.w = f2b(v.w);
  *(ushort4*)(dst + (size_t)idx * 4) = o;
}

// -------- GEMM: C = alpha*(A @ B^T) + bias, A[M,K] bf16, B[N,K] bf16 --------
// BK=64, global_load_lds 16B staging.
// LDS layout: row r (128 B) has 8 slots of 16B; slot s holds global chunk (s-r)&7
// (slot = (chunk + r)&7). 8 consecutive lanes of a frag read hit 8 consecutive
// slots -> 32 distinct banks, conflict-free (row stride 128B aliases all rows).
// grid.x multiple of 8 indexes the LARGE shared operand so same-tile blocks
// co-locate per XCD (flat id % 8 == bx % 8 when gridDim.x % 8 == 0).
// mode 0: bx=A row tile, by=B col tile.      mode 4: bx=B col tile, by=A row tile.
// mode 3: merged QK (by<8 -> Cout*alpha, by>=8 -> Cout2*1).
// mode 1: banded logits, grid (96,5): row tile bx (s=bx>>5,ti=bx&31), col tile ti+by-2.
// mode 2: attT(banded,lda=640) @ VT, grid (96,8): K window [max(ti-2,0)*128,min(ti+3,32)*128).
__global__ __launch_bounds__(256) void k_gemm(
    const unsigned short* __restrict__ A, int lda,
    const unsigned short* __restrict__ B, int ldb,
    void* __restrict__ Cout, void* __restrict__ Cout2, int ldc,
    int K, float alpha,
    const float* __restrict__ bias, int relu, int out_bf16, int mode,
    const unsigned short* __restrict__ A1, const unsigned short* __restrict__ A2) {
  __shared__ unsigned short smem[2 * 128 * 64];
  unsigned short* As = smem;
  unsigned short* Bs = smem + 128 * 64;
  int bx = blockIdx.x, by = blockIdx.y;
  const unsigned short* Ab;
  const unsigned short* Bb;
  void* Cdst = Cout;
  float aeff = alpha;
  int k0 = 0, k1 = K, a_koff = 0;
  int crow0 = bx * 128, ccol0 = by * 128;
  if (mode == 0) {
    Ab = A + (size_t)bx * 128 * lda;
    Bb = B + (size_t)by * 128 * ldb;
  } else if (mode == 4) {
    Ab = A + (size_t)by * 128 * lda;
    Bb = B + (size_t)bx * 128 * ldb;
    crow0 = by * 128; ccol0 = bx * 128;
  } else if (mode == 3) {
    Ab = A + (size_t)bx * 128 * lda;
    Bb = B + (size_t)by * 128 * ldb;
    if (by >= 8) { Cdst = Cout2; aeff = 1.f; }
    ccol0 = (by & 7) * 128;
  } else if (mode == 1) {
    int s = bx >> 5, ti = bx & 31;
    int bt = ti + by - 2;
    if (bt < 0 || bt >= 32) return;
    Ab = A + (size_t)bx * 128 * lda;
    Bb = B + (size_t)(s * 32 + bt) * 128 * ldb;
  } else {  // mode 2
    int s = bx >> 5, ti = bx & 31;
    const unsigned short* Abase = (s == 0) ? A : ((s == 1) ? A1 : A2);
    Ab = Abase + (size_t)ti * 128 * lda;  // lda = 640
    int lo = ti - 2; if (lo < 0) lo = 0;
    int hi = ti + 3; if (hi > 32) hi = 32;
    k0 = lo * 128; k1 = hi * 128;
    a_koff = (ti - 2) * 128;
    Bb = B + (size_t)by * 128 * ldb + s * NSEQ;
  }

  const int t = threadIdx.x;
  const int l = t & 63;
  const int w = t >> 6;
  const int fr = l & 15;
  const int quad = l >> 4;
  const int wm = (w >> 1) * 64;
  const int wn = (w & 1) * 64;
  const int fq4 = quad * 4;

  // staging: 4 insts per matrix per wave; inst j covers rows w*32+j*8 .. +7
  int srow[4], scg[4], sloff[4];
#pragma unroll
  for (int j = 0; j < 4; j++) {
    srow[j] = w * 32 + j * 8 + (l >> 3);
    scg[j] = ((l & 7) - srow[j]) & 7;       // global chunk for LDS slot l&7 of row srow
    sloff[j] = (w * 32 + j * 8) * 64 + l * 8;
  }

  f32x4 acc[4][4];
#pragma unroll
  for (int m = 0; m < 4; m++)
#pragma unroll
    for (int n = 0; n < 4; n++) acc[m][n] = (f32x4){0.f, 0.f, 0.f, 0.f};

  for (int kk = k0; kk < k1; kk += 64) {
    int ka = kk - a_koff;
    __syncthreads();
#pragma unroll
    for (int j = 0; j < 4; j++)
      __builtin_amdgcn_global_load_lds(
          (gvoid_t*)(Ab + (size_t)srow[j] * lda + ka + scg[j] * 8),
          (lvoid_t*)(As + sloff[j]), 16, 0, 0);
#pragma unroll
    for (int j = 0; j < 4; j++)
      __builtin_amdgcn_global_load_lds(
          (gvoid_t*)(Bb + (size_t)srow[j] * ldb + kk + scg[j] * 8),
          (lvoid_t*)(Bs + sloff[j]), 16, 0, 0);
    __syncthreads();
#pragma unroll
    for (int s = 0; s < 2; s++) {
      short8 af[4], bf[4];
#pragma unroll
      for (int m = 0; m < 4; m++) {
        int r = wm + m * 16 + fr;
        int slot = (s * 4 + quad + r) & 7;
        af[m] = *(const short8*)(As + r * 64 + slot * 8);
      }
#pragma unroll
      for (int n = 0; n < 4; n++) {
        int r = wn + n * 16 + fr;
        int slot = (s * 4 + quad + r) & 7;
        bf[n] = *(const short8*)(Bs + r * 64 + slot * 8);
      }
#pragma unroll
      for (int m = 0; m < 4; m++)
#pragma unroll
        for (int n = 0; n < 4; n++)
          acc[m][n] = __builtin_amdgcn_mfma_f32_16x16x32_bf16(af[m], bf[n], acc[m][n], 0, 0, 0);
    }
  }

  if (out_bf16) {
    // stage C tile (128x128 bf16) in LDS with chunk swizzle, then coalesced 16B stores
    __syncthreads();
#pragma unroll
    for (int m = 0; m < 4; m++) {
#pragma unroll
      for (int n = 0; n < 4; n++) {
        int colb = wn + n * 16 + fr;
        float bv = bias ? bias[ccol0 + colb] : 0.f;
#pragma unroll
        for (int r = 0; r < 4; r++) {
          int row = wm + m * 16 + fq4 + r;
          float v = acc[m][n][r] * aeff + bv;
          if (relu) v = fmaxf(v, 0.f);
          int cc = ((colb >> 3) + row) & 15;
          smem[row * 128 + cc * 8 + (colb & 7)] = f2b(v);
        }
      }
    }
    __syncthreads();
    unsigned short* Cp = (unsigned short*)Cdst;
    for (int i = t; i < 2048; i += 256) {
      int row = i >> 4, lc = i & 15;
      int pc = (lc + row) & 15;
      uint4 v = *(const uint4*)(smem + row * 128 + pc * 8);
      *(uint4*)(Cp + (size_t)(crow0 + row) * ldc + ccol0 + lc * 8) = v;
    }
  } else {
    float* Cp = (float*)Cdst;
#pragma unroll
    for (int m = 0; m < 4; m++) {
#pragma unroll
      for (int n = 0; n < 4; n++) {
        int colb = wn + n * 16 + fr;
        float bv = bias ? bias[ccol0 + colb] : 0.f;
#pragma unroll
        for (int r = 0; r < 4; r++) {
          int row = wm + m * 16 + fq4 + r;
          float v = acc[m][n][r] * aeff + bv;
          if (relu) v = fmaxf(v, 0.f);
          Cp[(size_t)(crow0 + row) * ldc + ccol0 + colb] = v;
        }
      }
    }
  }
}

// -------- per-row softmax stats over the band (batched 3 streams) --------
__global__ __launch_bounds__(256) void k_stats(const float* __restrict__ Lband,
                                               float2* __restrict__ stats) {
  int ig = blockIdx.x * 4 + (threadIdx.x >> 6);   // global row 0..12287
  int lane = threadIdx.x & 63;
  int i = ig & 4095;
  int ti = i >> 7;
  int cbase = (ti - 2) * 128;
  int jlo = i - 249; if (jlo < 0) jlo = 0;
  int jhi = i + 249; if (jhi > NSEQ - 1) jhi = NSEQ - 1;
  int clo = jlo - cbase, chi = jhi - cbase;
  const float* L = Lband + (size_t)ig * 640;
  float m = -1e30f;
  for (int c = clo + lane; c <= chi; c += 64) m = fmaxf(m, L[c]);
  for (int off = 32; off; off >>= 1) m = fmaxf(m, __shfl_xor(m, off));
  float s = 0.f;
  for (int c = clo + lane; c <= chi; c += 64) s += __expf(L[c] - m);
  for (int off = 32; off; off >>= 1) s += __shfl_xor(s, off);
  if (lane == 0) stats[ig] = make_float2(m, s);
}

// -------- build banded attT (bf16): attT_s[i][j - 128*((i>>7)-2)] = att[j][i] --------
__global__ __launch_bounds__(256) void k_build_attT(const float* __restrict__ Lband,
                                                    const float2* __restrict__ stats,
                                                    unsigned short* __restrict__ t0,
                                                    unsigned short* __restrict__ t1,
                                                    unsigned short* __restrict__ t2) {
  int byy = blockIdx.y;
  int s = byy >> 5, ti = byy & 31;       // i tile (attT rows), local
  int tj = ti + (int)blockIdx.x - 2;     // j tile
  if (tj < 0 || tj >= 32) return;
  unsigned short* dst = (s == 0) ? t0 : ((s == 1) ? t1 : t2);
  __shared__ unsigned short T[128][132];  // T[i_loc][j_loc]
  int t = threadIdx.x;
  int c0 = (ti - tj + 2) * 128;  // Lband col base for rows j reading i-tile ti
  int colg = (t & 31) * 4;       // i_loc
  for (int jj = t >> 5; jj < 128; jj += 8) {
    int jg = s * NSEQ + tj * 128 + jj;
    float2 st = stats[jg];
    float inv = 1.f / st.y;
    float4 v = *(const float4*)&Lband[(size_t)jg * 640 + c0 + colg];
    float vv[4] = {v.x, v.y, v.z, v.w};
#pragma unroll
    for (int q = 0; q < 4; q++) {
      int i = ti * 128 + colg + q;
      int d = i - (tj * 128 + jj);
      float a = (d < 250 && d > -250) ? __expf(vv[q] - st.x) * inv : 0.f;
      T[colg + q][jj] = f2b(a);
    }
  }
  __syncthreads();
  int jb0 = (tj - ti + 2) * 128;  // banded col base in attT rows of tile ti
  for (int ii = t >> 5; ii < 128; ii += 8) {
    size_t o = (size_t)(ti * 128 + ii) * 640 + jb0 + colg;
    *(ushort4*)(dst + o) = *(ushort4*)&T[ii][colg];
  }
}

// -------- write full fp32 att (stream 0 / x1), zeros outside band --------
__global__ __launch_bounds__(256) void k_write_att(const float* __restrict__ Lband,
                                                   const float2* __restrict__ stats,
                                                   float* __restrict__ att) {
  int i = blockIdx.x;
  int ti = i >> 7, cbase = (ti - 2) * 128;
  int jlo = i - 249; if (jlo < 0) jlo = 0;
  int jhi = i + 249; if (jhi > NSEQ - 1) jhi = NSEQ - 1;
  float2 st = stats[i];
  float m = st.x, inv = 1.f / st.y;
  const float* L = Lband + (size_t)i * 640;
  float* arow = att + (size_t)i * NSEQ;
  for (int j0 = threadIdx.x * 4; j0 < NSEQ; j0 += 1024) {
    float ov[4];
#pragma unroll
    for (int q = 0; q < 4; q++) {
      int j = j0 + q;
      ov[q] = (j >= jlo && j <= jhi) ? __expf(L[j - cbase] - m) * inv : 0.f;
    }
    *(float4*)(arow + j0) = make_float4(ov[0], ov[1], ov[2], ov[3]);
  }
}

// -------- residual + LayerNorm (ddof=1, eps on std) for 3 streams, sum -> bf16 --------
__global__ __launch_bounds__(256) void k_ln3(const unsigned short* __restrict__ yo,
                                             const float* __restrict__ x1,
                                             const float* __restrict__ x2,
                                             const float* __restrict__ x3,
                                             const float* __restrict__ g,
                                             const float* __restrict__ b,
                                             unsigned short* __restrict__ ysum_b) {
  int i = blockIdx.x, t = threadIdx.x;
  int w = t >> 6, lane = t & 63;
  __shared__ float red[8];
  const float* xs[3] = {x1, x2, x3};
  float4 gg = *(const float4*)(g + t * 4);
  float4 bb = *(const float4*)(b + t * 4);
  float acc[4] = {0.f, 0.f, 0.f, 0.f};
  for (int s = 0; s < 3; s++) {
    ushort4 yv = *(const ushort4*)(yo + ((size_t)(s * NSEQ + i)) * MDIM + t * 4);
    float4 xx = *(const float4*)(xs[s] + (size_t)i * MDIM + t * 4);
    float v[4] = {b2f(yv.x) + xx.x, b2f(yv.y) + xx.y, b2f(yv.z) + xx.z, b2f(yv.w) + xx.w};
    float s1 = v[0] + v[1] + v[2] + v[3];
    float s2 = v[0]*v[0] + v[1]*v[1] + v[2]*v[2] + v[3]*v[3];
    for (int off = 32; off; off >>= 1) { s1 += __shfl_xor(s1, off); s2 += __shfl_xor(s2, off); }
    __syncthreads();
    if (lane == 0) { red[w] = s1; red[4 + w] = s2; }
    __syncthreads();
    float S1 = red[0] + red[1] + red[2] + red[3];
    float S2 = red[4] + red[5] + red[6] + red[7];
    float mean = S1 * (1.f / 1024.f);
    float var = (S2 - S1 * mean) * (1.f / 1023.f);
    float rstd = 1.f / (sqrtf(var) + 1e-6f);
    acc[0] += gg.x * (v[0] - mean) * rstd + bb.x;
    acc[1] += gg.y * (v[1] - mean) * rstd + bb.y;
    acc[2] += gg.z * (v[2] - mean) * rstd + bb.z;
    acc[3] += gg.w * (v[3] - mean) * rstd + bb.w;
  }
  ushort4 o;
  o.x = f2b(acc[0]); o.y = f2b(acc[1]); o.z = f2b(acc[2]); o.w = f2b(acc[3]);
  *(ushort4*)(ysum_b + (size_t)i * MDIM + t * 4) = o;
}

// -------- final: LN(128, gkc/bkc) -> dot(kd_w) + kd_b -> sigmoid --------
__global__ __launch_bounds__(128) void k_final(const float* __restrict__ h3,
                                               const float* __restrict__ g,
                                               const float* __restrict__ b,
                                               const float* __restrict__ kdw,
                                               const float* __restrict__ kdb,
                                               float* __restrict__ yout) {
  int i = blockIdx.x, t = threadIdx.x;
  float v = h3[(size_t)i * 128 + t];
  float s1 = v, s2 = v * v;
  for (int off = 32; off; off >>= 1) { s1 += __shfl_xor(s1, off); s2 += __shfl_xor(s2, off); }
  __shared__ float red[4];
  int w = t >> 6, lane = t & 63;
  if (lane == 0) { red[w] = s1; red[2 + w] = s2; }
  __syncthreads();
  float S1 = red[0] + red[1], S2 = red[2] + red[3];
  float mean = S1 * (1.f / 128.f);
  float var = (S2 - S1 * mean) * (1.f / 127.f);
  float rstd = 1.f / (sqrtf(var) + 1e-6f);
  float ln = g[t] * (v - mean) * rstd + b[t];
  float p = ln * kdw[t];
  for (int off = 32; off; off >>= 1) p += __shfl_xor(p, off);
  __syncthreads();
  if (lane == 0) red[w] = p;
  __syncthreads();
  if (t == 0) {
    float z = red[0] + red[1] + kdb[0];
    yout[i] = 1.f / (1.f + __expf(-z));
  }
}

extern "C" void kernel_launch(void* const* d_in, const int* in_sizes, int n_in,
                              void* d_out, int out_size, void* d_ws, size_t ws_size,
                              hipStream_t stream) {
  const float* x1 = (const float*)d_in[0];
  const float* x2 = (const float*)d_in[1];
  const float* x3 = (const float*)d_in[2];
  const float* Wq = (const float*)d_in[3];
  const float* Wk = (const float*)d_in[4];
  const float* Wv = (const float*)d_in[5];
  const float* Wo = (const float*)d_in[6];
  const float* ka_w = (const float*)d_in[7];
  const float* ka_b = (const float*)d_in[8];
  const float* kb_w = (const float*)d_in[9];
  const float* kb_b = (const float*)d_in[10];
  const float* kc_w = (const float*)d_in[11];
  const float* kc_b = (const float*)d_in[12];
  const float* kd_w = (const float*)d_in[13];
  const float* kd_b = (const float*)d_in[14];
  const float* g13 = (const float*)d_in[15];
  const float* b13 = (const float*)d_in[16];
  const float* gkc = (const float*)d_in[17];
  const float* bkc = (const float*)d_in[18];

  float* y_out = (float*)d_out;
  float* att_out = y_out + NSEQ;  // [4096,4096] fp32

  char* ws = (char*)d_ws;
  size_t off = 0;
  auto alloc = [&](size_t bytes) -> void* {
    void* p = ws + off;
    off += (bytes + 255) & ~(size_t)255;
    return p;
  };
  const size_t NM = (size_t)3 * NSEQ * MDIM;  // 12.6M elems
  // weight block must stay contiguous (k_cvt_w writes it as one run)
  unsigned short* Wq_b = (unsigned short*)alloc(1024 * 1024 * 2);
  unsigned short* Wk_b = (unsigned short*)alloc(1024 * 1024 * 2);
  unsigned short* Wv_b = (unsigned short*)alloc(1024 * 1024 * 2);
  unsigned short* Wo_b = (unsigned short*)alloc(1024 * 1024 * 2);
  unsigned short* ka_wb = (unsigned short*)alloc(1024 * 1024 * 2);
  unsigned short* kb_wb = (unsigned short*)alloc(512 * 1024 * 2);
  unsigned short* kc_wb = (unsigned short*)alloc(128 * 512 * 2);
  unsigned short* Xb = (unsigned short*)alloc(NM * 2);   // later: yb, then h3 (fp32 2MB)
  unsigned short* Qb = (unsigned short*)alloc(NM * 2);   // later: yo (bf16), then h2b
  unsigned short* Kb = (unsigned short*)alloc(NM * 2);   // later: ysum_b (8MB)
  unsigned short* VTb = (unsigned short*)alloc(NM * 2);  // later: h1b (8MB)
  float* Lband = (float*)alloc((size_t)3 * NSEQ * 640 * 4);
  float2* stats = (float2*)alloc((size_t)3 * NSEQ * 8);
  unsigned short* aT0 = (unsigned short*)alloc((size_t)NSEQ * 640 * 2);
  unsigned short* aT1 = (unsigned short*)alloc((size_t)NSEQ * 640 * 2);
  unsigned short* aT2 = (unsigned short*)alloc((size_t)NSEQ * 640 * 2);
  // aliases (lifetimes disjoint)
  unsigned short* yb = Xb;
  unsigned short* yo = Qb;
  unsigned short* ysum_b = Kb;
  unsigned short* h1b = VTb;
  unsigned short* h2b = Qb;
  float* h3 = (float*)Xb;

  auto gemm = [&](int gx, int gy, const unsigned short* A, int lda,
                  const unsigned short* B, int ldb, void* C, void* C2, int ldc,
                  int K, float alpha, const float* bias, int relu, int out_bf16,
                  int mode, const unsigned short* A1 = nullptr,
                  const unsigned short* A2 = nullptr) {
    k_gemm<<<dim3(gx, gy), 256, 0, stream>>>(A, lda, B, ldb, C, C2, ldc, K, alpha,
                                             bias, relu, out_bf16, mode, A1, A2);
  };

  // weights -> bf16 (contiguous dst starting at Wq_b)
  k_cvt_w<<<5696, 256, 0, stream>>>(Wq, Wk, Wv, Wo, ka_w, kb_w, kc_w, Wq_b);
  // x1..x3 -> Xb batched [12288,1024]
  k_cvt3<<<12288, 256, 0, stream>>>(x1, x2, x3, Xb);

  // merged Q+K projection: B = [Wq;Wk] (contiguous), Q gets x0.06
  gemm(96, 16, Xb, 1024, Wq_b, 1024, Qb, Kb, 1024, 1024, 0.06f, nullptr, 0, 1, 3);
  // VT[1024,12288] = Wv @ X^T  (transposed grid: bx = X tile for XCD locality)
  gemm(96, 8, Wv_b, 1024, Xb, 1024, VTb, nullptr, 3 * NSEQ, 1024, 1.f, nullptr, 0, 1, 4);
  // banded logits, all streams: Lband[12288,640] fp32
  gemm(96, 5, Qb, 1024, Kb, 1024, Lband, nullptr, 640, 1024, 1.f, nullptr, 0, 0, 1);
  k_stats<<<3072, 256, 0, stream>>>(Lband, stats);
  k_build_attT<<<dim3(5, 96), 256, 0, stream>>>(Lband, stats, aT0, aT1, aT2);
  // y[12288,1024] = attT @ V (banded K), bf16 into yb
  gemm(96, 8, aT0, 640, VTb, 3 * NSEQ, yb, nullptr, 1024, NSEQ, 1.f, nullptr, 0, 1, 2, aT1, aT2);
  k_write_att<<<4096, 256, 0, stream>>>(Lband, stats, att_out);
  // yo = y @ Wo^T (bf16)
  gemm(96, 8, yb, 1024, Wo_b, 1024, yo, nullptr, 1024, 1024, 1.f, nullptr, 0, 1, 0);
  // residual + LN + 3-stream sum -> bf16
  k_ln3<<<4096, 256, 0, stream>>>(yo, x1, x2, x3, g13, b13, ysum_b);

  // MLP head (M=4096)
  gemm(32, 8, ysum_b, 1024, ka_wb, 1024, h1b, nullptr, 1024, 1024, 1.f, ka_b, 0, 1, 0);
  gemm(32, 4, h1b, 1024, kb_wb, 1024, h2b, nullptr, 512, 1024, 1.f, kb_b, 0, 1, 0);
  gemm(32, 1, h2b, 512, kc_wb, 512, h3, nullptr, 128, 512, 1.f, kc_b, 1, 0, 0);
  k_final<<<4096, 128, 0, stream>>>(h3, gkc, bkc, kd_w, kd_b, y_out);
}

// Round 5
// 451.279 us; speedup vs baseline: 1.9168x; 1.0834x over previous
//
#include <hip/hip_runtime.h>
#include <hip/hip_bf16.h>
#include <cstdint>
#include <cstddef>

// Problem constants
#define NSEQ 4096
#define MDIM 1024
// band: |i-j| < 250 -> row-tile ti needs col-tiles [ti-2, ti+2]
// banded layout (Lband bf16, attT bf16): row i, col c = j - 128*((i>>7)-2), width 640

typedef __attribute__((ext_vector_type(8))) short short8;
typedef __attribute__((ext_vector_type(4))) float f32x4;

typedef const __attribute__((address_space(1))) void gvoid_t;
typedef __attribute__((address_space(3))) void lvoid_t;

__device__ __forceinline__ unsigned short f2b(float x) {
  union { float f; unsigned int u; } a; a.f = x;
  unsigned int r = (a.u + 0x7fffu + ((a.u >> 16) & 1u)) >> 16;
  return (unsigned short)r;
}
__device__ __forceinline__ float b2f(unsigned short u) {
  union { float f; unsigned int u32; } a; a.u32 = ((unsigned int)u) << 16;
  return a.f;
}

// -------- merged cvt: 7 weight tensors -> Wdst (contiguous), x1..x3 -> Xdst --------
__global__ __launch_bounds__(256) void k_cvt_all(
    const float* __restrict__ s0, const float* __restrict__ s1,
    const float* __restrict__ s2, const float* __restrict__ s3,
    const float* __restrict__ s4, const float* __restrict__ s5,
    const float* __restrict__ s6,
    const float* __restrict__ xa, const float* __restrict__ xb,
    const float* __restrict__ xc,
    unsigned short* __restrict__ Wdst, unsigned short* __restrict__ Xdst) {
  int idx = blockIdx.x * 256 + threadIdx.x;  // chunk of 4 floats
  const float* src; int local; unsigned short* dst; int didx;
  if (idx < 1458176) {  // weights: 5*2^18 + 2^17 + 2^14
    dst = Wdst; didx = idx;
    if (idx < 1310720) {
      int seg = idx >> 18; local = idx & 262143;
      src = (seg == 0) ? s0 : (seg == 1) ? s1 : (seg == 2) ? s2 : (seg == 3) ? s3 : s4;
    } else if (idx < 1441792) { src = s5; local = idx - 1310720; }
    else { src = s6; local = idx - 1441792; }
  } else {
    int i2 = idx - 1458176;   // 0 .. 3*2^20-1
    dst = Xdst; didx = i2;
    int seg = i2 >> 20; local = i2 & 1048575;
    src = (seg == 0) ? xa : (seg == 1) ? xb : xc;
  }
  float4 v = *(const float4*)(src + (size_t)local * 4);
  ushort4 o; o.x = f2b(v.x); o.y = f2b(v.y); o.z = f2b(v.z); o.w = f2b(v.w);
  *(ushort4*)(dst + (size_t)didx * 4) = o;
}

// -------- GEMM: C = alpha*(A @ B^T) + bias, A[M,K] bf16, B[N,K] bf16 --------
// BK=64, global_load_lds 16B staging.
// LDS layout: row r (128 B) has 8 slots of 16B; slot s holds global chunk (s-r)&7.
// 8 consecutive lanes of a frag read hit 8 consecutive slots -> conflict-free.
// grid.x (mult of 8) indexes the LARGE shared operand -> same-tile blocks same XCD.
// mode 3: merged QKV, grid (96,24). by<8: Q=alpha*(X@Wq^T); by in 8..15: K=X@Wk^T;
//         by>=16: VT[1024,12288] = Wv @ X^T (A1=Wv, output A2, ldc=12288).
// mode 0: bx=A row tile, by=B col tile.
// mode 1: banded logits -> bf16 Lband[12288,640], grid (96,5).
// mode 2: attT(banded,lda=640) @ VT, grid (96,8): K window [max(ti-2,0),min(ti+3,32))*128.
__global__ __launch_bounds__(256) void k_gemm(
    const unsigned short* __restrict__ A, int lda,
    const unsigned short* __restrict__ B, int ldb,
    void* __restrict__ Cout, void* __restrict__ Cout2, int ldc,
    int K, float alpha,
    const float* __restrict__ bias, int relu, int out_bf16, int mode,
    const unsigned short* __restrict__ A1, const unsigned short* __restrict__ A2) {
  __shared__ unsigned short smem[2 * 128 * 64];
  unsigned short* As = smem;
  unsigned short* Bs = smem + 128 * 64;
  int bx = blockIdx.x, by = blockIdx.y;
  const unsigned short* Ab;
  const unsigned short* Bb;
  void* Cdst = Cout;
  float aeff = alpha;
  int k0 = 0, k1 = K, a_koff = 0;
  int ldce = ldc;
  int crow0 = bx * 128, ccol0 = by * 128;
  if (mode == 0) {
    Ab = A + (size_t)bx * 128 * lda;
    Bb = B + (size_t)by * 128 * ldb;
  } else if (mode == 3) {
    if (by < 16) {
      Ab = A + (size_t)bx * 128 * lda;
      Bb = B + (size_t)by * 128 * ldb;
      if (by >= 8) { Cdst = Cout2; aeff = 1.f; }
      ccol0 = (by & 7) * 128;
    } else {
      Ab = A1 + (size_t)(by - 16) * 128 * 1024;   // Wv rows
      Bb = A + (size_t)bx * 128 * lda;            // X rows
      Cdst = (void*)const_cast<unsigned short*>(A2);
      aeff = 1.f;
      crow0 = (by - 16) * 128; ccol0 = bx * 128;
      ldce = 3 * NSEQ;
    }
  } else if (mode == 1) {
    int s = bx >> 5, ti = bx & 31;
    int bt = ti + by - 2;
    if (bt < 0 || bt >= 32) return;
    Ab = A + (size_t)bx * 128 * lda;
    Bb = B + (size_t)(s * 32 + bt) * 128 * ldb;
  } else {  // mode 2
    int s = bx >> 5, ti = bx & 31;
    const unsigned short* Abase = (s == 0) ? A : ((s == 1) ? A1 : A2);
    Ab = Abase + (size_t)ti * 128 * lda;  // lda = 640
    int lo = ti - 2; if (lo < 0) lo = 0;
    int hi = ti + 3; if (hi > 32) hi = 32;
    k0 = lo * 128; k1 = hi * 128;
    a_koff = (ti - 2) * 128;
    Bb = B + (size_t)by * 128 * ldb + s * NSEQ;
  }

  const int t = threadIdx.x;
  const int l = t & 63;
  const int w = t >> 6;
  const int fr = l & 15;
  const int quad = l >> 4;
  const int wm = (w >> 1) * 64;
  const int wn = (w & 1) * 64;
  const int fq4 = quad * 4;

  // staging: 4 insts per matrix per wave; inst j covers rows w*32+j*8 .. +7
  int srow[4], scg[4], sloff[4];
#pragma unroll
  for (int j = 0; j < 4; j++) {
    srow[j] = w * 32 + j * 8 + (l >> 3);
    scg[j] = ((l & 7) - srow[j]) & 7;       // global chunk for LDS slot l&7 of row srow
    sloff[j] = (w * 32 + j * 8) * 64 + l * 8;
  }

  f32x4 acc[4][4];
#pragma unroll
  for (int m = 0; m < 4; m++)
#pragma unroll
    for (int n = 0; n < 4; n++) acc[m][n] = (f32x4){0.f, 0.f, 0.f, 0.f};

  for (int kk = k0; kk < k1; kk += 64) {
    int ka = kk - a_koff;
    __syncthreads();
#pragma unroll
    for (int j = 0; j < 4; j++)
      __builtin_amdgcn_global_load_lds(
          (gvoid_t*)(Ab + (size_t)srow[j] * lda + ka + scg[j] * 8),
          (lvoid_t*)(As + sloff[j]), 16, 0, 0);
#pragma unroll
    for (int j = 0; j < 4; j++)
      __builtin_amdgcn_global_load_lds(
          (gvoid_t*)(Bb + (size_t)srow[j] * ldb + kk + scg[j] * 8),
          (lvoid_t*)(Bs + sloff[j]), 16, 0, 0);
    __syncthreads();
#pragma unroll
    for (int s = 0; s < 2; s++) {
      short8 af[4], bf[4];
#pragma unroll
      for (int m = 0; m < 4; m++) {
        int r = wm + m * 16 + fr;
        int slot = (s * 4 + quad + r) & 7;
        af[m] = *(const short8*)(As + r * 64 + slot * 8);
      }
#pragma unroll
      for (int n = 0; n < 4; n++) {
        int r = wn + n * 16 + fr;
        int slot = (s * 4 + quad + r) & 7;
        bf[n] = *(const short8*)(Bs + r * 64 + slot * 8);
      }
#pragma unroll
      for (int m = 0; m < 4; m++)
#pragma unroll
        for (int n = 0; n < 4; n++)
          acc[m][n] = __builtin_amdgcn_mfma_f32_16x16x32_bf16(af[m], bf[n], acc[m][n], 0, 0, 0);
    }
  }

  if (out_bf16) {
    // stage C tile (128x128 bf16) in LDS with chunk swizzle, then coalesced 16B stores
    __syncthreads();
#pragma unroll
    for (int m = 0; m < 4; m++) {
#pragma unroll
      for (int n = 0; n < 4; n++) {
        int colb = wn + n * 16 + fr;
        float bv = bias ? bias[ccol0 + colb] : 0.f;
#pragma unroll
        for (int r = 0; r < 4; r++) {
          int row = wm + m * 16 + fq4 + r;
          float v = acc[m][n][r] * aeff + bv;
          if (relu) v = fmaxf(v, 0.f);
          int cc = ((colb >> 3) + row) & 15;
          smem[row * 128 + cc * 8 + (colb & 7)] = f2b(v);
        }
      }
    }
    __syncthreads();
    unsigned short* Cp = (unsigned short*)Cdst;
    for (int i = t; i < 2048; i += 256) {
      int row = i >> 4, lc = i & 15;
      int pc = (lc + row) & 15;
      uint4 v = *(const uint4*)(smem + row * 128 + pc * 8);
      *(uint4*)(Cp + (size_t)(crow0 + row) * ldce + ccol0 + lc * 8) = v;
    }
  } else {
    float* Cp = (float*)Cdst;
#pragma unroll
    for (int m = 0; m < 4; m++) {
#pragma unroll
      for (int n = 0; n < 4; n++) {
        int colb = wn + n * 16 + fr;
        float bv = bias ? bias[ccol0 + colb] : 0.f;
#pragma unroll
        for (int r = 0; r < 4; r++) {
          int row = wm + m * 16 + fq4 + r;
          float v = acc[m][n][r] * aeff + bv;
          if (relu) v = fmaxf(v, 0.f);
          Cp[(size_t)(crow0 + row) * ldce + ccol0 + colb] = v;
        }
      }
    }
  }
}

// -------- small GEMM: 64x64 tile, same staging/swizzle, for the MLP head --------
__global__ __launch_bounds__(256) void k_gemm64(
    const unsigned short* __restrict__ A, int lda,
    const unsigned short* __restrict__ B, int ldb,
    void* __restrict__ Cout, int ldc, int K,
    const float* __restrict__ bias, int relu, int out_bf16) {
  __shared__ unsigned short smem[2 * 64 * 64];
  unsigned short* As = smem;
  unsigned short* Bs = smem + 64 * 64;
  int bx = blockIdx.x, by = blockIdx.y;
  const unsigned short* Ab = A + (size_t)bx * 64 * lda;
  const unsigned short* Bb = B + (size_t)by * 64 * ldb;
  int crow0 = bx * 64, ccol0 = by * 64;

  const int t = threadIdx.x;
  const int l = t & 63;
  const int w = t >> 6;
  const int fr = l & 15;
  const int quad = l >> 4;
  const int wm = (w & 1) * 32;
  const int wn = (w >> 1) * 32;
  const int fq4 = quad * 4;

  int srow[2], scg[2], sloff[2];
#pragma unroll
  for (int j = 0; j < 2; j++) {
    srow[j] = w * 16 + j * 8 + (l >> 3);
    scg[j] = ((l & 7) - srow[j]) & 7;
    sloff[j] = (w * 16 + j * 8) * 64 + l * 8;
  }

  f32x4 acc[2][2];
#pragma unroll
  for (int m = 0; m < 2; m++)
#pragma unroll
    for (int n = 0; n < 2; n++) acc[m][n] = (f32x4){0.f, 0.f, 0.f, 0.f};

  for (int kk = 0; kk < K; kk += 64) {
    __syncthreads();
#pragma unroll
    for (int j = 0; j < 2; j++)
      __builtin_amdgcn_global_load_lds(
          (gvoid_t*)(Ab + (size_t)srow[j] * lda + kk + scg[j] * 8),
          (lvoid_t*)(As + sloff[j]), 16, 0, 0);
#pragma unroll
    for (int j = 0; j < 2; j++)
      __builtin_amdgcn_global_load_lds(
          (gvoid_t*)(Bb + (size_t)srow[j] * ldb + kk + scg[j] * 8),
          (lvoid_t*)(Bs + sloff[j]), 16, 0, 0);
    __syncthreads();
#pragma unroll
    for (int s = 0; s < 2; s++) {
      short8 af[2], bf[2];
#pragma unroll
      for (int m = 0; m < 2; m++) {
        int r = wm + m * 16 + fr;
        int slot = (s * 4 + quad + r) & 7;
        af[m] = *(const short8*)(As + r * 64 + slot * 8);
      }
#pragma unroll
      for (int n = 0; n < 2; n++) {
        int r = wn + n * 16 + fr;
        int slot = (s * 4 + quad + r) & 7;
        bf[n] = *(const short8*)(Bs + r * 64 + slot * 8);
      }
#pragma unroll
      for (int m = 0; m < 2; m++)
#pragma unroll
        for (int n = 0; n < 2; n++)
          acc[m][n] = __builtin_amdgcn_mfma_f32_16x16x32_bf16(af[m], bf[n], acc[m][n], 0, 0, 0);
    }
  }

  if (out_bf16) {
    __syncthreads();
#pragma unroll
    for (int m = 0; m < 2; m++) {
#pragma unroll
      for (int n = 0; n < 2; n++) {
        int colb = wn + n * 16 + fr;
        float bv = bias ? bias[ccol0 + colb] : 0.f;
#pragma unroll
        for (int r = 0; r < 4; r++) {
          int row = wm + m * 16 + fq4 + r;
          float v = acc[m][n][r] + bv;
          if (relu) v = fmaxf(v, 0.f);
          int cc = ((colb >> 3) + row) & 7;
          smem[row * 64 + cc * 8 + (colb & 7)] = f2b(v);
        }
      }
    }
    __syncthreads();
    unsigned short* Cp = (unsigned short*)Cout;
    for (int i = t; i < 512; i += 256) {
      int row = i >> 3, lc = i & 7;
      int pc = (lc + row) & 7;
      uint4 v = *(const uint4*)(smem + row * 64 + pc * 8);
      *(uint4*)(Cp + (size_t)(crow0 + row) * ldc + ccol0 + lc * 8) = v;
    }
  } else {
    float* Cp = (float*)Cout;
#pragma unroll
    for (int m = 0; m < 2; m++) {
#pragma unroll
      for (int n = 0; n < 2; n++) {
        int colb = wn + n * 16 + fr;
        float bv = bias ? bias[ccol0 + colb] : 0.f;
#pragma unroll
        for (int r = 0; r < 4; r++) {
          int row = wm + m * 16 + fq4 + r;
          float v = acc[m][n][r] + bv;
          if (relu) v = fmaxf(v, 0.f);
          Cp[(size_t)(crow0 + row) * ldc + ccol0 + colb] = v;
        }
      }
    }
  }
}

// -------- per-row softmax stats over the band (batched 3 streams, bf16 Lband) --------
__global__ __launch_bounds__(256) void k_stats(const unsigned short* __restrict__ Lband,
                                               float2* __restrict__ stats) {
  int ig = blockIdx.x * 4 + (threadIdx.x >> 6);   // global row 0..12287
  int lane = threadIdx.x & 63;
  int i = ig & 4095;
  int ti = i >> 7;
  int cbase = (ti - 2) * 128;
  int jlo = i - 249; if (jlo < 0) jlo = 0;
  int jhi = i + 249; if (jhi > NSEQ - 1) jhi = NSEQ - 1;
  int clo = jlo - cbase, chi = jhi - cbase;
  const unsigned short* L = Lband + (size_t)ig * 640;
  float m = -1e30f;
  for (int c = clo + lane; c <= chi; c += 64) m = fmaxf(m, b2f(L[c]));
  for (int off = 32; off; off >>= 1) m = fmaxf(m, __shfl_xor(m, off));
  float s = 0.f;
  for (int c = clo + lane; c <= chi; c += 64) s += __expf(b2f(L[c]) - m);
  for (int off = 32; off; off >>= 1) s += __shfl_xor(s, off);
  if (lane == 0) stats[ig] = make_float2(m, s);
}

// -------- build banded attT (bf16): attT_s[i][j - 128*((i>>7)-2)] = att[j][i] --------
__global__ __launch_bounds__(256) void k_build_attT(const unsigned short* __restrict__ Lband,
                                                    const float2* __restrict__ stats,
                                                    unsigned short* __restrict__ t0,
                                                    unsigned short* __restrict__ t1,
                                                    unsigned short* __restrict__ t2) {
  int byy = blockIdx.y;
  int s = byy >> 5, ti = byy & 31;       // i tile (attT rows), local
  int tj = ti + (int)blockIdx.x - 2;     // j tile
  if (tj < 0 || tj >= 32) return;
  unsigned short* dst = (s == 0) ? t0 : ((s == 1) ? t1 : t2);
  __shared__ unsigned short T[128][132];  // T[i_loc][j_loc]
  int t = threadIdx.x;
  int c0 = (ti - tj + 2) * 128;  // Lband col base for rows j reading i-tile ti
  int colg = (t & 31) * 4;       // i_loc
  for (int jj = t >> 5; jj < 128; jj += 8) {
    int jg = s * NSEQ + tj * 128 + jj;
    float2 st = stats[jg];
    float inv = 1.f / st.y;
    ushort4 v = *(const ushort4*)&Lband[(size_t)jg * 640 + c0 + colg];
    float vv[4] = {b2f(v.x), b2f(v.y), b2f(v.z), b2f(v.w)};
#pragma unroll
    for (int q = 0; q < 4; q++) {
      int i = ti * 128 + colg + q;
      int d = i - (tj * 128 + jj);
      float a = (d < 250 && d > -250) ? __expf(vv[q] - st.x) * inv : 0.f;
      T[colg + q][jj] = f2b(a);
    }
  }
  __syncthreads();
  int jb0 = (tj - ti + 2) * 128;  // banded col base in attT rows of tile ti
  for (int ii = t >> 5; ii < 128; ii += 8) {
    size_t o = (size_t)(ti * 128 + ii) * 640 + jb0 + colg;
    *(ushort4*)(dst + o) = *(ushort4*)&T[ii][colg];
  }
}

// -------- write full fp32 att (stream 0 / x1), zeros outside band --------
__global__ __launch_bounds__(256) void k_write_att(const unsigned short* __restrict__ Lband,
                                                   const float2* __restrict__ stats,
                                                   float* __restrict__ att) {
  int i = blockIdx.x;
  int ti = i >> 7, cbase = (ti - 2) * 128;
  int jlo = i - 249; if (jlo < 0) jlo = 0;
  int jhi = i + 249; if (jhi > NSEQ - 1) jhi = NSEQ - 1;
  float2 st = stats[i];
  float m = st.x, inv = 1.f / st.y;
  const unsigned short* L = Lband + (size_t)i * 640;
  float* arow = att + (size_t)i * NSEQ;
  for (int j0 = threadIdx.x * 4; j0 < NSEQ; j0 += 1024) {
    float ov[4];
#pragma unroll
    for (int q = 0; q < 4; q++) {
      int j = j0 + q;
      ov[q] = (j >= jlo && j <= jhi) ? __expf(b2f(L[j - cbase]) - m) * inv : 0.f;
    }
    *(float4*)(arow + j0) = make_float4(ov[0], ov[1], ov[2], ov[3]);
  }
}

// -------- residual + LayerNorm (ddof=1, eps on std) for 3 streams, sum -> bf16 --------
__global__ __launch_bounds__(256) void k_ln3(const unsigned short* __restrict__ yo,
                                             const float* __restrict__ x1,
                                             const float* __restrict__ x2,
                                             const float* __restrict__ x3,
                                             const float* __restrict__ g,
                                             const float* __restrict__ b,
                                             unsigned short* __restrict__ ysum_b) {
  int i = blockIdx.x, t = threadIdx.x;
  int w = t >> 6, lane = t & 63;
  __shared__ float red[8];
  const float* xs[3] = {x1, x2, x3};
  float4 gg = *(const float4*)(g + t * 4);
  float4 bb = *(const float4*)(b + t * 4);
  float acc[4] = {0.f, 0.f, 0.f, 0.f};
  for (int s = 0; s < 3; s++) {
    ushort4 yv = *(const ushort4*)(yo + ((size_t)(s * NSEQ + i)) * MDIM + t * 4);
    float4 xx = *(const float4*)(xs[s] + (size_t)i * MDIM + t * 4);
    float v[4] = {b2f(yv.x) + xx.x, b2f(yv.y) + xx.y, b2f(yv.z) + xx.z, b2f(yv.w) + xx.w};
    float s1 = v[0] + v[1] + v[2] + v[3];
    float s2 = v[0]*v[0] + v[1]*v[1] + v[2]*v[2] + v[3]*v[3];
    for (int off = 32; off; off >>= 1) { s1 += __shfl_xor(s1, off); s2 += __shfl_xor(s2, off); }
    __syncthreads();
    if (lane == 0) { red[w] = s1; red[4 + w] = s2; }
    __syncthreads();
    float S1 = red[0] + red[1] + red[2] + red[3];
    float S2 = red[4] + red[5] + red[6] + red[7];
    float mean = S1 * (1.f / 1024.f);
    float var = (S2 - S1 * mean) * (1.f / 1023.f);
    float rstd = 1.f / (sqrtf(var) + 1e-6f);
    acc[0] += gg.x * (v[0] - mean) * rstd + bb.x;
    acc[1] += gg.y * (v[1] - mean) * rstd + bb.y;
    acc[2] += gg.z * (v[2] - mean) * rstd + bb.z;
    acc[3] += gg.w * (v[3] - mean) * rstd + bb.w;
  }
  ushort4 o;
  o.x = f2b(acc[0]); o.y = f2b(acc[1]); o.z = f2b(acc[2]); o.w = f2b(acc[3]);
  *(ushort4*)(ysum_b + (size_t)i * MDIM + t * 4) = o;
}

// -------- final: LN(128, gkc/bkc) -> dot(kd_w) + kd_b -> sigmoid --------
__global__ __launch_bounds__(128) void k_final(const float* __restrict__ h3,
                                               const float* __restrict__ g,
                                               const float* __restrict__ b,
                                               const float* __restrict__ kdw,
                                               const float* __restrict__ kdb,
                                               float* __restrict__ yout) {
  int i = blockIdx.x, t = threadIdx.x;
  float v = h3[(size_t)i * 128 + t];
  float s1 = v, s2 = v * v;
  for (int off = 32; off; off >>= 1) { s1 += __shfl_xor(s1, off); s2 += __shfl_xor(s2, off); }
  __shared__ float red[4];
  int w = t >> 6, lane = t & 63;
  if (lane == 0) { red[w] = s1; red[2 + w] = s2; }
  __syncthreads();
  float S1 = red[0] + red[1], S2 = red[2] + red[3];
  float mean = S1 * (1.f / 128.f);
  float var = (S2 - S1 * mean) * (1.f / 127.f);
  float rstd = 1.f / (sqrtf(var) + 1e-6f);
  float ln = g[t] * (v - mean) * rstd + b[t];
  float p = ln * kdw[t];
  for (int off = 32; off; off >>= 1) p += __shfl_xor(p, off);
  __syncthreads();
  if (lane == 0) red[w] = p;
  __syncthreads();
  if (t == 0) {
    float z = red[0] + red[1] + kdb[0];
    yout[i] = 1.f / (1.f + __expf(-z));
  }
}

extern "C" void kernel_launch(void* const* d_in, const int* in_sizes, int n_in,
                              void* d_out, int out_size, void* d_ws, size_t ws_size,
                              hipStream_t stream) {
  const float* x1 = (const float*)d_in[0];
  const float* x2 = (const float*)d_in[1];
  const float* x3 = (const float*)d_in[2];
  const float* Wq = (const float*)d_in[3];
  const float* Wk = (const float*)d_in[4];
  const float* Wv = (const float*)d_in[5];
  const float* Wo = (const float*)d_in[6];
  const float* ka_w = (const float*)d_in[7];
  const float* ka_b = (const float*)d_in[8];
  const float* kb_w = (const float*)d_in[9];
  const float* kb_b = (const float*)d_in[10];
  const float* kc_w = (const float*)d_in[11];
  const float* kc_b = (const float*)d_in[12];
  const float* kd_w = (const float*)d_in[13];
  const float* kd_b = (const float*)d_in[14];
  const float* g13 = (const float*)d_in[15];
  const float* b13 = (const float*)d_in[16];
  const float* gkc = (const float*)d_in[17];
  const float* bkc = (const float*)d_in[18];

  float* y_out = (float*)d_out;
  float* att_out = y_out + NSEQ;  // [4096,4096] fp32

  char* ws = (char*)d_ws;
  size_t off = 0;
  auto alloc = [&](size_t bytes) -> void* {
    void* p = ws + off;
    off += (bytes + 255) & ~(size_t)255;
    return p;
  };
  const size_t NM = (size_t)3 * NSEQ * MDIM;  // 12.6M elems
  // weight block must stay contiguous (k_cvt_all writes it as one run)
  unsigned short* Wq_b = (unsigned short*)alloc(1024 * 1024 * 2);
  unsigned short* Wk_b = (unsigned short*)alloc(1024 * 1024 * 2);
  unsigned short* Wv_b = (unsigned short*)alloc(1024 * 1024 * 2);
  unsigned short* Wo_b = (unsigned short*)alloc(1024 * 1024 * 2);
  unsigned short* ka_wb = (unsigned short*)alloc(1024 * 1024 * 2);
  unsigned short* kb_wb = (unsigned short*)alloc(512 * 1024 * 2);
  unsigned short* kc_wb = (unsigned short*)alloc(128 * 512 * 2);
  unsigned short* Xb = (unsigned short*)alloc(NM * 2);   // later: yb, then h3 (fp32 2MB)
  unsigned short* Qb = (unsigned short*)alloc(NM * 2);   // later: yo (bf16), then h2b
  unsigned short* Kb = (unsigned short*)alloc(NM * 2);   // later: ysum_b (8MB)
  unsigned short* VTb = (unsigned short*)alloc(NM * 2);  // later: h1b (8MB)
  unsigned short* Lband = (unsigned short*)alloc((size_t)3 * NSEQ * 640 * 2);
  float2* stats = (float2*)alloc((size_t)3 * NSEQ * 8);
  unsigned short* aT0 = (unsigned short*)alloc((size_t)NSEQ * 640 * 2);
  unsigned short* aT1 = (unsigned short*)alloc((size_t)NSEQ * 640 * 2);
  unsigned short* aT2 = (unsigned short*)alloc((size_t)NSEQ * 640 * 2);
  // aliases (lifetimes disjoint)
  unsigned short* yb = Xb;
  unsigned short* yo = Qb;
  unsigned short* ysum_b = Kb;
  unsigned short* h1b = VTb;
  unsigned short* h2b = Qb;
  float* h3 = (float*)Xb;

  auto gemm = [&](int gx, int gy, const unsigned short* A, int lda,
                  const unsigned short* B, int ldb, void* C, void* C2, int ldc,
                  int K, float alpha, const float* bias, int relu, int out_bf16,
                  int mode, const unsigned short* A1 = nullptr,
                  const unsigned short* A2 = nullptr) {
    k_gemm<<<dim3(gx, gy), 256, 0, stream>>>(A, lda, B, ldb, C, C2, ldc, K, alpha,
                                             bias, relu, out_bf16, mode, A1, A2);
  };

  // all fp32->bf16 conversions in one dispatch (4603904 chunks / 256)
  k_cvt_all<<<17984, 256, 0, stream>>>(Wq, Wk, Wv, Wo, ka_w, kb_w, kc_w,
                                       x1, x2, x3, Wq_b, Xb);

  // merged Q+K+VT: Q=0.06*(X@Wq^T), K=X@Wk^T, VT=Wv@X^T
  gemm(96, 24, Xb, 1024, Wq_b, 1024, Qb, Kb, 1024, 1024, 0.06f, nullptr, 0, 1, 3,
       Wv_b, VTb);
  // banded logits, all streams: Lband[12288,640] bf16
  gemm(96, 5, Qb, 1024, Kb, 1024, Lband, nullptr, 640, 1024, 1.f, nullptr, 0, 1, 1);
  k_stats<<<3072, 256, 0, stream>>>(Lband, stats);
  k_build_attT<<<dim3(5, 96), 256, 0, stream>>>(Lband, stats, aT0, aT1, aT2);
  // y[12288,1024] = attT @ V (banded K), bf16 into yb
  gemm(96, 8, aT0, 640, VTb, 3 * NSEQ, yb, nullptr, 1024, NSEQ, 1.f, nullptr, 0, 1, 2, aT1, aT2);
  k_write_att<<<4096, 256, 0, stream>>>(Lband, stats, att_out);
  // yo = y @ Wo^T (bf16)
  gemm(96, 8, yb, 1024, Wo_b, 1024, yo, nullptr, 1024, 1024, 1.f, nullptr, 0, 1, 0);
  // residual + LN + 3-stream sum -> bf16
  k_ln3<<<4096, 256, 0, stream>>>(yo, x1, x2, x3, g13, b13, ysum_b);

  // MLP head (M=4096) with 64x64-tile GEMMs for full-grid occupancy
  k_gemm64<<<dim3(64, 16), 256, 0, stream>>>(ysum_b, 1024, ka_wb, 1024, h1b, 1024,
                                             1024, ka_b, 0, 1);
  k_gemm64<<<dim3(64, 8), 256, 0, stream>>>(h1b, 1024, kb_wb, 1024, h2b, 512,
                                            1024, kb_b, 0, 1);
  k_gemm64<<<dim3(64, 2), 256, 0, stream>>>(h2b, 512, kc_wb, 512, h3, 128,
                                            512, kc_b, 1, 0);
  k_final<<<4096, 128, 0, stream>>>(h3, gkc, bkc, kd_w, kd_b, y_out);
}

// Round 7
// 385.399 us; speedup vs baseline: 2.2444x; 1.1709x over previous
//
#include <hip/hip_runtime.h>
#include <hip/hip_bf16.h>
#include <cstdint>
#include <cstddef>

// Problem constants
#define NSEQ 4096
#define MDIM 1024
// band: |i-j| < 250 -> row-tile ti needs col-tiles [ti-2, ti+2]
// banded layout (Eband bf16 = exp(logits), attT fp8 x16): row i, col c = j - 128*((i>>7)-2), width 640
// fp8 scaling: attn weights x64, attT x16, y stored x8; MLP kept bf16 for accuracy.

typedef __attribute__((ext_vector_type(8))) short short8;
typedef __attribute__((ext_vector_type(4))) float f32x4;

typedef const __attribute__((address_space(1))) void gvoid_t;
typedef __attribute__((address_space(3))) void lvoid_t;

__device__ __forceinline__ unsigned short f2b(float x) {
  union { float f; unsigned int u; } a; a.f = x;
  unsigned int r = (a.u + 0x7fffu + ((a.u >> 16) & 1u)) >> 16;
  return (unsigned short)r;
}
__device__ __forceinline__ float b2f(unsigned short u) {
  union { float f; unsigned int u32; } a; a.u32 = ((unsigned int)u) << 16;
  return a.f;
}
__device__ __forceinline__ unsigned char f2e4(float x) {
  return (unsigned char)(__builtin_amdgcn_cvt_pk_fp8_f32(x, x, 0, false) & 0xff);
}
__device__ __forceinline__ unsigned int f2e4x4(float a, float b, float c, float d) {
  unsigned int lo = __builtin_amdgcn_cvt_pk_fp8_f32(a, b, 0, false);
  return (unsigned int)__builtin_amdgcn_cvt_pk_fp8_f32(c, d, lo, true);
}

// -------- merged cvt: Wq..Wo (x64)->fp8, ka/kb/kc->bf16, x1..x3->fp8 --------
__global__ __launch_bounds__(256) void k_cvt_all(
    const float* __restrict__ s0, const float* __restrict__ s1,
    const float* __restrict__ s2, const float* __restrict__ s3,
    const float* __restrict__ s4, const float* __restrict__ s5,
    const float* __restrict__ s6,
    const float* __restrict__ xa, const float* __restrict__ xb,
    const float* __restrict__ xc,
    unsigned char* __restrict__ Wf8, unsigned short* __restrict__ Wmlp,
    unsigned char* __restrict__ Xdst) {
  int idx = blockIdx.x * 256 + threadIdx.x;  // chunk of 4 floats
  if (idx < 1048576) {  // Wq,Wk,Wv,Wo fp8 x64
    int seg = idx >> 18, local = idx & 262143;
    const float* src = (seg == 0) ? s0 : (seg == 1) ? s1 : (seg == 2) ? s2 : s3;
    float4 v = *(const float4*)(src + (size_t)local * 4);
    *(unsigned int*)(Wf8 + (size_t)idx * 4) =
        f2e4x4(v.x * 64.f, v.y * 64.f, v.z * 64.f, v.w * 64.f);
  } else if (idx < 1458176) {  // ka,kb,kc bf16
    int i2 = idx - 1048576;
    const float* src; int local;
    if (i2 < 262144) { src = s4; local = i2; }
    else if (i2 < 393216) { src = s5; local = i2 - 262144; }
    else { src = s6; local = i2 - 393216; }
    float4 v = *(const float4*)(src + (size_t)local * 4);
    ushort4 o; o.x = f2b(v.x); o.y = f2b(v.y); o.z = f2b(v.z); o.w = f2b(v.w);
    *(ushort4*)(Wmlp + (size_t)i2 * 4) = o;
  } else {  // x1..x3 fp8
    int i2 = idx - 1458176;   // 0 .. 3*2^20-1
    int seg = i2 >> 20, local = i2 & 1048575;
    const float* src = (seg == 0) ? xa : (seg == 1) ? xb : xc;
    float4 v = *(const float4*)(src + (size_t)local * 4);
    *(unsigned int*)(Xdst + (size_t)i2 * 4) = f2e4x4(v.x, v.y, v.z, v.w);
  }
}

// -------- fp8 GEMM: C = alpha*(A @ B^T) + bias, A[M,K] fp8, B[N,K] fp8 --------
// BK=128, global_load_lds 16B staging. LDS row = 128 B = 8 slots of 16B;
// slot s holds global 16B-chunk (s-r)&7 -> staging and frag reads conflict-free.
// grid.x (mult of 8) indexes the large shared operand (XCD co-location).
// okind: 0=f32 out, 1=bf16 out (do_exp: v=exp(v)), 2=fp8 out.
// mode 3: merged QKV, grid (96,24). by<8: Q; 8..15: K (Cout2); >=16: VT=Wv@X^T
//         (A1=Wv, out A2 fp8 [1024,12288]).
// mode 0: bx=A row tile, by=B col tile.
// mode 1: banded logits -> Eband (exp, bf16) [12288,640], grid (96,5).
// mode 2: attT(banded fp8,lda=640) @ VT, grid (96,8): K window
//         [max(ti-2,0),min(ti+3,32))*128, B col base s*4096.
__global__ __launch_bounds__(256) void k_gemm(
    const unsigned char* __restrict__ A, int lda,
    const unsigned char* __restrict__ B, int ldb,
    void* __restrict__ Cout, void* __restrict__ Cout2, int ldc,
    int K, float alpha,
    const float* __restrict__ bias, int relu, int okind, int do_exp, int mode,
    const unsigned char* __restrict__ A1, const unsigned char* __restrict__ A2) {
  __shared__ unsigned char smem[2 * 128 * 128];  // 32 KB
  unsigned char* As = smem;
  unsigned char* Bs = smem + 128 * 128;
  int bx = blockIdx.x, by = blockIdx.y;
  const unsigned char* Ab;
  const unsigned char* Bb;
  void* Cdst = Cout;
  int k0 = 0, k1 = K, a_koff = 0;
  int ldce = ldc;
  int crow0 = bx * 128, ccol0 = by * 128;
  if (mode == 0) {
    Ab = A + (size_t)bx * 128 * lda;
    Bb = B + (size_t)by * 128 * ldb;
  } else if (mode == 3) {
    if (by < 16) {
      Ab = A + (size_t)bx * 128 * lda;
      Bb = B + (size_t)by * 128 * ldb;
      if (by >= 8) Cdst = Cout2;
      ccol0 = (by & 7) * 128;
    } else {
      Ab = A1 + (size_t)(by - 16) * 128 * 1024;   // Wv rows
      Bb = A + (size_t)bx * 128 * lda;            // X rows
      Cdst = (void*)const_cast<unsigned char*>(A2);
      crow0 = (by - 16) * 128; ccol0 = bx * 128;
      ldce = 3 * NSEQ;
    }
  } else if (mode == 1) {
    int s = bx >> 5, ti = bx & 31;
    int bt = ti + by - 2;
    if (bt < 0 || bt >= 32) return;
    Ab = A + (size_t)bx * 128 * lda;
    Bb = B + (size_t)(s * 32 + bt) * 128 * ldb;
  } else {  // mode 2
    int s = bx >> 5, ti = bx & 31;
    const unsigned char* Abase = (s == 0) ? A : ((s == 1) ? A1 : A2);
    Ab = Abase + (size_t)ti * 128 * lda;  // lda = 640
    int lo = ti - 2; if (lo < 0) lo = 0;
    int hi = ti + 3; if (hi > 32) hi = 32;
    k0 = lo * 128; k1 = hi * 128;
    a_koff = (ti - 2) * 128;
    Bb = B + (size_t)by * 128 * ldb + s * NSEQ;
  }

  const int t = threadIdx.x;
  const int l = t & 63;
  const int w = t >> 6;
  const int fr = l & 15;
  const int quad = l >> 4;
  const int wm = (w >> 1) * 64;
  const int wn = (w & 1) * 64;
  const int fq4 = quad * 4;

  // staging: 4 insts per matrix per wave; inst j covers rows w*32+j*8 .. +7
  int srow[4], scg[4], sloff[4];
#pragma unroll
  for (int j = 0; j < 4; j++) {
    srow[j] = w * 32 + j * 8 + (l >> 3);
    scg[j] = ((l & 7) - srow[j]) & 7;       // global chunk for LDS slot l&7
    sloff[j] = (w * 32 + j * 8) * 128 + l * 16;
  }

  f32x4 acc[4][4];
#pragma unroll
  for (int m = 0; m < 4; m++)
#pragma unroll
    for (int n = 0; n < 4; n++) acc[m][n] = (f32x4){0.f, 0.f, 0.f, 0.f};

  for (int kk = k0; kk < k1; kk += 128) {
    int ka = kk - a_koff;
    __syncthreads();
#pragma unroll
    for (int j = 0; j < 4; j++)
      __builtin_amdgcn_global_load_lds(
          (gvoid_t*)(Ab + (size_t)srow[j] * lda + ka + scg[j] * 16),
          (lvoid_t*)(As + sloff[j]), 16, 0, 0);
#pragma unroll
    for (int j = 0; j < 4; j++)
      __builtin_amdgcn_global_load_lds(
          (gvoid_t*)(Bb + (size_t)srow[j] * ldb + kk + scg[j] * 16),
          (lvoid_t*)(Bs + sloff[j]), 16, 0, 0);
    __syncthreads();
#pragma unroll
    for (int kb = 0; kb < 4; kb++) {
      long af[4], bf[4];
      int cbase = 2 * kb + (quad >> 1);
      int dsub = (quad & 1) * 8;
#pragma unroll
      for (int m = 0; m < 4; m++) {
        int r = wm + m * 16 + fr;
        int slot = (cbase + r) & 7;
        af[m] = *(const long*)(As + r * 128 + slot * 16 + dsub);
      }
#pragma unroll
      for (int n = 0; n < 4; n++) {
        int r = wn + n * 16 + fr;
        int slot = (cbase + r) & 7;
        bf[n] = *(const long*)(Bs + r * 128 + slot * 16 + dsub);
      }
#pragma unroll
      for (int m = 0; m < 4; m++)
#pragma unroll
        for (int n = 0; n < 4; n++)
          acc[m][n] = __builtin_amdgcn_mfma_f32_16x16x32_fp8_fp8(af[m], bf[n], acc[m][n], 0, 0, 0);
    }
  }

  if (okind == 1) {
    // bf16 out via LDS (32 KB tile), optional exp
    __syncthreads();
    unsigned short* sm16 = (unsigned short*)smem;
#pragma unroll
    for (int m = 0; m < 4; m++) {
#pragma unroll
      for (int n = 0; n < 4; n++) {
        int colb = wn + n * 16 + fr;
        float bv = bias ? bias[ccol0 + colb] : 0.f;
#pragma unroll
        for (int r = 0; r < 4; r++) {
          int row = wm + m * 16 + fq4 + r;
          float v = acc[m][n][r] * alpha + bv;
          if (do_exp) v = __expf(v);
          if (relu) v = fmaxf(v, 0.f);
          int cc = ((colb >> 3) + row) & 15;
          sm16[row * 128 + cc * 8 + (colb & 7)] = f2b(v);
        }
      }
    }
    __syncthreads();
    unsigned short* Cp = (unsigned short*)Cdst;
    for (int i = t; i < 2048; i += 256) {
      int row = i >> 4, lc = i & 15;
      int pc = (lc + row) & 15;
      uint4 v = *(const uint4*)(sm16 + row * 128 + pc * 8);
      *(uint4*)(Cp + (size_t)(crow0 + row) * ldce + ccol0 + lc * 8) = v;
    }
  } else if (okind == 2) {
    // fp8 out via LDS (16 KB tile)
    __syncthreads();
#pragma unroll
    for (int m = 0; m < 4; m++) {
#pragma unroll
      for (int n = 0; n < 4; n++) {
        int colb = wn + n * 16 + fr;
        float bv = bias ? bias[ccol0 + colb] : 0.f;
#pragma unroll
        for (int r = 0; r < 4; r++) {
          int row = wm + m * 16 + fq4 + r;
          float v = acc[m][n][r] * alpha + bv;
          if (relu) v = fmaxf(v, 0.f);
          int sl = ((colb >> 4) + row) & 7;
          smem[row * 128 + sl * 16 + (colb & 15)] = f2e4(v);
        }
      }
    }
    __syncthreads();
    unsigned char* Cp = (unsigned char*)Cdst;
    for (int i = t; i < 1024; i += 256) {
      int row = i >> 3, lc = i & 7;
      int pc = (lc + row) & 7;
      uint4 v = *(const uint4*)(smem + row * 128 + pc * 16);
      *(uint4*)(Cp + (size_t)(crow0 + row) * ldce + ccol0 + lc * 16) = v;
    }
  } else {
    float* Cp = (float*)Cdst;
#pragma unroll
    for (int m = 0; m < 4; m++) {
#pragma unroll
      for (int n = 0; n < 4; n++) {
        int colb = wn + n * 16 + fr;
        float bv = bias ? bias[ccol0 + colb] : 0.f;
#pragma unroll
        for (int r = 0; r < 4; r++) {
          int row = wm + m * 16 + fq4 + r;
          float v = acc[m][n][r] * alpha + bv;
          if (relu) v = fmaxf(v, 0.f);
          Cp[(size_t)(crow0 + row) * ldce + ccol0 + colb] = v;
        }
      }
    }
  }
}

// -------- small bf16 GEMM: 64x64 tile, BK=64 (MLP head, accuracy-critical) --------
__global__ __launch_bounds__(256) void k_gemm64(
    const unsigned short* __restrict__ A, int lda,
    const unsigned short* __restrict__ B, int ldb,
    void* __restrict__ Cout, int ldc, int K,
    const float* __restrict__ bias, int relu, int out_bf16) {
  __shared__ unsigned short smem[2 * 64 * 64];
  unsigned short* As = smem;
  unsigned short* Bs = smem + 64 * 64;
  int bx = blockIdx.x, by = blockIdx.y;
  const unsigned short* Ab = A + (size_t)bx * 64 * lda;
  const unsigned short* Bb = B + (size_t)by * 64 * ldb;
  int crow0 = bx * 64, ccol0 = by * 64;

  const int t = threadIdx.x;
  const int l = t & 63;
  const int w = t >> 6;
  const int fr = l & 15;
  const int quad = l >> 4;
  const int wm = (w & 1) * 32;
  const int wn = (w >> 1) * 32;
  const int fq4 = quad * 4;

  int srow[2], scg[2], sloff[2];
#pragma unroll
  for (int j = 0; j < 2; j++) {
    srow[j] = w * 16 + j * 8 + (l >> 3);
    scg[j] = ((l & 7) - srow[j]) & 7;
    sloff[j] = (w * 16 + j * 8) * 64 + l * 8;
  }

  f32x4 acc[2][2];
#pragma unroll
  for (int m = 0; m < 2; m++)
#pragma unroll
    for (int n = 0; n < 2; n++) acc[m][n] = (f32x4){0.f, 0.f, 0.f, 0.f};

  for (int kk = 0; kk < K; kk += 64) {
    __syncthreads();
#pragma unroll
    for (int j = 0; j < 2; j++)
      __builtin_amdgcn_global_load_lds(
          (gvoid_t*)(Ab + (size_t)srow[j] * lda + kk + scg[j] * 8),
          (lvoid_t*)(As + sloff[j]), 16, 0, 0);
#pragma unroll
    for (int j = 0; j < 2; j++)
      __builtin_amdgcn_global_load_lds(
          (gvoid_t*)(Bb + (size_t)srow[j] * ldb + kk + scg[j] * 8),
          (lvoid_t*)(Bs + sloff[j]), 16, 0, 0);
    __syncthreads();
#pragma unroll
    for (int s = 0; s < 2; s++) {
      short8 af[2], bf[2];
#pragma unroll
      for (int m = 0; m < 2; m++) {
        int r = wm + m * 16 + fr;
        int slot = (s * 4 + quad + r) & 7;
        af[m] = *(const short8*)(As + r * 64 + slot * 8);
      }
#pragma unroll
      for (int n = 0; n < 2; n++) {
        int r = wn + n * 16 + fr;
        int slot = (s * 4 + quad + r) & 7;
        bf[n] = *(const short8*)(Bs + r * 64 + slot * 8);
      }
#pragma unroll
      for (int m = 0; m < 2; m++)
#pragma unroll
        for (int n = 0; n < 2; n++)
          acc[m][n] = __builtin_amdgcn_mfma_f32_16x16x32_bf16(af[m], bf[n], acc[m][n], 0, 0, 0);
    }
  }

  if (out_bf16) {
    __syncthreads();
#pragma unroll
    for (int m = 0; m < 2; m++) {
#pragma unroll
      for (int n = 0; n < 2; n++) {
        int colb = wn + n * 16 + fr;
        float bv = bias ? bias[ccol0 + colb] : 0.f;
#pragma unroll
        for (int r = 0; r < 4; r++) {
          int row = wm + m * 16 + fq4 + r;
          float v = acc[m][n][r] + bv;
          if (relu) v = fmaxf(v, 0.f);
          int cc = ((colb >> 3) + row) & 7;
          smem[row * 64 + cc * 8 + (colb & 7)] = f2b(v);
        }
      }
    }
    __syncthreads();
    unsigned short* Cp = (unsigned short*)Cout;
    for (int i = t; i < 512; i += 256) {
      int row = i >> 3, lc = i & 7;
      int pc = (lc + row) & 7;
      uint4 v = *(const uint4*)(smem + row * 64 + pc * 8);
      *(uint4*)(Cp + (size_t)(crow0 + row) * ldc + ccol0 + lc * 8) = v;
    }
  } else {
    float* Cp = (float*)Cout;
#pragma unroll
    for (int m = 0; m < 2; m++) {
#pragma unroll
      for (int n = 0; n < 2; n++) {
        int colb = wn + n * 16 + fr;
        float bv = bias ? bias[ccol0 + colb] : 0.f;
#pragma unroll
        for (int r = 0; r < 4; r++) {
          int row = wm + m * 16 + fq4 + r;
          float v = acc[m][n][r] + bv;
          if (relu) v = fmaxf(v, 0.f);
          Cp[(size_t)(crow0 + row) * ldc + ccol0 + colb] = v;
        }
      }
    }
  }
}

// -------- per-row softmax denominator: sums[i] = sum of E over the band --------
__global__ __launch_bounds__(256) void k_stats(const unsigned short* __restrict__ Eband,
                                               float* __restrict__ sums) {
  int ig = blockIdx.x * 4 + (threadIdx.x >> 6);   // global row 0..12287
  int lane = threadIdx.x & 63;
  int i = ig & 4095;
  int ti = i >> 7;
  int cbase = (ti - 2) * 128;
  int jlo = i - 249; if (jlo < 0) jlo = 0;
  int jhi = i + 249; if (jhi > NSEQ - 1) jhi = NSEQ - 1;
  int clo = jlo - cbase, chi = jhi - cbase;
  const unsigned short* L = Eband + (size_t)ig * 640;
  float s = 0.f;
  for (int c = clo + lane; c <= chi; c += 64) s += b2f(L[c]);
  for (int off = 32; off; off >>= 1) s += __shfl_xor(s, off);
  if (lane == 0) sums[ig] = s;
}

// -------- build banded attT (fp8 x16): attT_s[i][j - 128*((i>>7)-2)] = 16*att[j][i] --------
__global__ __launch_bounds__(256) void k_build_attT(const unsigned short* __restrict__ Eband,
                                                    const float* __restrict__ sums,
                                                    unsigned char* __restrict__ t0,
                                                    unsigned char* __restrict__ t1,
                                                    unsigned char* __restrict__ t2) {
  int byy = blockIdx.y;
  int s = byy >> 5, ti = byy & 31;       // i tile (attT rows), local
  int tj = ti + (int)blockIdx.x - 2;     // j tile
  if (tj < 0 || tj >= 32) return;
  unsigned char* dst = (s == 0) ? t0 : ((s == 1) ? t1 : t2);
  __shared__ unsigned char T[128][132];  // T[i_loc][j_loc]
  int t = threadIdx.x;
  int c0 = (ti - tj + 2) * 128;  // Eband col base for rows j reading i-tile ti
  int colg = (t & 31) * 4;       // i_loc
  for (int jj = t >> 5; jj < 128; jj += 8) {
    int jg = s * NSEQ + tj * 128 + jj;
    float inv = 16.f / sums[jg];
    ushort4 v = *(const ushort4*)&Eband[(size_t)jg * 640 + c0 + colg];
    float vv[4] = {b2f(v.x), b2f(v.y), b2f(v.z), b2f(v.w)};
#pragma unroll
    for (int q = 0; q < 4; q++) {
      int i = ti * 128 + colg + q;
      int d = i - (tj * 128 + jj);
      float a = (d < 250 && d > -250) ? vv[q] * inv : 0.f;
      T[colg + q][jj] = f2e4(a);
    }
  }
  __syncthreads();
  int jb0 = (tj - ti + 2) * 128;  // banded col base in attT rows of tile ti
  for (int ii = t >> 5; ii < 128; ii += 8) {
    size_t o = (size_t)(ti * 128 + ii) * 640 + jb0 + colg;
    *(unsigned int*)(dst + o) = *(const unsigned int*)&T[ii][colg];
  }
}

// -------- write full fp32 att (stream 0 / x1), zeros outside band --------
__global__ __launch_bounds__(256) void k_write_att(const unsigned short* __restrict__ Eband,
                                                   const float* __restrict__ sums,
                                                   float* __restrict__ att) {
  int i = blockIdx.x;
  int ti = i >> 7, cbase = (ti - 2) * 128;
  int jlo = i - 249; if (jlo < 0) jlo = 0;
  int jhi = i + 249; if (jhi > NSEQ - 1) jhi = NSEQ - 1;
  float inv = 1.f / sums[i];
  const unsigned short* L = Eband + (size_t)i * 640;
  float* arow = att + (size_t)i * NSEQ;
  for (int j0 = threadIdx.x * 4; j0 < NSEQ; j0 += 1024) {
    float ov[4];
#pragma unroll
    for (int q = 0; q < 4; q++) {
      int j = j0 + q;
      ov[q] = (j >= jlo && j <= jhi) ? b2f(L[j - cbase]) * inv : 0.f;
    }
    *(float4*)(arow + j0) = make_float4(ov[0], ov[1], ov[2], ov[3]);
  }
}

// -------- residual + LayerNorm (ddof=1, eps on std) for 3 streams, sum -> bf16 --------
__global__ __launch_bounds__(256) void k_ln3(const unsigned short* __restrict__ yo,
                                             const float* __restrict__ x1,
                                             const float* __restrict__ x2,
                                             const float* __restrict__ x3,
                                             const float* __restrict__ g,
                                             const float* __restrict__ b,
                                             unsigned short* __restrict__ ysum_b) {
  int i = blockIdx.x, t = threadIdx.x;
  int w = t >> 6, lane = t & 63;
  __shared__ float red[8];
  const float* xs[3] = {x1, x2, x3};
  float4 gg = *(const float4*)(g + t * 4);
  float4 bb = *(const float4*)(b + t * 4);
  float acc[4] = {0.f, 0.f, 0.f, 0.f};
  for (int s = 0; s < 3; s++) {
    ushort4 yv = *(const ushort4*)(yo + ((size_t)(s * NSEQ + i)) * MDIM + t * 4);
    float4 xx = *(const float4*)(xs[s] + (size_t)i * MDIM + t * 4);
    float v[4] = {b2f(yv.x) + xx.x, b2f(yv.y) + xx.y, b2f(yv.z) + xx.z, b2f(yv.w) + xx.w};
    float s1 = v[0] + v[1] + v[2] + v[3];
    float s2 = v[0]*v[0] + v[1]*v[1] + v[2]*v[2] + v[3]*v[3];
    for (int off = 32; off; off >>= 1) { s1 += __shfl_xor(s1, off); s2 += __shfl_xor(s2, off); }
    __syncthreads();
    if (lane == 0) { red[w] = s1; red[4 + w] = s2; }
    __syncthreads();
    float S1 = red[0] + red[1] + red[2] + red[3];
    float S2 = red[4] + red[5] + red[6] + red[7];
    float mean = S1 * (1.f / 1024.f);
    float var = (S2 - S1 * mean) * (1.f / 1023.f);
    float rstd = 1.f / (sqrtf(var) + 1e-6f);
    acc[0] += gg.x * (v[0] - mean) * rstd + bb.x;
    acc[1] += gg.y * (v[1] - mean) * rstd + bb.y;
    acc[2] += gg.z * (v[2] - mean) * rstd + bb.z;
    acc[3] += gg.w * (v[3] - mean) * rstd + bb.w;
  }
  ushort4 o;
  o.x = f2b(acc[0]); o.y = f2b(acc[1]); o.z = f2b(acc[2]); o.w = f2b(acc[3]);
  *(ushort4*)(ysum_b + (size_t)i * MDIM + t * 4) = o;
}

// -------- final: LN(128, gkc/bkc) -> dot(kd_w) + kd_b -> sigmoid --------
__global__ __launch_bounds__(128) void k_final(const float* __restrict__ h3,
                                               const float* __restrict__ g,
                                               const float* __restrict__ b,
                                               const float* __restrict__ kdw,
                                               const float* __restrict__ kdb,
                                               float* __restrict__ yout) {
  int i = blockIdx.x, t = threadIdx.x;
  float v = h3[(size_t)i * 128 + t];
  float s1 = v, s2 = v * v;
  for (int off = 32; off; off >>= 1) { s1 += __shfl_xor(s1, off); s2 += __shfl_xor(s2, off); }
  __shared__ float red[4];
  int w = t >> 6, lane = t & 63;
  if (lane == 0) { red[w] = s1; red[2 + w] = s2; }
  __syncthreads();
  float S1 = red[0] + red[1], S2 = red[2] + red[3];
  float mean = S1 * (1.f / 128.f);
  float var = (S2 - S1 * mean) * (1.f / 127.f);
  float rstd = 1.f / (sqrtf(var) + 1e-6f);
  float ln = g[t] * (v - mean) * rstd + b[t];
  float p = ln * kdw[t];
  for (int off = 32; off; off >>= 1) p += __shfl_xor(p, off);
  __syncthreads();
  if (lane == 0) red[w] = p;
  __syncthreads();
  if (t == 0) {
    float z = red[0] + red[1] + kdb[0];
    yout[i] = 1.f / (1.f + __expf(-z));
  }
}

extern "C" void kernel_launch(void* const* d_in, const int* in_sizes, int n_in,
                              void* d_out, int out_size, void* d_ws, size_t ws_size,
                              hipStream_t stream) {
  const float* x1 = (const float*)d_in[0];
  const float* x2 = (const float*)d_in[1];
  const float* x3 = (const float*)d_in[2];
  const float* Wq = (const float*)d_in[3];
  const float* Wk = (const float*)d_in[4];
  const float* Wv = (const float*)d_in[5];
  const float* Wo = (const float*)d_in[6];
  const float* ka_w = (const float*)d_in[7];
  const float* ka_b = (const float*)d_in[8];
  const float* kb_w = (const float*)d_in[9];
  const float* kb_b = (const float*)d_in[10];
  const float* kc_w = (const float*)d_in[11];
  const float* kc_b = (const float*)d_in[12];
  const float* kd_w = (const float*)d_in[13];
  const float* kd_b = (const float*)d_in[14];
  const float* g13 = (const float*)d_in[15];
  const float* b13 = (const float*)d_in[16];
  const float* gkc = (const float*)d_in[17];
  const float* bkc = (const float*)d_in[18];

  float* y_out = (float*)d_out;
  float* att_out = y_out + NSEQ;  // [4096,4096] fp32

  char* ws = (char*)d_ws;
  size_t off = 0;
  auto alloc = [&](size_t bytes) -> void* {
    void* p = ws + off;
    off += (bytes + 255) & ~(size_t)255;
    return p;
  };
  const size_t NM = (size_t)3 * NSEQ * MDIM;  // 12.6M elems
  // fp8 attention weights, contiguous: Wq|Wk|Wv|Wo (x64 scaled)
  unsigned char* Wf = (unsigned char*)alloc(4 * 1048576);
  // bf16 MLP weights, contiguous: ka|kb|kc
  unsigned short* Wmlp = (unsigned short*)alloc((1048576 + 524288 + 65536) * 2);
  unsigned char* Xf = (unsigned char*)alloc(NM);      // later: yb fp8, then h1b bf16
  unsigned char* Qf = (unsigned char*)alloc(NM);      // yo bf16 spans Qf+Kf; later h2b
  unsigned char* Kf = (unsigned char*)alloc(NM);
  unsigned char* VTf = (unsigned char*)alloc(NM);     // later: ysum_b bf16 (8MB)
  unsigned short* Eband = (unsigned short*)alloc((size_t)3 * NSEQ * 640 * 2);
  float* sums = (float*)alloc((size_t)3 * NSEQ * 4);
  unsigned char* aT0 = (unsigned char*)alloc((size_t)NSEQ * 640);  // later: h3 f32
  unsigned char* aT1 = (unsigned char*)alloc((size_t)NSEQ * 640);
  unsigned char* aT2 = (unsigned char*)alloc((size_t)NSEQ * 640);
  // weight sub-pointers
  unsigned char* Wv_f = Wf + 2097152;
  unsigned char* Wo_f = Wf + 3145728;
  unsigned short* ka_b16 = Wmlp;
  unsigned short* kb_b16 = Wmlp + 1048576;
  unsigned short* kc_b16 = Wmlp + 1572864;
  // aliases (lifetimes disjoint)
  unsigned char* yb = Xf;                       // fp8 [12288,1024] = 8*y
  unsigned short* yo = (unsigned short*)Qf;     // bf16 [12288,1024] spans Qf..Kf
  unsigned short* ysum_b = (unsigned short*)VTf;// bf16 [4096,1024]
  unsigned short* h1b = (unsigned short*)Xf;    // bf16 [4096,1024]
  unsigned short* h2b = (unsigned short*)Qf;    // bf16 [4096,512]
  float* h3 = (float*)aT0;                      // f32 [4096,128]

  // all conversions in one dispatch
  k_cvt_all<<<17984, 256, 0, stream>>>(Wq, Wk, Wv, Wo, ka_w, kb_w, kc_w,
                                       x1, x2, x3, Wf, Wmlp, Xf);

  // merged Q+K+VT fp8 (alpha 1/64; 0.06 deferred to logits)
  k_gemm<<<dim3(96, 24), 256, 0, stream>>>(Xf, 1024, Wf, 1024, Qf, Kf, 1024,
                                           1024, 1.f / 64.f, nullptr, 0, 2, 0, 3,
                                           Wv_f, VTf);
  // banded logits -> E = exp(0.06 * Q.K) bf16 [12288,640]
  k_gemm<<<dim3(96, 5), 256, 0, stream>>>(Qf, 1024, Kf, 1024, Eband, nullptr, 640,
                                          1024, 0.06f, nullptr, 0, 1, 1, 1,
                                          nullptr, nullptr);
  k_stats<<<3072, 256, 0, stream>>>(Eband, sums);
  k_build_attT<<<dim3(5, 96), 256, 0, stream>>>(Eband, sums, aT0, aT1, aT2);
  // yb = 8*y: (16att)@V * 0.5, fp8 out
  k_gemm<<<dim3(96, 8), 256, 0, stream>>>(aT0, 640, VTf, 3 * NSEQ, yb, nullptr, 1024,
                                          NSEQ, 0.5f, nullptr, 0, 2, 0, 2,
                                          aT1, aT2);
  k_write_att<<<4096, 256, 0, stream>>>(Eband, sums, att_out);
  // yo = y @ Wo^T (bf16 out): (8y)@(64Wo) * 1/512
  k_gemm<<<dim3(96, 8), 256, 0, stream>>>(yb, 1024, Wo_f, 1024, yo, nullptr, 1024,
                                          1024, 1.f / 512.f, nullptr, 0, 1, 0, 0,
                                          nullptr, nullptr);
  // residual + LN + 3-stream sum -> bf16
  k_ln3<<<4096, 256, 0, stream>>>(yo, x1, x2, x3, g13, b13, ysum_b);

  // MLP head (bf16, 64x64 tiles)
  k_gemm64<<<dim3(64, 16), 256, 0, stream>>>(ysum_b, 1024, ka_b16, 1024, h1b, 1024,
                                             1024, ka_b, 0, 1);
  k_gemm64<<<dim3(64, 8), 256, 0, stream>>>(h1b, 1024, kb_b16, 1024, h2b, 512,
                                            1024, kb_b, 0, 1);
  k_gemm64<<<dim3(64, 2), 256, 0, stream>>>(h2b, 512, kc_b16, 512, h3, 128,
                                            512, kc_b, 1, 0);
  k_final<<<4096, 128, 0, stream>>>(h3, gkc, bkc, kd_w, kd_b, y_out);
}

// Round 8
// 372.086 us; speedup vs baseline: 2.3247x; 1.0358x over previous
//
#include <hip/hip_runtime.h>
#include <hip/hip_bf16.h>
#include <cstdint>
#include <cstddef>

// Problem constants
#define NSEQ 4096
#define MDIM 1024
// band: |i-j| < 250 -> row-tile ti needs col-tiles [ti-2, ti+2]
// banded layout (Eband bf16 = exp(logits), attT fp8 x16): row i, col c = j - 128*((i>>7)-2), width 640
// fp8 scaling: attn weights x64, attT x16, y stored x8; MLP kept bf16 for accuracy.
// fp8 frag reads: ds_read_b128 of one 16B slot = 2 MFMAs (low/high 8B); K-order is
// permuted identically for A and B (chunk cq = quad*2+kb2, slot (cq+r)&7) -> exact
// result, conflict-free banks (replicates the measured-clean bf16 pattern).

typedef __attribute__((ext_vector_type(8))) short short8;
typedef __attribute__((ext_vector_type(4))) float f32x4;
typedef __attribute__((ext_vector_type(2))) long long2v;

typedef const __attribute__((address_space(1))) void gvoid_t;
typedef __attribute__((address_space(3))) void lvoid_t;

__device__ __forceinline__ unsigned short f2b(float x) {
  union { float f; unsigned int u; } a; a.f = x;
  unsigned int r = (a.u + 0x7fffu + ((a.u >> 16) & 1u)) >> 16;
  return (unsigned short)r;
}
__device__ __forceinline__ float b2f(unsigned short u) {
  union { float f; unsigned int u32; } a; a.u32 = ((unsigned int)u) << 16;
  return a.f;
}
__device__ __forceinline__ unsigned char f2e4(float x) {
  return (unsigned char)(__builtin_amdgcn_cvt_pk_fp8_f32(x, x, 0, false) & 0xff);
}
__device__ __forceinline__ unsigned int f2e4x4(float a, float b, float c, float d) {
  unsigned int lo = __builtin_amdgcn_cvt_pk_fp8_f32(a, b, 0, false);
  return (unsigned int)__builtin_amdgcn_cvt_pk_fp8_f32(c, d, lo, true);
}

// -------- merged cvt: Wq..Wo (x64)->fp8, ka/kb/kc->bf16, x1..x3->fp8 --------
__global__ __launch_bounds__(256) void k_cvt_all(
    const float* __restrict__ s0, const float* __restrict__ s1,
    const float* __restrict__ s2, const float* __restrict__ s3,
    const float* __restrict__ s4, const float* __restrict__ s5,
    const float* __restrict__ s6,
    const float* __restrict__ xa, const float* __restrict__ xb,
    const float* __restrict__ xc,
    unsigned char* __restrict__ Wf8, unsigned short* __restrict__ Wmlp,
    unsigned char* __restrict__ Xdst) {
  int idx = blockIdx.x * 256 + threadIdx.x;  // chunk of 4 floats
  if (idx < 1048576) {  // Wq,Wk,Wv,Wo fp8 x64
    int seg = idx >> 18, local = idx & 262143;
    const float* src = (seg == 0) ? s0 : (seg == 1) ? s1 : (seg == 2) ? s2 : s3;
    float4 v = *(const float4*)(src + (size_t)local * 4);
    *(unsigned int*)(Wf8 + (size_t)idx * 4) =
        f2e4x4(v.x * 64.f, v.y * 64.f, v.z * 64.f, v.w * 64.f);
  } else if (idx < 1458176) {  // ka,kb,kc bf16
    int i2 = idx - 1048576;
    const float* src; int local;
    if (i2 < 262144) { src = s4; local = i2; }
    else if (i2 < 393216) { src = s5; local = i2 - 262144; }
    else { src = s6; local = i2 - 393216; }
    float4 v = *(const float4*)(src + (size_t)local * 4);
    ushort4 o; o.x = f2b(v.x); o.y = f2b(v.y); o.z = f2b(v.z); o.w = f2b(v.w);
    *(ushort4*)(Wmlp + (size_t)i2 * 4) = o;
  } else {  // x1..x3 fp8
    int i2 = idx - 1458176;   // 0 .. 3*2^20-1
    int seg = i2 >> 20, local = i2 & 1048575;
    const float* src = (seg == 0) ? xa : (seg == 1) ? xb : xc;
    float4 v = *(const float4*)(src + (size_t)local * 4);
    *(unsigned int*)(Xdst + (size_t)i2 * 4) = f2e4x4(v.x, v.y, v.z, v.w);
  }
}

// -------- fp8 GEMM: C = alpha*(A @ B^T) + bias, A[M,K] fp8, B[N,K] fp8 --------
// BK=128, global_load_lds 16B staging. LDS row = 128 B = 8 slots of 16B;
// slot s holds global 16B-chunk (s-r)&7. Frag reads: b128 slot reads, 2 MFMAs each
// (K-permuted consistently for A/B). grid.x (mult of 8) indexes the large shared
// operand (XCD co-location).
// okind: 0=f32 out, 1=bf16 out (do_exp: v=exp(v)), 2=fp8 out.
// mode 3: merged QKV, grid (96,24). by<8: Q; 8..15: K (Cout2); >=16: VT=Wv@X^T
//         (A1=Wv, out A2 fp8 [1024,12288]).
// mode 0: bx=A row tile, by=B col tile.
// mode 1: banded logits -> Eband (exp, bf16) [12288,640], grid (96,5).
// mode 2: attT(banded fp8,lda=640) @ VT, grid (96,8): K window
//         [max(ti-2,0),min(ti+3,32))*128, B col base s*4096.
__global__ __launch_bounds__(256) void k_gemm(
    const unsigned char* __restrict__ A, int lda,
    const unsigned char* __restrict__ B, int ldb,
    void* __restrict__ Cout, void* __restrict__ Cout2, int ldc,
    int K, float alpha,
    const float* __restrict__ bias, int relu, int okind, int do_exp, int mode,
    const unsigned char* __restrict__ A1, const unsigned char* __restrict__ A2) {
  __shared__ unsigned char smem[2 * 128 * 128];  // 32 KB
  unsigned char* As = smem;
  unsigned char* Bs = smem + 128 * 128;
  int bx = blockIdx.x, by = blockIdx.y;
  const unsigned char* Ab;
  const unsigned char* Bb;
  void* Cdst = Cout;
  int k0 = 0, k1 = K, a_koff = 0;
  int ldce = ldc;
  int crow0 = bx * 128, ccol0 = by * 128;
  if (mode == 0) {
    Ab = A + (size_t)bx * 128 * lda;
    Bb = B + (size_t)by * 128 * ldb;
  } else if (mode == 3) {
    if (by < 16) {
      Ab = A + (size_t)bx * 128 * lda;
      Bb = B + (size_t)by * 128 * ldb;
      if (by >= 8) Cdst = Cout2;
      ccol0 = (by & 7) * 128;
    } else {
      Ab = A1 + (size_t)(by - 16) * 128 * 1024;   // Wv rows
      Bb = A + (size_t)bx * 128 * lda;            // X rows
      Cdst = (void*)const_cast<unsigned char*>(A2);
      crow0 = (by - 16) * 128; ccol0 = bx * 128;
      ldce = 3 * NSEQ;
    }
  } else if (mode == 1) {
    int s = bx >> 5, ti = bx & 31;
    int bt = ti + by - 2;
    if (bt < 0 || bt >= 32) return;
    Ab = A + (size_t)bx * 128 * lda;
    Bb = B + (size_t)(s * 32 + bt) * 128 * ldb;
  } else {  // mode 2
    int s = bx >> 5, ti = bx & 31;
    const unsigned char* Abase = (s == 0) ? A : ((s == 1) ? A1 : A2);
    Ab = Abase + (size_t)ti * 128 * lda;  // lda = 640
    int lo = ti - 2; if (lo < 0) lo = 0;
    int hi = ti + 3; if (hi > 32) hi = 32;
    k0 = lo * 128; k1 = hi * 128;
    a_koff = (ti - 2) * 128;
    Bb = B + (size_t)by * 128 * ldb + s * NSEQ;
  }

  const int t = threadIdx.x;
  const int l = t & 63;
  const int w = t >> 6;
  const int fr = l & 15;
  const int quad = l >> 4;
  const int wm = (w >> 1) * 64;
  const int wn = (w & 1) * 64;
  const int fq4 = quad * 4;

  // staging: 4 insts per matrix per wave; inst j covers rows w*32+j*8 .. +7
  int srow[4], scg[4], sloff[4];
#pragma unroll
  for (int j = 0; j < 4; j++) {
    srow[j] = w * 32 + j * 8 + (l >> 3);
    scg[j] = ((l & 7) - srow[j]) & 7;       // global chunk for LDS slot l&7
    sloff[j] = (w * 32 + j * 8) * 128 + l * 16;
  }

  f32x4 acc[4][4];
#pragma unroll
  for (int m = 0; m < 4; m++)
#pragma unroll
    for (int n = 0; n < 4; n++) acc[m][n] = (f32x4){0.f, 0.f, 0.f, 0.f};

  for (int kk = k0; kk < k1; kk += 128) {
    int ka = kk - a_koff;
    __syncthreads();
#pragma unroll
    for (int j = 0; j < 4; j++)
      __builtin_amdgcn_global_load_lds(
          (gvoid_t*)(Ab + (size_t)srow[j] * lda + ka + scg[j] * 16),
          (lvoid_t*)(As + sloff[j]), 16, 0, 0);
#pragma unroll
    for (int j = 0; j < 4; j++)
      __builtin_amdgcn_global_load_lds(
          (gvoid_t*)(Bb + (size_t)srow[j] * ldb + kk + scg[j] * 16),
          (lvoid_t*)(Bs + sloff[j]), 16, 0, 0);
    __syncthreads();
#pragma unroll
    for (int kb2 = 0; kb2 < 2; kb2++) {
      long2v a16[4], b16[4];
      int cq = quad * 2 + kb2;   // logical chunk for this lane, this MFMA pair
#pragma unroll
      for (int m = 0; m < 4; m++) {
        int r = wm + m * 16 + fr;
        int slot = (cq + r) & 7;
        a16[m] = *(const long2v*)(As + r * 128 + slot * 16);
      }
#pragma unroll
      for (int n = 0; n < 4; n++) {
        int r = wn + n * 16 + fr;
        int slot = (cq + r) & 7;
        b16[n] = *(const long2v*)(Bs + r * 128 + slot * 16);
      }
#pragma unroll
      for (int m = 0; m < 4; m++)
#pragma unroll
        for (int n = 0; n < 4; n++)
          acc[m][n] = __builtin_amdgcn_mfma_f32_16x16x32_fp8_fp8(a16[m].x, b16[n].x, acc[m][n], 0, 0, 0);
#pragma unroll
      for (int m = 0; m < 4; m++)
#pragma unroll
        for (int n = 0; n < 4; n++)
          acc[m][n] = __builtin_amdgcn_mfma_f32_16x16x32_fp8_fp8(a16[m].y, b16[n].y, acc[m][n], 0, 0, 0);
    }
  }

  if (okind == 1) {
    // bf16 out via LDS (32 KB tile), optional exp
    __syncthreads();
    unsigned short* sm16 = (unsigned short*)smem;
#pragma unroll
    for (int m = 0; m < 4; m++) {
#pragma unroll
      for (int n = 0; n < 4; n++) {
        int colb = wn + n * 16 + fr;
        float bv = bias ? bias[ccol0 + colb] : 0.f;
#pragma unroll
        for (int r = 0; r < 4; r++) {
          int row = wm + m * 16 + fq4 + r;
          float v = acc[m][n][r] * alpha + bv;
          if (do_exp) v = __expf(v);
          if (relu) v = fmaxf(v, 0.f);
          int cc = ((colb >> 3) + row) & 15;
          sm16[row * 128 + cc * 8 + (colb & 7)] = f2b(v);
        }
      }
    }
    __syncthreads();
    unsigned short* Cp = (unsigned short*)Cdst;
    for (int i = t; i < 2048; i += 256) {
      int row = i >> 4, lc = i & 15;
      int pc = (lc + row) & 15;
      uint4 v = *(const uint4*)(sm16 + row * 128 + pc * 8);
      *(uint4*)(Cp + (size_t)(crow0 + row) * ldce + ccol0 + lc * 8) = v;
    }
  } else if (okind == 2) {
    // fp8 out via LDS (16 KB tile)
    __syncthreads();
#pragma unroll
    for (int m = 0; m < 4; m++) {
#pragma unroll
      for (int n = 0; n < 4; n++) {
        int colb = wn + n * 16 + fr;
        float bv = bias ? bias[ccol0 + colb] : 0.f;
#pragma unroll
        for (int r = 0; r < 4; r++) {
          int row = wm + m * 16 + fq4 + r;
          float v = acc[m][n][r] * alpha + bv;
          if (relu) v = fmaxf(v, 0.f);
          int sl = ((colb >> 4) + row) & 7;
          smem[row * 128 + sl * 16 + (colb & 15)] = f2e4(v);
        }
      }
    }
    __syncthreads();
    unsigned char* Cp = (unsigned char*)Cdst;
    for (int i = t; i < 1024; i += 256) {
      int row = i >> 3, lc = i & 7;
      int pc = (lc + row) & 7;
      uint4 v = *(const uint4*)(smem + row * 128 + pc * 16);
      *(uint4*)(Cp + (size_t)(crow0 + row) * ldce + ccol0 + lc * 16) = v;
    }
  } else {
    float* Cp = (float*)Cdst;
#pragma unroll
    for (int m = 0; m < 4; m++) {
#pragma unroll
      for (int n = 0; n < 4; n++) {
        int colb = wn + n * 16 + fr;
        float bv = bias ? bias[ccol0 + colb] : 0.f;
#pragma unroll
        for (int r = 0; r < 4; r++) {
          int row = wm + m * 16 + fq4 + r;
          float v = acc[m][n][r] * alpha + bv;
          if (relu) v = fmaxf(v, 0.f);
          Cp[(size_t)(crow0 + row) * ldce + ccol0 + colb] = v;
        }
      }
    }
  }
}

// -------- small bf16 GEMM: 64x64 tile, BK=64 (MLP head, accuracy-critical) --------
__global__ __launch_bounds__(256) void k_gemm64(
    const unsigned short* __restrict__ A, int lda,
    const unsigned short* __restrict__ B, int ldb,
    void* __restrict__ Cout, int ldc, int K,
    const float* __restrict__ bias, int relu, int out_bf16) {
  __shared__ unsigned short smem[2 * 64 * 64];
  unsigned short* As = smem;
  unsigned short* Bs = smem + 64 * 64;
  int bx = blockIdx.x, by = blockIdx.y;
  const unsigned short* Ab = A + (size_t)bx * 64 * lda;
  const unsigned short* Bb = B + (size_t)by * 64 * ldb;
  int crow0 = bx * 64, ccol0 = by * 64;

  const int t = threadIdx.x;
  const int l = t & 63;
  const int w = t >> 6;
  const int fr = l & 15;
  const int quad = l >> 4;
  const int wm = (w & 1) * 32;
  const int wn = (w >> 1) * 32;
  const int fq4 = quad * 4;

  int srow[2], scg[2], sloff[2];
#pragma unroll
  for (int j = 0; j < 2; j++) {
    srow[j] = w * 16 + j * 8 + (l >> 3);
    scg[j] = ((l & 7) - srow[j]) & 7;
    sloff[j] = (w * 16 + j * 8) * 64 + l * 8;
  }

  f32x4 acc[2][2];
#pragma unroll
  for (int m = 0; m < 2; m++)
#pragma unroll
    for (int n = 0; n < 2; n++) acc[m][n] = (f32x4){0.f, 0.f, 0.f, 0.f};

  for (int kk = 0; kk < K; kk += 64) {
    __syncthreads();
#pragma unroll
    for (int j = 0; j < 2; j++)
      __builtin_amdgcn_global_load_lds(
          (gvoid_t*)(Ab + (size_t)srow[j] * lda + kk + scg[j] * 8),
          (lvoid_t*)(As + sloff[j]), 16, 0, 0);
#pragma unroll
    for (int j = 0; j < 2; j++)
      __builtin_amdgcn_global_load_lds(
          (gvoid_t*)(Bb + (size_t)srow[j] * ldb + kk + scg[j] * 8),
          (lvoid_t*)(Bs + sloff[j]), 16, 0, 0);
    __syncthreads();
#pragma unroll
    for (int s = 0; s < 2; s++) {
      short8 af[2], bf[2];
#pragma unroll
      for (int m = 0; m < 2; m++) {
        int r = wm + m * 16 + fr;
        int slot = (s * 4 + quad + r) & 7;
        af[m] = *(const short8*)(As + r * 64 + slot * 8);
      }
#pragma unroll
      for (int n = 0; n < 2; n++) {
        int r = wn + n * 16 + fr;
        int slot = (s * 4 + quad + r) & 7;
        bf[n] = *(const short8*)(Bs + r * 64 + slot * 8);
      }
#pragma unroll
      for (int m = 0; m < 2; m++)
#pragma unroll
        for (int n = 0; n < 2; n++)
          acc[m][n] = __builtin_amdgcn_mfma_f32_16x16x32_bf16(af[m], bf[n], acc[m][n], 0, 0, 0);
    }
  }

  if (out_bf16) {
    __syncthreads();
#pragma unroll
    for (int m = 0; m < 2; m++) {
#pragma unroll
      for (int n = 0; n < 2; n++) {
        int colb = wn + n * 16 + fr;
        float bv = bias ? bias[ccol0 + colb] : 0.f;
#pragma unroll
        for (int r = 0; r < 4; r++) {
          int row = wm + m * 16 + fq4 + r;
          float v = acc[m][n][r] + bv;
          if (relu) v = fmaxf(v, 0.f);
          int cc = ((colb >> 3) + row) & 7;
          smem[row * 64 + cc * 8 + (colb & 7)] = f2b(v);
        }
      }
    }
    __syncthreads();
    unsigned short* Cp = (unsigned short*)Cout;
    for (int i = t; i < 512; i += 256) {
      int row = i >> 3, lc = i & 7;
      int pc = (lc + row) & 7;
      uint4 v = *(const uint4*)(smem + row * 64 + pc * 8);
      *(uint4*)(Cp + (size_t)(crow0 + row) * ldc + ccol0 + lc * 8) = v;
    }
  } else {
    float* Cp = (float*)Cout;
#pragma unroll
    for (int m = 0; m < 2; m++) {
#pragma unroll
      for (int n = 0; n < 2; n++) {
        int colb = wn + n * 16 + fr;
        float bv = bias ? bias[ccol0 + colb] : 0.f;
#pragma unroll
        for (int r = 0; r < 4; r++) {
          int row = wm + m * 16 + fq4 + r;
          float v = acc[m][n][r] + bv;
          if (relu) v = fmaxf(v, 0.f);
          Cp[(size_t)(crow0 + row) * ldc + ccol0 + colb] = v;
        }
      }
    }
  }
}

// -------- per-row softmax denominator: sums[i] = sum of E over the band --------
__global__ __launch_bounds__(256) void k_stats(const unsigned short* __restrict__ Eband,
                                               float* __restrict__ sums) {
  int ig = blockIdx.x * 4 + (threadIdx.x >> 6);   // global row 0..12287
  int lane = threadIdx.x & 63;
  int i = ig & 4095;
  int ti = i >> 7;
  int cbase = (ti - 2) * 128;
  int jlo = i - 249; if (jlo < 0) jlo = 0;
  int jhi = i + 249; if (jhi > NSEQ - 1) jhi = NSEQ - 1;
  int clo = jlo - cbase, chi = jhi - cbase;
  const unsigned short* L = Eband + (size_t)ig * 640;
  float s = 0.f;
  for (int c = clo + lane; c <= chi; c += 64) s += b2f(L[c]);
  for (int off = 32; off; off >>= 1) s += __shfl_xor(s, off);
  if (lane == 0) sums[ig] = s;
}

// -------- build banded attT (fp8 x16): attT_s[i][j - 128*((i>>7)-2)] = 16*att[j][i] --------
__global__ __launch_bounds__(256) void k_build_attT(const unsigned short* __restrict__ Eband,
                                                    const float* __restrict__ sums,
                                                    unsigned char* __restrict__ t0,
                                                    unsigned char* __restrict__ t1,
                                                    unsigned char* __restrict__ t2) {
  int byy = blockIdx.y;
  int s = byy >> 5, ti = byy & 31;       // i tile (attT rows), local
  int tj = ti + (int)blockIdx.x - 2;     // j tile
  if (tj < 0 || tj >= 32) return;
  unsigned char* dst = (s == 0) ? t0 : ((s == 1) ? t1 : t2);
  __shared__ unsigned char T[128][132];  // T[i_loc][j_loc]
  int t = threadIdx.x;
  int c0 = (ti - tj + 2) * 128;  // Eband col base for rows j reading i-tile ti
  int colg = (t & 31) * 4;       // i_loc
  for (int jj = t >> 5; jj < 128; jj += 8) {
    int jg = s * NSEQ + tj * 128 + jj;
    float inv = 16.f / sums[jg];
    ushort4 v = *(const ushort4*)&Eband[(size_t)jg * 640 + c0 + colg];
    float vv[4] = {b2f(v.x), b2f(v.y), b2f(v.z), b2f(v.w)};
#pragma unroll
    for (int q = 0; q < 4; q++) {
      int i = ti * 128 + colg + q;
      int d = i - (tj * 128 + jj);
      float a = (d < 250 && d > -250) ? vv[q] * inv : 0.f;
      T[colg + q][jj] = f2e4(a);
    }
  }
  __syncthreads();
  int jb0 = (tj - ti + 2) * 128;  // banded col base in attT rows of tile ti
  for (int ii = t >> 5; ii < 128; ii += 8) {
    size_t o = (size_t)(ti * 128 + ii) * 640 + jb0 + colg;
    *(unsigned int*)(dst + o) = *(const unsigned int*)&T[ii][colg];
  }
}

// -------- write full fp32 att (stream 0 / x1), zeros outside band --------
__global__ __launch_bounds__(256) void k_write_att(const unsigned short* __restrict__ Eband,
                                                   const float* __restrict__ sums,
                                                   float* __restrict__ att) {
  int i = blockIdx.x;
  int ti = i >> 7, cbase = (ti - 2) * 128;
  int jlo = i - 249; if (jlo < 0) jlo = 0;
  int jhi = i + 249; if (jhi > NSEQ - 1) jhi = NSEQ - 1;
  float inv = 1.f / sums[i];
  const unsigned short* L = Eband + (size_t)i * 640;
  float* arow = att + (size_t)i * NSEQ;
  for (int j0 = threadIdx.x * 4; j0 < NSEQ; j0 += 1024) {
    float ov[4];
#pragma unroll
    for (int q = 0; q < 4; q++) {
      int j = j0 + q;
      ov[q] = (j >= jlo && j <= jhi) ? b2f(L[j - cbase]) * inv : 0.f;
    }
    *(float4*)(arow + j0) = make_float4(ov[0], ov[1], ov[2], ov[3]);
  }
}

// -------- residual + LayerNorm (ddof=1, eps on std) for 3 streams, sum -> bf16 --------
__global__ __launch_bounds__(256) void k_ln3(const unsigned short* __restrict__ yo,
                                             const float* __restrict__ x1,
                                             const float* __restrict__ x2,
                                             const float* __restrict__ x3,
                                             const float* __restrict__ g,
                                             const float* __restrict__ b,
                                             unsigned short* __restrict__ ysum_b) {
  int i = blockIdx.x, t = threadIdx.x;
  int w = t >> 6, lane = t & 63;
  __shared__ float red[8];
  const float* xs[3] = {x1, x2, x3};
  float4 gg = *(const float4*)(g + t * 4);
  float4 bb = *(const float4*)(b + t * 4);
  float acc[4] = {0.f, 0.f, 0.f, 0.f};
  for (int s = 0; s < 3; s++) {
    ushort4 yv = *(const ushort4*)(yo + ((size_t)(s * NSEQ + i)) * MDIM + t * 4);
    float4 xx = *(const float4*)(xs[s] + (size_t)i * MDIM + t * 4);
    float v[4] = {b2f(yv.x) + xx.x, b2f(yv.y) + xx.y, b2f(yv.z) + xx.z, b2f(yv.w) + xx.w};
    float s1 = v[0] + v[1] + v[2] + v[3];
    float s2 = v[0]*v[0] + v[1]*v[1] + v[2]*v[2] + v[3]*v[3];
    for (int off = 32; off; off >>= 1) { s1 += __shfl_xor(s1, off); s2 += __shfl_xor(s2, off); }
    __syncthreads();
    if (lane == 0) { red[w] = s1; red[4 + w] = s2; }
    __syncthreads();
    float S1 = red[0] + red[1] + red[2] + red[3];
    float S2 = red[4] + red[5] + red[6] + red[7];
    float mean = S1 * (1.f / 1024.f);
    float var = (S2 - S1 * mean) * (1.f / 1023.f);
    float rstd = 1.f / (sqrtf(var) + 1e-6f);
    acc[0] += gg.x * (v[0] - mean) * rstd + bb.x;
    acc[1] += gg.y * (v[1] - mean) * rstd + bb.y;
    acc[2] += gg.z * (v[2] - mean) * rstd + bb.z;
    acc[3] += gg.w * (v[3] - mean) * rstd + bb.w;
  }
  ushort4 o;
  o.x = f2b(acc[0]); o.y = f2b(acc[1]); o.z = f2b(acc[2]); o.w = f2b(acc[3]);
  *(ushort4*)(ysum_b + (size_t)i * MDIM + t * 4) = o;
}

// -------- final: LN(128, gkc/bkc) -> dot(kd_w) + kd_b -> sigmoid --------
__global__ __launch_bounds__(128) void k_final(const float* __restrict__ h3,
                                               const float* __restrict__ g,
                                               const float* __restrict__ b,
                                               const float* __restrict__ kdw,
                                               const float* __restrict__ kdb,
                                               float* __restrict__ yout) {
  int i = blockIdx.x, t = threadIdx.x;
  float v = h3[(size_t)i * 128 + t];
  float s1 = v, s2 = v * v;
  for (int off = 32; off; off >>= 1) { s1 += __shfl_xor(s1, off); s2 += __shfl_xor(s2, off); }
  __shared__ float red[4];
  int w = t >> 6, lane = t & 63;
  if (lane == 0) { red[w] = s1; red[2 + w] = s2; }
  __syncthreads();
  float S1 = red[0] + red[1], S2 = red[2] + red[3];
  float mean = S1 * (1.f / 128.f);
  float var = (S2 - S1 * mean) * (1.f / 127.f);
  float rstd = 1.f / (sqrtf(var) + 1e-6f);
  float ln = g[t] * (v - mean) * rstd + b[t];
  float p = ln * kdw[t];
  for (int off = 32; off; off >>= 1) p += __shfl_xor(p, off);
  __syncthreads();
  if (lane == 0) red[w] = p;
  __syncthreads();
  if (t == 0) {
    float z = red[0] + red[1] + kdb[0];
    yout[i] = 1.f / (1.f + __expf(-z));
  }
}

extern "C" void kernel_launch(void* const* d_in, const int* in_sizes, int n_in,
                              void* d_out, int out_size, void* d_ws, size_t ws_size,
                              hipStream_t stream) {
  const float* x1 = (const float*)d_in[0];
  const float* x2 = (const float*)d_in[1];
  const float* x3 = (const float*)d_in[2];
  const float* Wq = (const float*)d_in[3];
  const float* Wk = (const float*)d_in[4];
  const float* Wv = (const float*)d_in[5];
  const float* Wo = (const float*)d_in[6];
  const float* ka_w = (const float*)d_in[7];
  const float* ka_b = (const float*)d_in[8];
  const float* kb_w = (const float*)d_in[9];
  const float* kb_b = (const float*)d_in[10];
  const float* kc_w = (const float*)d_in[11];
  const float* kc_b = (const float*)d_in[12];
  const float* kd_w = (const float*)d_in[13];
  const float* kd_b = (const float*)d_in[14];
  const float* g13 = (const float*)d_in[15];
  const float* b13 = (const float*)d_in[16];
  const float* gkc = (const float*)d_in[17];
  const float* bkc = (const float*)d_in[18];

  float* y_out = (float*)d_out;
  float* att_out = y_out + NSEQ;  // [4096,4096] fp32

  char* ws = (char*)d_ws;
  size_t off = 0;
  auto alloc = [&](size_t bytes) -> void* {
    void* p = ws + off;
    off += (bytes + 255) & ~(size_t)255;
    return p;
  };
  const size_t NM = (size_t)3 * NSEQ * MDIM;  // 12.6M elems
  // fp8 attention weights, contiguous: Wq|Wk|Wv|Wo (x64 scaled)
  unsigned char* Wf = (unsigned char*)alloc(4 * 1048576);
  // bf16 MLP weights, contiguous: ka|kb|kc
  unsigned short* Wmlp = (unsigned short*)alloc((1048576 + 524288 + 65536) * 2);
  unsigned char* Xf = (unsigned char*)alloc(NM);      // later: yb fp8, then h1b bf16
  unsigned char* Qf = (unsigned char*)alloc(NM);      // yo bf16 spans Qf+Kf; later h2b
  unsigned char* Kf = (unsigned char*)alloc(NM);
  unsigned char* VTf = (unsigned char*)alloc(NM);     // later: ysum_b bf16 (8MB)
  unsigned short* Eband = (unsigned short*)alloc((size_t)3 * NSEQ * 640 * 2);
  float* sums = (float*)alloc((size_t)3 * NSEQ * 4);
  unsigned char* aT0 = (unsigned char*)alloc((size_t)NSEQ * 640);  // later: h3 f32
  unsigned char* aT1 = (unsigned char*)alloc((size_t)NSEQ * 640);
  unsigned char* aT2 = (unsigned char*)alloc((size_t)NSEQ * 640);
  // weight sub-pointers
  unsigned char* Wv_f = Wf + 2097152;
  unsigned char* Wo_f = Wf + 3145728;
  unsigned short* ka_b16 = Wmlp;
  unsigned short* kb_b16 = Wmlp + 1048576;
  unsigned short* kc_b16 = Wmlp + 1572864;
  // aliases (lifetimes disjoint)
  unsigned char* yb = Xf;                       // fp8 [12288,1024] = 8*y
  unsigned short* yo = (unsigned short*)Qf;     // bf16 [12288,1024] spans Qf..Kf
  unsigned short* ysum_b = (unsigned short*)VTf;// bf16 [4096,1024]
  unsigned short* h1b = (unsigned short*)Xf;    // bf16 [4096,1024]
  unsigned short* h2b = (unsigned short*)Qf;    // bf16 [4096,512]
  float* h3 = (float*)aT0;                      // f32 [4096,128]

  // all conversions in one dispatch
  k_cvt_all<<<17984, 256, 0, stream>>>(Wq, Wk, Wv, Wo, ka_w, kb_w, kc_w,
                                       x1, x2, x3, Wf, Wmlp, Xf);

  // merged Q+K+VT fp8 (alpha 1/64; 0.06 deferred to logits)
  k_gemm<<<dim3(96, 24), 256, 0, stream>>>(Xf, 1024, Wf, 1024, Qf, Kf, 1024,
                                           1024, 1.f / 64.f, nullptr, 0, 2, 0, 3,
                                           Wv_f, VTf);
  // banded logits -> E = exp(0.06 * Q.K) bf16 [12288,640]
  k_gemm<<<dim3(96, 5), 256, 0, stream>>>(Qf, 1024, Kf, 1024, Eband, nullptr, 640,
                                          1024, 0.06f, nullptr, 0, 1, 1, 1,
                                          nullptr, nullptr);
  k_stats<<<3072, 256, 0, stream>>>(Eband, sums);
  k_build_attT<<<dim3(5, 96), 256, 0, stream>>>(Eband, sums, aT0, aT1, aT2);
  // yb = 8*y: (16att)@V * 0.5, fp8 out
  k_gemm<<<dim3(96, 8), 256, 0, stream>>>(aT0, 640, VTf, 3 * NSEQ, yb, nullptr, 1024,
                                          NSEQ, 0.5f, nullptr, 0, 2, 0, 2,
                                          aT1, aT2);
  k_write_att<<<4096, 256, 0, stream>>>(Eband, sums, att_out);
  // yo = y @ Wo^T (bf16 out): (8y)@(64Wo) * 1/512
  k_gemm<<<dim3(96, 8), 256, 0, stream>>>(yb, 1024, Wo_f, 1024, yo, nullptr, 1024,
                                          1024, 1.f / 512.f, nullptr, 0, 1, 0, 0,
                                          nullptr, nullptr);
  // residual + LN + 3-stream sum -> bf16
  k_ln3<<<4096, 256, 0, stream>>>(yo, x1, x2, x3, g13, b13, ysum_b);

  // MLP head (bf16, 64x64 tiles)
  k_gemm64<<<dim3(64, 16), 256, 0, stream>>>(ysum_b, 1024, ka_b16, 1024, h1b, 1024,
                                             1024, ka_b, 0, 1);
  k_gemm64<<<dim3(64, 8), 256, 0, stream>>>(h1b, 1024, kb_b16, 1024, h2b, 512,
                                            1024, kb_b, 0, 1);
  k_gemm64<<<dim3(64, 2), 256, 0, stream>>>(h2b, 512, kc_b16, 512, h3, 128,
                                            512, kc_b, 1, 0);
  k_final<<<4096, 128, 0, stream>>>(h3, gkc, bkc, kd_w, kd_b, y_out);
}

// Round 9
// 363.077 us; speedup vs baseline: 2.3824x; 1.0248x over previous
//
#include <hip/hip_runtime.h>
#include <hip/hip_bf16.h>
#include <cstdint>
#include <cstddef>

// Problem constants
#define NSEQ 4096
#define MDIM 1024
// band: |i-j| < 250 -> row-tile ti needs col-tiles [ti-2, ti+2]
// banded layout (Eband bf16 = exp(logits), attT fp8 x16): row i, col c = j - 128*((i>>7)-2), width 640
// fp8 scaling: attn weights x64, attT x16, y stored x8; MLP kept bf16 for accuracy.
// GEMM operand rule: A = matrix indexing the OUTPUT'S MINOR DIM (D-layout puts A-dim
// on quad*4+reg -> 4 consecutive out-cols per thread -> pack in reg, store direct to
// global; no LDS epilogue, no conflicts).

typedef __attribute__((ext_vector_type(8))) short short8;
typedef __attribute__((ext_vector_type(4))) float f32x4;
typedef __attribute__((ext_vector_type(2))) long long2v;

typedef const __attribute__((address_space(1))) void gvoid_t;
typedef __attribute__((address_space(3))) void lvoid_t;

__device__ __forceinline__ unsigned short f2b(float x) {
  union { float f; unsigned int u; } a; a.f = x;
  unsigned int r = (a.u + 0x7fffu + ((a.u >> 16) & 1u)) >> 16;
  return (unsigned short)r;
}
__device__ __forceinline__ float b2f(unsigned short u) {
  union { float f; unsigned int u32; } a; a.u32 = ((unsigned int)u) << 16;
  return a.f;
}
__device__ __forceinline__ unsigned char f2e4(float x) {
  return (unsigned char)(__builtin_amdgcn_cvt_pk_fp8_f32(x, x, 0, false) & 0xff);
}
__device__ __forceinline__ unsigned int f2e4x4(float a, float b, float c, float d) {
  unsigned int lo = __builtin_amdgcn_cvt_pk_fp8_f32(a, b, 0, false);
  return (unsigned int)__builtin_amdgcn_cvt_pk_fp8_f32(c, d, lo, true);
}

// -------- merged cvt: Wq..Wo (x64)->fp8, ka/kb/kc->bf16, x1..x3->fp8 --------
__global__ __launch_bounds__(256) void k_cvt_all(
    const float* __restrict__ s0, const float* __restrict__ s1,
    const float* __restrict__ s2, const float* __restrict__ s3,
    const float* __restrict__ s4, const float* __restrict__ s5,
    const float* __restrict__ s6,
    const float* __restrict__ xa, const float* __restrict__ xb,
    const float* __restrict__ xc,
    unsigned char* __restrict__ Wf8, unsigned short* __restrict__ Wmlp,
    unsigned char* __restrict__ Xdst) {
  int idx = blockIdx.x * 256 + threadIdx.x;  // chunk of 4 floats
  if (idx < 1048576) {  // Wq,Wk,Wv,Wo fp8 x64
    int seg = idx >> 18, local = idx & 262143;
    const float* src = (seg == 0) ? s0 : (seg == 1) ? s1 : (seg == 2) ? s2 : s3;
    float4 v = *(const float4*)(src + (size_t)local * 4);
    *(unsigned int*)(Wf8 + (size_t)idx * 4) =
        f2e4x4(v.x * 64.f, v.y * 64.f, v.z * 64.f, v.w * 64.f);
  } else if (idx < 1458176) {  // ka,kb,kc bf16
    int i2 = idx - 1048576;
    const float* src; int local;
    if (i2 < 262144) { src = s4; local = i2; }
    else if (i2 < 393216) { src = s5; local = i2 - 262144; }
    else { src = s6; local = i2 - 393216; }
    float4 v = *(const float4*)(src + (size_t)local * 4);
    ushort4 o; o.x = f2b(v.x); o.y = f2b(v.y); o.z = f2b(v.z); o.w = f2b(v.w);
    *(ushort4*)(Wmlp + (size_t)i2 * 4) = o;
  } else {  // x1..x3 fp8
    int i2 = idx - 1458176;   // 0 .. 3*2^20-1
    int seg = i2 >> 20, local = i2 & 1048575;
    const float* src = (seg == 0) ? xa : (seg == 1) ? xb : xc;
    float4 v = *(const float4*)(src + (size_t)local * 4);
    *(unsigned int*)(Xdst + (size_t)i2 * 4) = f2e4x4(v.x, v.y, v.z, v.w);
  }
}

// -------- fp8 GEMM, direct-store epilogue --------
// BK=128, global_load_lds 16B staging; LDS row=128B=8 slots; slot s holds chunk (s-r)&7.
// Frag reads: b128 slot reads, 2 MFMAs each (K-permuted identically for A/B -> exact).
// Out element (orow, ocol): orow = rbase + wn + n*16 + fr (B-dim, lanes),
// ocol = cbase + wm + m*16 + quad*4 + r (A-dim, 4 consecutive per thread -> packed store).
// okind: 0=f32(dwordx4), 1=bf16(8B, optional exp), 2=fp8(dword).
// mode 3: QKV, grid(96,24). by<8: Q (A=Wq,B=X); 8..15: K; >=16: VT (A=X,B=Wv, out A2).
// mode 1: logits->Eband, grid(96,5): A=K-tile (bt), B=Q-tile (bx).
// mode 2: y=attT@V, grid(96,8): A=VT (+s*4096), B=attT banded (b_koff), K window.
// mode 0: Wo, grid(96,8): A=Wo (by), B=y (bx).
__global__ __launch_bounds__(256) void k_gemm(
    const unsigned char* __restrict__ A, int lda,
    const unsigned char* __restrict__ B, int ldb,
    void* __restrict__ Cout, void* __restrict__ Cout2, int ldc,
    int K, float alpha, int okind, int do_exp, int mode,
    const unsigned char* __restrict__ A1, const unsigned char* __restrict__ A2) {
  __shared__ unsigned char smem[2 * 128 * 128];  // 32 KB staging
  unsigned char* As = smem;
  unsigned char* Bs = smem + 128 * 128;
  int bx = blockIdx.x, by = blockIdx.y;
  const unsigned char* Ab;
  const unsigned char* Bb;
  void* Cdst = Cout;
  int k0 = 0, k1 = K, b_koff = 0;
  int ldce = ldc;
  int rbase, cbase;
  int ldae = lda, ldbe = ldb;
  if (mode == 0) {
    Ab = A + (size_t)by * 128 * lda;      // Wo rows
    Bb = B + (size_t)bx * 128 * ldb;      // y rows
    rbase = bx * 128; cbase = by * 128;
  } else if (mode == 3) {
    if (by < 16) {
      Ab = A + (size_t)by * 128 * lda;    // Wq|Wk contiguous rows
      Bb = B + (size_t)bx * 128 * ldb;    // X rows
      if (by >= 8) Cdst = Cout2;
      rbase = bx * 128; cbase = (by & 7) * 128;
    } else {
      Ab = B + (size_t)bx * 128 * ldb;                 // X rows (qc = x)
      Bb = A1 + (size_t)(by - 16) * 128 * 1024;        // Wv rows (qr = wv)
      Cdst = (void*)const_cast<unsigned char*>(A2);    // VT [1024,12288]
      rbase = (by - 16) * 128; cbase = bx * 128;
      ldce = 3 * NSEQ;
    }
  } else if (mode == 1) {
    int s = bx >> 5, ti = bx & 31;
    int bt = ti + by - 2;
    if (bt < 0 || bt >= 32) return;
    Ab = A + (size_t)(s * 32 + bt) * 128 * lda;   // K rows (qc = band col)
    Bb = B + (size_t)bx * 128 * ldb;              // Q rows (qr = i)
    rbase = bx * 128; cbase = by * 128;           // ldce = 640
  } else {  // mode 2
    int s = bx >> 5, ti = bx & 31;
    Ab = A + (size_t)by * 128 * lda + s * NSEQ;   // VT rows (qc = v), col offset s*4096
    const unsigned char* Bbase = (s == 0) ? B : ((s == 1) ? A1 : A2);
    Bb = Bbase + (size_t)ti * 128 * 640;          // attT banded rows (qr = i)
    ldbe = 640;
    int lo = ti - 2; if (lo < 0) lo = 0;
    int hi = ti + 3; if (hi > 32) hi = 32;
    k0 = lo * 128; k1 = hi * 128;
    b_koff = (ti - 2) * 128;
    rbase = bx * 128; cbase = by * 128;
  }

  const int t = threadIdx.x;
  const int l = t & 63;
  const int w = t >> 6;
  const int fr = l & 15;
  const int quad = l >> 4;
  const int wm = (w >> 1) * 64;
  const int wn = (w & 1) * 64;
  const int fq4 = quad * 4;

  // staging: 4 insts per matrix per wave; inst j covers rows w*32+j*8 .. +7
  int srow[4], scg[4], sloff[4];
#pragma unroll
  for (int j = 0; j < 4; j++) {
    srow[j] = w * 32 + j * 8 + (l >> 3);
    scg[j] = ((l & 7) - srow[j]) & 7;       // global chunk for LDS slot l&7
    sloff[j] = (w * 32 + j * 8) * 128 + l * 16;
  }

  f32x4 acc[4][4];
#pragma unroll
  for (int m = 0; m < 4; m++)
#pragma unroll
    for (int n = 0; n < 4; n++) acc[m][n] = (f32x4){0.f, 0.f, 0.f, 0.f};

  for (int kk = k0; kk < k1; kk += 128) {
    int kb = kk - b_koff;
    __syncthreads();
#pragma unroll
    for (int j = 0; j < 4; j++)
      __builtin_amdgcn_global_load_lds(
          (gvoid_t*)(Ab + (size_t)srow[j] * ldae + kk + scg[j] * 16),
          (lvoid_t*)(As + sloff[j]), 16, 0, 0);
#pragma unroll
    for (int j = 0; j < 4; j++)
      __builtin_amdgcn_global_load_lds(
          (gvoid_t*)(Bb + (size_t)srow[j] * ldbe + kb + scg[j] * 16),
          (lvoid_t*)(Bs + sloff[j]), 16, 0, 0);
    __syncthreads();
#pragma unroll
    for (int kb2 = 0; kb2 < 2; kb2++) {
      long2v a16[4], b16[4];
      int cq = quad * 2 + kb2;   // logical chunk for this lane, this MFMA pair
#pragma unroll
      for (int m = 0; m < 4; m++) {
        int r = wm + m * 16 + fr;
        int slot = (cq + r) & 7;
        a16[m] = *(const long2v*)(As + r * 128 + slot * 16);
      }
#pragma unroll
      for (int n = 0; n < 4; n++) {
        int r = wn + n * 16 + fr;
        int slot = (cq + r) & 7;
        b16[n] = *(const long2v*)(Bs + r * 128 + slot * 16);
      }
#pragma unroll
      for (int m = 0; m < 4; m++)
#pragma unroll
        for (int n = 0; n < 4; n++)
          acc[m][n] = __builtin_amdgcn_mfma_f32_16x16x32_fp8_fp8(a16[m].x, b16[n].x, acc[m][n], 0, 0, 0);
#pragma unroll
      for (int m = 0; m < 4; m++)
#pragma unroll
        for (int n = 0; n < 4; n++)
          acc[m][n] = __builtin_amdgcn_mfma_f32_16x16x32_fp8_fp8(a16[m].y, b16[n].y, acc[m][n], 0, 0, 0);
    }
  }

  // direct-store epilogue: per (m,n) the 4 r-values are 4 consecutive out-cols
#pragma unroll
  for (int m = 0; m < 4; m++) {
#pragma unroll
    for (int n = 0; n < 4; n++) {
      int oc = cbase + wm + m * 16 + fq4;
      int orow = rbase + wn + n * 16 + fr;
      float v0 = acc[m][n][0] * alpha, v1 = acc[m][n][1] * alpha;
      float v2 = acc[m][n][2] * alpha, v3 = acc[m][n][3] * alpha;
      if (okind == 1) {
        if (do_exp) { v0 = __expf(v0); v1 = __expf(v1); v2 = __expf(v2); v3 = __expf(v3); }
        ushort4 o; o.x = f2b(v0); o.y = f2b(v1); o.z = f2b(v2); o.w = f2b(v3);
        *(uint2*)((unsigned short*)Cdst + (size_t)orow * ldce + oc) = *(uint2*)&o;
      } else if (okind == 2) {
        *(unsigned int*)((unsigned char*)Cdst + (size_t)orow * ldce + oc) =
            f2e4x4(v0, v1, v2, v3);
      } else {
        *(float4*)((float*)Cdst + (size_t)orow * ldce + oc) = make_float4(v0, v1, v2, v3);
      }
    }
  }
}

// -------- small bf16 GEMM: 64x64 tile, BK=64, direct-store (MLP head) --------
// A = weight (qc dim), B = activation (qr dim).
__global__ __launch_bounds__(256) void k_gemm64(
    const unsigned short* __restrict__ A, int lda,
    const unsigned short* __restrict__ B, int ldb,
    void* __restrict__ Cout, int ldc, int K,
    const float* __restrict__ bias, int relu, int out_bf16) {
  __shared__ unsigned short smem[2 * 64 * 64];
  unsigned short* As = smem;
  unsigned short* Bs = smem + 64 * 64;
  int bx = blockIdx.x, by = blockIdx.y;
  const unsigned short* Ab = A + (size_t)by * 64 * lda;   // weight rows
  const unsigned short* Bb = B + (size_t)bx * 64 * ldb;   // activation rows
  int rbase = bx * 64, cbase = by * 64;

  const int t = threadIdx.x;
  const int l = t & 63;
  const int w = t >> 6;
  const int fr = l & 15;
  const int quad = l >> 4;
  const int wm = (w & 1) * 32;
  const int wn = (w >> 1) * 32;
  const int fq4 = quad * 4;

  int srow[2], scg[2], sloff[2];
#pragma unroll
  for (int j = 0; j < 2; j++) {
    srow[j] = w * 16 + j * 8 + (l >> 3);
    scg[j] = ((l & 7) - srow[j]) & 7;
    sloff[j] = (w * 16 + j * 8) * 64 + l * 8;
  }

  f32x4 acc[2][2];
#pragma unroll
  for (int m = 0; m < 2; m++)
#pragma unroll
    for (int n = 0; n < 2; n++) acc[m][n] = (f32x4){0.f, 0.f, 0.f, 0.f};

  for (int kk = 0; kk < K; kk += 64) {
    __syncthreads();
#pragma unroll
    for (int j = 0; j < 2; j++)
      __builtin_amdgcn_global_load_lds(
          (gvoid_t*)(Ab + (size_t)srow[j] * lda + kk + scg[j] * 8),
          (lvoid_t*)(As + sloff[j]), 16, 0, 0);
#pragma unroll
    for (int j = 0; j < 2; j++)
      __builtin_amdgcn_global_load_lds(
          (gvoid_t*)(Bb + (size_t)srow[j] * ldb + kk + scg[j] * 8),
          (lvoid_t*)(Bs + sloff[j]), 16, 0, 0);
    __syncthreads();
#pragma unroll
    for (int s = 0; s < 2; s++) {
      short8 af[2], bf[2];
#pragma unroll
      for (int m = 0; m < 2; m++) {
        int r = wm + m * 16 + fr;
        int slot = (s * 4 + quad + r) & 7;
        af[m] = *(const short8*)(As + r * 64 + slot * 8);
      }
#pragma unroll
      for (int n = 0; n < 2; n++) {
        int r = wn + n * 16 + fr;
        int slot = (s * 4 + quad + r) & 7;
        bf[n] = *(const short8*)(Bs + r * 64 + slot * 8);
      }
#pragma unroll
      for (int m = 0; m < 2; m++)
#pragma unroll
        for (int n = 0; n < 2; n++)
          acc[m][n] = __builtin_amdgcn_mfma_f32_16x16x32_bf16(af[m], bf[n], acc[m][n], 0, 0, 0);
    }
  }

#pragma unroll
  for (int m = 0; m < 2; m++) {
#pragma unroll
    for (int n = 0; n < 2; n++) {
      int oc = cbase + wm + m * 16 + fq4;
      int orow = rbase + wn + n * 16 + fr;
      float4 bv = bias ? *(const float4*)(bias + oc) : make_float4(0.f, 0.f, 0.f, 0.f);
      float v0 = acc[m][n][0] + bv.x, v1 = acc[m][n][1] + bv.y;
      float v2 = acc[m][n][2] + bv.z, v3 = acc[m][n][3] + bv.w;
      if (relu) {
        v0 = fmaxf(v0, 0.f); v1 = fmaxf(v1, 0.f);
        v2 = fmaxf(v2, 0.f); v3 = fmaxf(v3, 0.f);
      }
      if (out_bf16) {
        ushort4 o; o.x = f2b(v0); o.y = f2b(v1); o.z = f2b(v2); o.w = f2b(v3);
        *(uint2*)((unsigned short*)Cout + (size_t)orow * ldc + oc) = *(uint2*)&o;
      } else {
        *(float4*)((float*)Cout + (size_t)orow * ldc + oc) = make_float4(v0, v1, v2, v3);
      }
    }
  }
}

// -------- per-row softmax denominator: sums[i] = sum of E over the band --------
__global__ __launch_bounds__(256) void k_stats(const unsigned short* __restrict__ Eband,
                                               float* __restrict__ sums) {
  int ig = blockIdx.x * 4 + (threadIdx.x >> 6);   // global row 0..12287
  int lane = threadIdx.x & 63;
  int i = ig & 4095;
  int ti = i >> 7;
  int cbase = (ti - 2) * 128;
  int jlo = i - 249; if (jlo < 0) jlo = 0;
  int jhi = i + 249; if (jhi > NSEQ - 1) jhi = NSEQ - 1;
  int clo = jlo - cbase, chi = jhi - cbase;
  const unsigned short* L = Eband + (size_t)ig * 640;
  float s = 0.f;
  for (int c = clo + lane; c <= chi; c += 64) s += b2f(L[c]);
  for (int off = 32; off; off >>= 1) s += __shfl_xor(s, off);
  if (lane == 0) sums[ig] = s;
}

// -------- build banded attT (fp8 x16): attT_s[i][j - 128*((i>>7)-2)] = 16*att[j][i] --------
__global__ __launch_bounds__(256) void k_build_attT(const unsigned short* __restrict__ Eband,
                                                    const float* __restrict__ sums,
                                                    unsigned char* __restrict__ t0,
                                                    unsigned char* __restrict__ t1,
                                                    unsigned char* __restrict__ t2) {
  int byy = blockIdx.y;
  int s = byy >> 5, ti = byy & 31;       // i tile (attT rows), local
  int tj = ti + (int)blockIdx.x - 2;     // j tile
  if (tj < 0 || tj >= 32) return;
  unsigned char* dst = (s == 0) ? t0 : ((s == 1) ? t1 : t2);
  __shared__ unsigned char T[128][132];  // T[i_loc][j_loc]
  int t = threadIdx.x;
  int c0 = (ti - tj + 2) * 128;  // Eband col base for rows j reading i-tile ti
  int colg = (t & 31) * 4;       // i_loc
  for (int jj = t >> 5; jj < 128; jj += 8) {
    int jg = s * NSEQ + tj * 128 + jj;
    float inv = 16.f / sums[jg];
    ushort4 v = *(const ushort4*)&Eband[(size_t)jg * 640 + c0 + colg];
    float vv[4] = {b2f(v.x), b2f(v.y), b2f(v.z), b2f(v.w)};
#pragma unroll
    for (int q = 0; q < 4; q++) {
      int i = ti * 128 + colg + q;
      int d = i - (tj * 128 + jj);
      float a = (d < 250 && d > -250) ? vv[q] * inv : 0.f;
      T[colg + q][jj] = f2e4(a);
    }
  }
  __syncthreads();
  int jb0 = (tj - ti + 2) * 128;  // banded col base in attT rows of tile ti
  for (int ii = t >> 5; ii < 128; ii += 8) {
    size_t o = (size_t)(ti * 128 + ii) * 640 + jb0 + colg;
    *(unsigned int*)(dst + o) = *(const unsigned int*)&T[ii][colg];
  }
}

// -------- write full fp32 att (stream 0 / x1), zeros outside band --------
__global__ __launch_bounds__(256) void k_write_att(const unsigned short* __restrict__ Eband,
                                                   const float* __restrict__ sums,
                                                   float* __restrict__ att) {
  int i = blockIdx.x;
  int ti = i >> 7, cbase = (ti - 2) * 128;
  int jlo = i - 249; if (jlo < 0) jlo = 0;
  int jhi = i + 249; if (jhi > NSEQ - 1) jhi = NSEQ - 1;
  float inv = 1.f / sums[i];
  const unsigned short* L = Eband + (size_t)i * 640;
  float* arow = att + (size_t)i * NSEQ;
  for (int j0 = threadIdx.x * 4; j0 < NSEQ; j0 += 1024) {
    float ov[4];
#pragma unroll
    for (int q = 0; q < 4; q++) {
      int j = j0 + q;
      ov[q] = (j >= jlo && j <= jhi) ? b2f(L[j - cbase]) * inv : 0.f;
    }
    *(float4*)(arow + j0) = make_float4(ov[0], ov[1], ov[2], ov[3]);
  }
}

// -------- residual + LayerNorm (ddof=1, eps on std) for 3 streams, sum -> bf16 --------
__global__ __launch_bounds__(256) void k_ln3(const unsigned short* __restrict__ yo,
                                             const float* __restrict__ x1,
                                             const float* __restrict__ x2,
                                             const float* __restrict__ x3,
                                             const float* __restrict__ g,
                                             const float* __restrict__ b,
                                             unsigned short* __restrict__ ysum_b) {
  int i = blockIdx.x, t = threadIdx.x;
  int w = t >> 6, lane = t & 63;
  __shared__ float red[8];
  const float* xs[3] = {x1, x2, x3};
  float4 gg = *(const float4*)(g + t * 4);
  float4 bb = *(const float4*)(b + t * 4);
  float acc[4] = {0.f, 0.f, 0.f, 0.f};
  for (int s = 0; s < 3; s++) {
    ushort4 yv = *(const ushort4*)(yo + ((size_t)(s * NSEQ + i)) * MDIM + t * 4);
    float4 xx = *(const float4*)(xs[s] + (size_t)i * MDIM + t * 4);
    float v[4] = {b2f(yv.x) + xx.x, b2f(yv.y) + xx.y, b2f(yv.z) + xx.z, b2f(yv.w) + xx.w};
    float s1 = v[0] + v[1] + v[2] + v[3];
    float s2 = v[0]*v[0] + v[1]*v[1] + v[2]*v[2] + v[3]*v[3];
    for (int off = 32; off; off >>= 1) { s1 += __shfl_xor(s1, off); s2 += __shfl_xor(s2, off); }
    __syncthreads();
    if (lane == 0) { red[w] = s1; red[4 + w] = s2; }
    __syncthreads();
    float S1 = red[0] + red[1] + red[2] + red[3];
    float S2 = red[4] + red[5] + red[6] + red[7];
    float mean = S1 * (1.f / 1024.f);
    float var = (S2 - S1 * mean) * (1.f / 1023.f);
    float rstd = 1.f / (sqrtf(var) + 1e-6f);
    acc[0] += gg.x * (v[0] - mean) * rstd + bb.x;
    acc[1] += gg.y * (v[1] - mean) * rstd + bb.y;
    acc[2] += gg.z * (v[2] - mean) * rstd + bb.z;
    acc[3] += gg.w * (v[3] - mean) * rstd + bb.w;
  }
  ushort4 o;
  o.x = f2b(acc[0]); o.y = f2b(acc[1]); o.z = f2b(acc[2]); o.w = f2b(acc[3]);
  *(ushort4*)(ysum_b + (size_t)i * MDIM + t * 4) = o;
}

// -------- final: LN(128, gkc/bkc) -> dot(kd_w) + kd_b -> sigmoid --------
__global__ __launch_bounds__(128) void k_final(const float* __restrict__ h3,
                                               const float* __restrict__ g,
                                               const float* __restrict__ b,
                                               const float* __restrict__ kdw,
                                               const float* __restrict__ kdb,
                                               float* __restrict__ yout) {
  int i = blockIdx.x, t = threadIdx.x;
  float v = h3[(size_t)i * 128 + t];
  float s1 = v, s2 = v * v;
  for (int off = 32; off; off >>= 1) { s1 += __shfl_xor(s1, off); s2 += __shfl_xor(s2, off); }
  __shared__ float red[4];
  int w = t >> 6, lane = t & 63;
  if (lane == 0) { red[w] = s1; red[2 + w] = s2; }
  __syncthreads();
  float S1 = red[0] + red[1], S2 = red[2] + red[3];
  float mean = S1 * (1.f / 128.f);
  float var = (S2 - S1 * mean) * (1.f / 127.f);
  float rstd = 1.f / (sqrtf(var) + 1e-6f);
  float ln = g[t] * (v - mean) * rstd + b[t];
  float p = ln * kdw[t];
  for (int off = 32; off; off >>= 1) p += __shfl_xor(p, off);
  __syncthreads();
  if (lane == 0) red[w] = p;
  __syncthreads();
  if (t == 0) {
    float z = red[0] + red[1] + kdb[0];
    yout[i] = 1.f / (1.f + __expf(-z));
  }
}

extern "C" void kernel_launch(void* const* d_in, const int* in_sizes, int n_in,
                              void* d_out, int out_size, void* d_ws, size_t ws_size,
                              hipStream_t stream) {
  const float* x1 = (const float*)d_in[0];
  const float* x2 = (const float*)d_in[1];
  const float* x3 = (const float*)d_in[2];
  const float* Wq = (const float*)d_in[3];
  const float* Wk = (const float*)d_in[4];
  const float* Wv = (const float*)d_in[5];
  const float* Wo = (const float*)d_in[6];
  const float* ka_w = (const float*)d_in[7];
  const float* ka_b = (const float*)d_in[8];
  const float* kb_w = (const float*)d_in[9];
  const float* kb_b = (const float*)d_in[10];
  const float* kc_w = (const float*)d_in[11];
  const float* kc_b = (const float*)d_in[12];
  const float* kd_w = (const float*)d_in[13];
  const float* kd_b = (const float*)d_in[14];
  const float* g13 = (const float*)d_in[15];
  const float* b13 = (const float*)d_in[16];
  const float* gkc = (const float*)d_in[17];
  const float* bkc = (const float*)d_in[18];

  float* y_out = (float*)d_out;
  float* att_out = y_out + NSEQ;  // [4096,4096] fp32

  char* ws = (char*)d_ws;
  size_t off = 0;
  auto alloc = [&](size_t bytes) -> void* {
    void* p = ws + off;
    off += (bytes + 255) & ~(size_t)255;
    return p;
  };
  const size_t NM = (size_t)3 * NSEQ * MDIM;  // 12.6M elems
  // fp8 attention weights, contiguous: Wq|Wk|Wv|Wo (x64 scaled)
  unsigned char* Wf = (unsigned char*)alloc(4 * 1048576);
  // bf16 MLP weights, contiguous: ka|kb|kc
  unsigned short* Wmlp = (unsigned short*)alloc((1048576 + 524288 + 65536) * 2);
  unsigned char* Xf = (unsigned char*)alloc(NM);      // later: yb fp8, then h1b bf16
  unsigned char* Qf = (unsigned char*)alloc(NM);      // yo bf16 spans Qf+Kf; later h2b
  unsigned char* Kf = (unsigned char*)alloc(NM);
  unsigned char* VTf = (unsigned char*)alloc(NM);     // later: ysum_b bf16 (8MB)
  unsigned short* Eband = (unsigned short*)alloc((size_t)3 * NSEQ * 640 * 2);
  float* sums = (float*)alloc((size_t)3 * NSEQ * 4);
  unsigned char* aT0 = (unsigned char*)alloc((size_t)NSEQ * 640);  // later: h3 f32
  unsigned char* aT1 = (unsigned char*)alloc((size_t)NSEQ * 640);
  unsigned char* aT2 = (unsigned char*)alloc((size_t)NSEQ * 640);
  // weight sub-pointers
  unsigned char* Wv_f = Wf + 2097152;
  unsigned char* Wo_f = Wf + 3145728;
  unsigned short* ka_b16 = Wmlp;
  unsigned short* kb_b16 = Wmlp + 1048576;
  unsigned short* kc_b16 = Wmlp + 1572864;
  // aliases (lifetimes disjoint)
  unsigned char* yb = Xf;                       // fp8 [12288,1024] = 8*y
  unsigned short* yo = (unsigned short*)Qf;     // bf16 [12288,1024] spans Qf..Kf
  unsigned short* ysum_b = (unsigned short*)VTf;// bf16 [4096,1024]
  unsigned short* h1b = (unsigned short*)Xf;    // bf16 [4096,1024]
  unsigned short* h2b = (unsigned short*)Qf;    // bf16 [4096,512]
  float* h3 = (float*)aT0;                      // f32 [4096,128]

  // all conversions in one dispatch
  k_cvt_all<<<17984, 256, 0, stream>>>(Wq, Wk, Wv, Wo, ka_w, kb_w, kc_w,
                                       x1, x2, x3, Wf, Wmlp, Xf);

  // merged Q+K+VT fp8 (A = minor-dim operand): Q/K: A=Wq|Wk, B=X; VT: A=X, B=Wv
  k_gemm<<<dim3(96, 24), 256, 0, stream>>>(Wf, 1024, Xf, 1024, Qf, Kf, 1024,
                                           1024, 1.f / 64.f, 2, 0, 3, Wv_f, VTf);
  // banded logits -> E = exp(0.06 * Q.K) bf16 [12288,640]; A=K (band col), B=Q
  k_gemm<<<dim3(96, 5), 256, 0, stream>>>(Kf, 1024, Qf, 1024, Eband, nullptr, 640,
                                          1024, 0.06f, 1, 1, 1, nullptr, nullptr);
  k_stats<<<3072, 256, 0, stream>>>(Eband, sums);
  k_build_attT<<<dim3(5, 96), 256, 0, stream>>>(Eband, sums, aT0, aT1, aT2);
  // yb = 8*y: A=VT (v minor), B=attT banded; (16att)@V * 0.5, fp8 out
  k_gemm<<<dim3(96, 8), 256, 0, stream>>>(VTf, 3 * NSEQ, aT0, 640, yb, nullptr, 1024,
                                          NSEQ, 0.5f, 2, 0, 2, aT1, aT2);
  k_write_att<<<4096, 256, 0, stream>>>(Eband, sums, att_out);
  // yo = y @ Wo^T (bf16 out): A=Wo, B=y; (8y)@(64Wo) * 1/512
  k_gemm<<<dim3(96, 8), 256, 0, stream>>>(Wo_f, 1024, yb, 1024, yo, nullptr, 1024,
                                          1024, 1.f / 512.f, 1, 0, 0, nullptr, nullptr);
  // residual + LN + 3-stream sum -> bf16
  k_ln3<<<4096, 256, 0, stream>>>(yo, x1, x2, x3, g13, b13, ysum_b);

  // MLP head (bf16, 64x64 tiles, A=weight)
  k_gemm64<<<dim3(64, 16), 256, 0, stream>>>(ka_b16, 1024, ysum_b, 1024, h1b, 1024,
                                             1024, ka_b, 0, 1);
  k_gemm64<<<dim3(64, 8), 256, 0, stream>>>(kb_b16, 1024, h1b, 1024, h2b, 512,
                                            1024, kb_b, 0, 1);
  k_gemm64<<<dim3(64, 2), 256, 0, stream>>>(kc_b16, 512, h2b, 512, h3, 128,
                                            512, kc_b, 1, 0);
  k_final<<<4096, 128, 0, stream>>>(h3, gkc, bkc, kd_w, kd_b, y_out);
}